// Round 9
// baseline (1769.428 us; speedup 1.0000x reference)
//
#include <hip/hip_runtime.h>
#include <math.h>

typedef unsigned int u32;
typedef unsigned long long u64;

#define BIGN (-1e30f)

static constexpr int NB = 16;     // batch
static constexpr int TF = 2000;   // T_FEATS
static constexpr int TT = 400;    // T_TEXT

__device__ __forceinline__ float wsum(float v){
#pragma unroll
  for(int o=32;o;o>>=1) v += __shfl_xor(v,o,64);
  return v;
}
// raw HW transcendentals: v_exp_f32 (2^x), v_log_f32 (log2 x)
__device__ __forceinline__ float EXP2(float x){ return __builtin_amdgcn_exp2f(x); }
__device__ __forceinline__ float LOG2(float x){ return __builtin_amdgcn_logf(x); }

// log-sum-exp in BASE-2 domain
__device__ __forceinline__ float lse2b(float x, float y){
  float m = fmaxf(x,y);
  return m + LOG2(1.0f + EXP2(-fabsf(x-y)));
}
__device__ __forceinline__ float lse3b(float x, float y, float z){
  float mx = fmaxf(fmaxf(x,y),z);
  float md = __builtin_amdgcn_fmed3f(x,y,z);
  float mn = fminf(fminf(x,y),z);
  return mx + LOG2(1.0f + EXP2(md-mx) + EXP2(mn-mx));
}

// ---------------- gammaln tables ----------------
__global__ void k_lgt(double* lgt){
  int m = blockIdx.x*blockDim.x + threadIdx.x;
  if(m < 2432) lgt[m] = (m>=1)? lgamma((double)m) : 0.0;
}
__global__ void k_terms(const double* __restrict__ lgt, double* rowA, double* colA, double* sA){
  int i = blockIdx.x*blockDim.x + threadIdx.x;
  if(i < TF)   rowA[i] = -lgt[2401] - lgt[i+1] - lgt[2000-i] + lgt[2001];
  if(i < TT)   colA[i] =  lgt[401]  - lgt[i+2] - lgt[400-i];
  if(i < 2399) sA[i]   =  lgt[i+2]  + lgt[2399-i];
}

// ---------------- conv1d (cross-correlation, pad=(KW-1)/2), OIH weights ----------------
// 128 threads, 2 output channels per thread (o, o+128): each LDS window read feeds 2x the FMAs.
// Weights double-buffered in registers (8-channel tiles, float4-aligned: 8*KW*4B = 96/32 B).
template<int CIN, int KW, bool RELU>
__global__ __launch_bounds__(128,2) void conv_k(const float* __restrict__ in, const float* __restrict__ w,
    const float* __restrict__ bias, float* __restrict__ out, int P){
  constexpr int PT = 32;
  constexpr int ROWS = PT + KW - 1;
  constexpr int RPAD = (ROWS + 3) & ~3;
  constexpr int CT = 8;
  constexpr int WT = CT*KW;            // 24 (KW3) or 8 (KW1)
  __shared__ __align__(16) float xs[256][RPAD];
  const int b = blockIdx.y;
  const int p0 = blockIdx.x * PT;
  const int o = threadIdx.x;           // 0..127; outputs o and o+128
  float acc0[PT], acc1[PT];
  const float bo0 = bias[o], bo1 = bias[o+128];
#pragma unroll
  for(int i=0;i<PT;i++){ acc0[i] = bo0; acc1[i] = bo1; }
  const float* inb = in + (size_t)b * P * CIN;
  const float* wo0 = w + (size_t)o * CIN * KW;
  const float* wo1 = w + (size_t)(o+128) * CIN * KW;
  for(int cc=0; cc<CIN; cc+=256){
    __syncthreads();
    for(int i=0;i<ROWS;i++){
      int p = p0 + i - (KW==3 ? 1 : 0);
      float v0 = 0.f, v1 = 0.f;
      if(p>=0 && p<P){
        v0 = inb[(size_t)p*CIN + cc + o];
        v1 = inb[(size_t)p*CIN + cc + o + 128];
      }
      xs[o][i] = v0;
      xs[o+128][i] = v1;
    }
    __syncthreads();
    float wA0[WT], wA1[WT], wB0[WT], wB1[WT];
#pragma unroll
    for(int q=0;q<WT/4;q++){
      ((float4*)wA0)[q] = ((const float4*)(wo0 + (size_t)cc*KW))[q];
      ((float4*)wA1)[q] = ((const float4*)(wo1 + (size_t)cc*KW))[q];
    }
    for(int c0=0; c0<256; c0+=2*CT){
#pragma unroll
      for(int q=0;q<WT/4;q++){
        ((float4*)wB0)[q] = ((const float4*)(wo0 + (size_t)(cc+c0+CT)*KW))[q];
        ((float4*)wB1)[q] = ((const float4*)(wo1 + (size_t)(cc+c0+CT)*KW))[q];
      }
#pragma unroll
      for(int c=0;c<CT;c++){
        float win[RPAD];
#pragma unroll
        for(int q=0;q<RPAD/4;q++) ((float4*)win)[q] = ((const float4*)&xs[c0+c][0])[q];
        if(KW==3){
          float a0=wA0[c*3], a1=wA0[c*3+1], a2=wA0[c*3+2];
          float b0=wA1[c*3], b1=wA1[c*3+1], b2=wA1[c*3+2];
#pragma unroll
          for(int i=0;i<PT;i++){
            acc0[i] = fmaf(a2,win[i+2],fmaf(a1,win[i+1],fmaf(a0,win[i],acc0[i])));
            acc1[i] = fmaf(b2,win[i+2],fmaf(b1,win[i+1],fmaf(b0,win[i],acc1[i])));
          }
        } else {
          float a0=wA0[c], b0=wA1[c];
#pragma unroll
          for(int i=0;i<PT;i++){
            acc0[i] = fmaf(a0,win[i],acc0[i]);
            acc1[i] = fmaf(b0,win[i],acc1[i]);
          }
        }
      }
      int cn = (c0+2*CT < 256)? (cc+c0+2*CT) : cc;   // clamp: dummy reload on last pair
#pragma unroll
      for(int q=0;q<WT/4;q++){
        ((float4*)wA0)[q] = ((const float4*)(wo0 + (size_t)cn*KW))[q];
        ((float4*)wA1)[q] = ((const float4*)(wo1 + (size_t)cn*KW))[q];
      }
#pragma unroll
      for(int c=0;c<CT;c++){
        float win[RPAD];
#pragma unroll
        for(int q=0;q<RPAD/4;q++) ((float4*)win)[q] = ((const float4*)&xs[c0+CT+c][0])[q];
        if(KW==3){
          float a0=wB0[c*3], a1=wB0[c*3+1], a2=wB0[c*3+2];
          float b0=wB1[c*3], b1=wB1[c*3+1], b2=wB1[c*3+2];
#pragma unroll
          for(int i=0;i<PT;i++){
            acc0[i] = fmaf(a2,win[i+2],fmaf(a1,win[i+1],fmaf(a0,win[i],acc0[i])));
            acc1[i] = fmaf(b2,win[i+2],fmaf(b1,win[i+1],fmaf(b0,win[i],acc1[i])));
          }
        } else {
          float a0=wB0[c], b0=wB1[c];
#pragma unroll
          for(int i=0;i<PT;i++){
            acc0[i] = fmaf(a0,win[i],acc0[i]);
            acc1[i] = fmaf(b0,win[i],acc1[i]);
          }
        }
      }
    }
  }
#pragma unroll
  for(int i=0;i<PT;i++){
    int p = p0+i;
    if(p<P){
      float v0 = acc0[i], v1 = acc1[i];
      if(RELU){ v0 = fmaxf(v0,0.f); v1 = fmaxf(v1,0.f); }
      out[((size_t)b*P+p)*256 + o] = v0;
      out[((size_t)b*P+p)*256 + o + 128] = v1;
    }
  }
}

// ---------------- row squared norms ----------------
__global__ __launch_bounds__(256) void norm2_k(const float* __restrict__ x, float* __restrict__ o, int rows){
  int r = blockIdx.x*4 + (threadIdx.x>>6);
  int lane = threadIdx.x & 63;
  if(r>=rows) return;
  float4 v = ((const float4*)(x + (size_t)r*256))[lane];
  float s = v.x*v.x + v.y*v.y + v.z*v.z + v.w*v.w;
  s = wsum(s);
  if(lane==0) o[r] = s;
}

// ---------------- score = -sqrt(max(||f||^2+||t||^2-2 f.t, 1e-12)) ----------------
__global__ __launch_bounds__(256) void score_gemm(const float* __restrict__ F, const float* __restrict__ Tn,
    const float* __restrict__ fn2, const float* __restrict__ tn2, float* __restrict__ outp){
  constexpr int KC = 32;
  __shared__ __align__(16) float As[KC][68];
  __shared__ __align__(16) float Bs[KC][68];
  const int b = blockIdx.z;
  const int t0 = blockIdx.y*64, s0 = blockIdx.x*64;
  const int tid = threadIdx.x, tx = tid&15, ty = tid>>4;
  const float* Fb = F  + (size_t)b*TF*256;
  const float* Tb = Tn + (size_t)b*TT*256;
  float acc[4][4] = {};
  const int lk = tid & 31, lt0 = (tid>>5)*8;
  for(int k0=0;k0<256;k0+=KC){
    __syncthreads();
#pragma unroll
    for(int i=0;i<8;i++){
      int t = t0 + lt0 + i;
      As[lk][lt0+i] = (t<TF)? Fb[(size_t)t*256 + k0 + lk] : 0.f;
      int s = s0 + lt0 + i;
      Bs[lk][lt0+i] = (s<TT)? Tb[(size_t)s*256 + k0 + lk] : 0.f;
    }
    __syncthreads();
#pragma unroll
    for(int k=0;k<KC;k++){
      float a0[4], b0[4];
      *(float4*)a0 = *(const float4*)&As[k][ty*4];
      *(float4*)b0 = *(const float4*)&Bs[k][tx*4];
#pragma unroll
      for(int i=0;i<4;i++)
#pragma unroll
        for(int j=0;j<4;j++) acc[i][j] = fmaf(a0[i], b0[j], acc[i][j]);
    }
  }
#pragma unroll
  for(int i=0;i<4;i++){
    int t = t0 + ty*4 + i;
    if(t<TF){
      float fn = fn2[b*TF + t];
#pragma unroll
      for(int j=0;j<4;j++){
        int s = s0 + tx*4 + j;
        if(s<TT){
          float d2 = fn + tn2[b*TT + s] - 2.f*acc[i][j];
          outp[((size_t)b*TF + t)*TT + s] = -sqrtf(fmaxf(d2, 1e-12f));
        }
      }
    }
  }
}

// ---------------- per-row log_softmax + prior, and Z2 = logsumexp([BLANK, row]) ----------------
__global__ __launch_bounds__(128) void softmax_prior_k(float* __restrict__ logp,
    const double* __restrict__ rowA, const double* __restrict__ colA, const double* __restrict__ sA,
    float* __restrict__ Z2){
  const int row = blockIdx.x;           // b*TF + t0
  const int t0 = row % TF;
  float* rp = logp + (size_t)row*TT;
  const int tid = threadIdx.x;
  __shared__ float sh2[2];
  float v[4]; int ix[4];
#pragma unroll
  for(int i=0;i<4;i++){ ix[i] = tid + i*128; v[i] = (ix[i]<TT)? rp[ix[i]] : BIGN; }
  float m = fmaxf(fmaxf(v[0],v[1]),fmaxf(v[2],v[3]));
#pragma unroll
  for(int o=32;o;o>>=1) m = fmaxf(m, __shfl_xor(m,o,64));
  if((tid&63)==0) sh2[tid>>6] = m;
  __syncthreads();
  m = fmaxf(sh2[0], sh2[1]);
  float s = 0.f;
#pragma unroll
  for(int i=0;i<4;i++) if(ix[i]<TT) s += __expf(v[i]-m);
  s = wsum(s);
  __syncthreads();
  if((tid&63)==0) sh2[tid>>6] = s;
  __syncthreads();
  s = sh2[0] + sh2[1];
  const float lse = m + __logf(s);
  const double rA = rowA[t0];
  float f[4]; float m2 = BIGN;
#pragma unroll
  for(int i=0;i<4;i++){
    if(ix[i]<TT){
      float pr = (float)(colA[ix[i]] + sA[t0+ix[i]] + rA);
      f[i] = (v[i]-lse) + pr;
      rp[ix[i]] = f[i];
      m2 = fmaxf(m2, f[i]);
    } else f[i] = BIGN;
  }
#pragma unroll
  for(int o=32;o;o>>=1) m2 = fmaxf(m2, __shfl_xor(m2,o,64));
  __syncthreads();
  if((tid&63)==0) sh2[tid>>6] = m2;
  __syncthreads();
  m2 = fmaxf(fmaxf(sh2[0],sh2[1]), -1.0f);
  float s2 = (tid==0)? __expf(-1.0f - m2) : 0.f;
#pragma unroll
  for(int i=0;i<4;i++) if(ix[i]<TT) s2 += __expf(f[i]-m2);
  s2 = wsum(s2);
  __syncthreads();
  if((tid&63)==0) sh2[tid>>6] = s2;
  __syncthreads();
  if(tid==0) Z2[row] = m2 + __logf(sh2[0]+sh2[1]);
}

// ---------------- scans ----------------
// CTC blocks (0..15): bidirectional, two waves (t=0..999 fwd, t=1999..1000 reversed lattice),
//   seam-combined via LDS. MAS blocks (16..31): wave 0, full 2000 steps, cmp bits 1B/lane/step.
#define LCTC_STEP(E) { \
  float n1 = __shfl_up(a[13], 1); \
  if(lane==0) n1 = BIGN; \
  a[13] = lse3b(a[13], a[12], a[11]) + (E)[6]; \
  a[12] = lse2b(a[12], a[11]) + EBL; \
  a[11] = lse3b(a[11], a[10], a[9]) + (E)[5]; \
  a[10] = lse2b(a[10], a[9]) + EBL; \
  a[9]  = lse3b(a[9],  a[8],  a[7]) + (E)[4]; \
  a[8]  = lse2b(a[8],  a[7]) + EBL; \
  a[7]  = lse3b(a[7],  a[6],  a[5]) + (E)[3]; \
  a[6]  = lse2b(a[6],  a[5]) + EBL; \
  a[5]  = lse3b(a[5],  a[4],  a[3]) + (E)[2]; \
  a[4]  = lse2b(a[4],  a[3]) + EBL; \
  a[3]  = lse3b(a[3],  a[2],  a[1]) + (E)[1]; \
  a[2]  = lse2b(a[2],  a[1]) + EBL; \
  a[1]  = lse3b(a[1],  a[0],  n1) + (E)[0]; \
  a[0]  = lse2b(a[0],  n1) + EBL; }

// step index K in 1..999; row = dir? TF-1-K : K
#define CPREF(E, K) { int kk=(K); if(kk>999) kk=999; int row = dir? (TF-1-kk) : kk; \
  const float* rpp = lp + (size_t)row*TT; \
  (E)[0]=rpp[jc[0]]*IL2; (E)[1]=rpp[jc[1]]*IL2; (E)[2]=rpp[jc[2]]*IL2; (E)[3]=rpp[jc[3]]*IL2; \
  (E)[4]=rpp[jc[4]]*IL2; (E)[5]=rpp[jc[5]]*IL2; (E)[6]=rpp[jc[6]]*IL2; }

#define MAS_STEP(E, TIDX) { \
  float n1 = __shfl_up(q[6],1); \
  u32 byte = 0; \
  if(lane>0 && n1 >= q[0]) byte |= 1u; \
  if(q[0] >= q[1]) byte |= 2u; \
  if(q[1] >= q[2]) byte |= 4u; \
  if(q[2] >= q[3]) byte |= 8u; \
  if(q[3] >= q[4]) byte |= 16u; \
  if(q[4] >= q[5]) byte |= 32u; \
  if(q[5] >= q[6]) byte |= 64u; \
  cb[(size_t)((TIDX)-1)*64 + lane] = (unsigned char)byte; \
  q[6] = fmaxf(q[6], q[5]) + (E)[6]; \
  q[5] = fmaxf(q[5], q[4]) + (E)[5]; \
  q[4] = fmaxf(q[4], q[3]) + (E)[4]; \
  q[3] = fmaxf(q[3], q[2]) + (E)[3]; \
  q[2] = fmaxf(q[2], q[1]) + (E)[2]; \
  q[1] = fmaxf(q[1], q[0]) + (E)[1]; \
  q[0] = fmaxf(q[0], (lane>0)? n1 : BIGN) + (E)[0]; }

#define MPREF(E, ROW) { int rr=(ROW); rr = (rr>TF-1)? (TF-1) : rr; const float* rpp = lp + (size_t)rr*TT; \
  (E)[0]=rpp[jc[0]]; (E)[1]=rpp[jc[1]]; (E)[2]=rpp[jc[2]]; (E)[3]=rpp[jc[3]]; \
  (E)[4]=rpp[jc[4]]; (E)[5]=rpp[jc[5]]; (E)[6]=rpp[jc[6]]; }

__global__ __launch_bounds__(128) __attribute__((amdgpu_waves_per_eu(1,1)))
void scan_k(const float* __restrict__ logp,
    const float* __restrict__ Z2, unsigned char* __restrict__ cmpb, float* __restrict__ nll){
  const int lane = threadIdx.x & 63;
  const int wave = threadIdx.x >> 6;
  constexpr float IL2 = 1.4426950408889634f;   // 1/ln2
  constexpr float L2  = 0.6931471805599453f;   // ln2
  if(blockIdx.x < NB){
    const int b = blockIdx.x;
    const float* lp = logp + (size_t)b*TF*TT;
    __shared__ float af[801], ag[801];
    const int dir = wave;                      // 0: t=0..999 ; 1: t=1999..1000 (state w=800-s)
    double zs = 0.0;
    if(wave==0){
      for(int t=lane; t<TF; t+=64) zs += (double)Z2[b*TF + t];
#pragma unroll
      for(int o=32;o;o>>=1) zs += __shfl_xor(zs, o, 64);
    }
    int jc[7];
#pragma unroll
    for(int i=0;i<7;i++){ int j = 7*lane + i; j = (j < TT)? j : (TT-1); jc[i] = dir? (TT-1-j) : j; }
    float a[14];
#pragma unroll
    for(int i=0;i<14;i++) a[i] = BIGN;
    if(lane==0){
      a[0] = -1.0f*IL2;                                           // blank end-state (s=0 / s=800)
      a[1] = (dir? lp[(size_t)(TF-1)*TT + (TT-1)] : lp[0]) * IL2; // emit end-state (s=1 / s=799)
    }
    const float EBL = -1.0f*IL2;
    float e0[7],e1[7],e2[7],e3[7],e4[7],e5[7],e6[7],e7[7];
    CPREF(e0,1); CPREF(e1,2); CPREF(e2,3); CPREF(e3,4);
    CPREF(e4,5); CPREF(e5,6); CPREF(e6,7); CPREF(e7,8);
    int k = 1;
    for(; k + 8 <= 993; k += 8){
      LCTC_STEP(e0); CPREF(e0, k+8);
      LCTC_STEP(e1); CPREF(e1, k+9);
      LCTC_STEP(e2); CPREF(e2, k+10);
      LCTC_STEP(e3); CPREF(e3, k+11);
      LCTC_STEP(e4); CPREF(e4, k+12);
      LCTC_STEP(e5); CPREF(e5, k+13);
      LCTC_STEP(e6); CPREF(e6, k+14);
      LCTC_STEP(e7); CPREF(e7, k+15);
    }
    for(; k<=999; k++){          // tail, direct loads
      float P[7];
      CPREF(P, k);
      LCTC_STEP(P);
    }
    float* dst = wave? ag : af;
#pragma unroll
    for(int i=0;i<14;i++){ int s = 14*lane+i; if(s<=800) dst[s] = a[i]; }
    __syncthreads();
    if(wave==0){
      float acc = BIGN;
#pragma unroll
      for(int i=0;i<14;i++){
        int s = 14*lane+i;
        if(s<=800){
          float x0 = af[s];
          float x1 = (s>=1)? af[s-1] : BIGN;
          float x2 = ((s&1) && s>=3)? af[s-2] : BIGN;
          float A1 = lse3b(x0,x1,x2);                 // one transition, no emission
          acc = lse2b(acc, A1 + ag[800-s]);
        }
      }
#pragma unroll
      for(int o=32;o;o>>=1) acc = lse2b(acc, __shfl_xor(acc,o,64));
      if(lane==0) nll[b] = -((acc*L2) - (float)zs);
    }
  } else {
    if(wave) return;
    const int b = blockIdx.x - NB;
    const float* lp = logp + (size_t)b*TF*TT;
    unsigned char* cb = cmpb + (size_t)b*TF*64;
    int jc[7];
#pragma unroll
    for(int i=0;i<7;i++){ int j = 7*lane + i; jc[i] = (j < TT)? j : (TT-1); }
    float q[7];
#pragma unroll
    for(int i=0;i<7;i++) q[i] = BIGN;
    if(lane==0) q[0] = lp[0];
    float e0[7],e1[7],e2[7],e3[7];
    MPREF(e0,1); MPREF(e1,2); MPREF(e2,3); MPREF(e3,4);
    int t0 = 1;
    for(; t0 + 4 <= TF; t0 += 4){
      MAS_STEP(e0, t0);   MPREF(e0, t0+4);
      MAS_STEP(e1, t0+1); MPREF(e1, t0+5);
      MAS_STEP(e2, t0+2); MPREF(e2, t0+6);
      MAS_STEP(e3, t0+3); MPREF(e3, t0+7);
    }
    for(; t0<TF; t0++){
      float P[7];
      MPREF(P, t0);
      MAS_STEP(P, t0);
    }
    // final row of cmp bits (row TF-1)
    {
      float n1 = __shfl_up(q[6],1);
      u32 byte = 0;
      if(lane>0 && n1 >= q[0]) byte |= 1u;
      if(q[0] >= q[1]) byte |= 2u;
      if(q[1] >= q[2]) byte |= 4u;
      if(q[2] >= q[3]) byte |= 8u;
      if(q[3] >= q[4]) byte |= 16u;
      if(q[4] >= q[5]) byte |= 32u;
      if(q[5] >= q[6]) byte |= 64u;
      cb[(size_t)(TF-1)*64 + lane] = (unsigned char)byte;
    }
  }
}

// ---------------- MAS backtrack + ds + gather ----------------
__global__ __launch_bounds__(256) void masback_k(const unsigned char* __restrict__ cmpb,
    const float* __restrict__ logp, float* __restrict__ ds, float* __restrict__ gsum){
  const int b = blockIdx.x;
  const unsigned char* cb = cmpb + (size_t)b*TF*64;
  __shared__ unsigned char bits[500*64];
  __shared__ short Ash[TF];
  __shared__ int cnt[TT];
  __shared__ float ps[4];
  int a = TT-1;
  for(int ch=3; ch>=0; ch--){
    const int tlo = ch*500;
    __syncthreads();
    for(int i=threadIdx.x;i<8000;i+=256) ((u32*)bits)[i] = ((const u32*)(cb + (size_t)tlo*64))[i];
    __syncthreads();
    if(threadIdx.x==0){
      int thi = tlo + 499;
      if(ch==3){ Ash[TF-1] = (short)(TT-1); thi = TF-2; }
      for(int t=thi;t>=tlo;t--){
        if(a > 0){
          unsigned char w = bits[(t-tlo)*64 + a/7];
          a -= (int)((w >> (a%7)) & 1u);
        }
        Ash[t] = (short)a;
      }
    }
  }
  __syncthreads();
  for(int i=threadIdx.x;i<TT;i+=256) cnt[i]=0;
  __syncthreads();
  float part = 0.f;
  const float* lp = logp + (size_t)b*TF*TT;
  for(int t=threadIdx.x;t<TF;t+=256){
    int at = Ash[t];
    atomicAdd(&cnt[at], 1);
    part += lp[(size_t)t*TT + at];
  }
  __syncthreads();
  for(int i=threadIdx.x;i<TT;i+=256) ds[(size_t)b*TT + i] = (float)cnt[i];
  part = wsum(part);
  if((threadIdx.x&63)==0) ps[threadIdx.x>>6] = part;
  __syncthreads();
  if(threadIdx.x==0) gsum[b] = ps[0]+ps[1]+ps[2]+ps[3];
}

__global__ void final_k(const float* __restrict__ nll, const float* __restrict__ gsum, float* __restrict__ out){
  if(threadIdx.x==0 && blockIdx.x==0){
    float fs=0.f, bs=0.f;
    for(int b=0;b<NB;b++){ fs += nll[b] / (float)TT; bs += gsum[b] / (float)TF; }
    out[6400] = -(bs / (float)NB);   // bin_loss
    out[6401] = fs / (float)NB;      // forwardsum_loss
  }
}

extern "C" void kernel_launch(void* const* d_in, const int* in_sizes, int n_in,
                              void* d_out, int out_size, void* d_ws, size_t ws_size,
                              hipStream_t stream){
  const float* speech = (const float*)d_in[0];
  const float* txt    = (const float*)d_in[1];
  const float* tw1 = (const float*)d_in[4];
  const float* tb1 = (const float*)d_in[5];
  const float* tw2 = (const float*)d_in[6];
  const float* tb2 = (const float*)d_in[7];
  const float* fw1 = (const float*)d_in[8];
  const float* fb1 = (const float*)d_in[9];
  const float* fw2 = (const float*)d_in[10];
  const float* fb2 = (const float*)d_in[11];
  const float* fw3 = (const float*)d_in[12];
  const float* fb3 = (const float*)d_in[13];
  float* out  = (float*)d_out;
  float* ds   = out;                 // (16,400)
  float* logp = out + 6402;          // (16,2000,400)
  char* ws = (char*)d_ws;
  double* lgt  = (double*)(ws + 0);
  double* rowA = (double*)(ws + 20480);
  double* colA = (double*)(ws + 36864);
  double* sA   = (double*)(ws + 40960);
  float*  nll  = (float*)(ws + 61440);
  float*  gsum = (float*)(ws + 61696);
  float*  Z2   = (float*)(ws + 65536);
  float*  fn2  = (float*)(ws + 196608);
  float*  tn2  = (float*)(ws + 327680);
  unsigned char* cmpb = (unsigned char*)(ws + 360448);
  float*  tenc = (float*)(ws + 2408448);
  float*  f1   = (float*)(ws + 8962048);
  float*  t1   = f1;      // t1 dead before f1 (f-conv1 out) is written
  float*  f2   = logp;    // f-conv2 intermediate; dead before scores written
  if(ws_size < 41730048) return;

  k_lgt  <<<10,256,0,stream>>>(lgt);
  k_terms<<<10,256,0,stream>>>(lgt,rowA,colA,sA);

  conv_k<256,3,true ><<<dim3(13,NB),128,0,stream>>>(txt, tw1, tb1, t1, TT);
  conv_k<256,1,false><<<dim3(13,NB),128,0,stream>>>(t1, tw2, tb2, tenc, TT);
  conv_k<512,3,true ><<<dim3(63,NB),128,0,stream>>>(speech, fw1, fb1, f1, TF);
  conv_k<256,3,true ><<<dim3(63,NB),128,0,stream>>>(f1, fw2, fb2, f2, TF);
  conv_k<256,1,false><<<dim3(63,NB),128,0,stream>>>(f2, fw3, fb3, f1, TF);

  norm2_k<<<(NB*TF)/4,256,0,stream>>>(f1, fn2, NB*TF);
  norm2_k<<<(NB*TT)/4,256,0,stream>>>(tenc, tn2, NB*TT);

  score_gemm<<<dim3(7,32,NB),256,0,stream>>>(f1, tenc, fn2, tn2, logp);
  softmax_prior_k<<<NB*TF,128,0,stream>>>(logp, rowA, colA, sA, Z2);

  scan_k<<<2*NB,128,0,stream>>>(logp, Z2, cmpb, nll);
  masback_k<<<NB,256,0,stream>>>(cmpb, logp, ds, gsum);
  final_k<<<1,64,0,stream>>>(nll, gsum, out);
}

// Round 10
// 1570.553 us; speedup vs baseline: 1.1266x; 1.1266x over previous
//
#include <hip/hip_runtime.h>
#include <math.h>

typedef unsigned int u32;
typedef unsigned long long u64;

#define BIGN (-1e30f)

static constexpr int NB = 16;     // batch
static constexpr int TF = 2000;   // T_FEATS
static constexpr int TT = 400;    // T_TEXT

__device__ __forceinline__ float wsum(float v){
#pragma unroll
  for(int o=32;o;o>>=1) v += __shfl_xor(v,o,64);
  return v;
}
// raw HW transcendentals: v_exp_f32 (2^x), v_log_f32 (log2 x)
__device__ __forceinline__ float EXP2(float x){ return __builtin_amdgcn_exp2f(x); }
__device__ __forceinline__ float LOG2(float x){ return __builtin_amdgcn_logf(x); }

// log-sum-exp in BASE-2 domain
__device__ __forceinline__ float lse2b(float x, float y){
  float m = fmaxf(x,y);
  return m + LOG2(1.0f + EXP2(-fabsf(x-y)));
}
__device__ __forceinline__ float lse3b(float x, float y, float z){
  float mx = fmaxf(fmaxf(x,y),z);
  float md = __builtin_amdgcn_fmed3f(x,y,z);
  float mn = fminf(fminf(x,y),z);
  return mx + LOG2(1.0f + EXP2(md-mx) + EXP2(mn-mx));
}

// ---------------- gammaln tables ----------------
__global__ void k_lgt(double* lgt){
  int m = blockIdx.x*blockDim.x + threadIdx.x;
  if(m < 2432) lgt[m] = (m>=1)? lgamma((double)m) : 0.0;
}
__global__ void k_terms(const double* __restrict__ lgt, double* rowA, double* colA, double* sA){
  int i = blockIdx.x*blockDim.x + threadIdx.x;
  if(i < TF)   rowA[i] = -lgt[2401] - lgt[i+1] - lgt[2000-i] + lgt[2001];
  if(i < TT)   colA[i] =  lgt[401]  - lgt[i+2] - lgt[400-i];
  if(i < 2399) sA[i]   =  lgt[i+2]  + lgt[2399-i];
}

// ---------------- conv1d (cross-correlation, pad=(KW-1)/2), OIH weights ----------------
// 128 threads, 2 output channels per thread (o, o+128): each LDS window read feeds 2x the FMAs.
// waves_per_eu(1,1): full VGPR budget (Round-9 lesson: (128,2) capped at 128 VGPR -> 883MB spill).
template<int CIN, int KW, bool RELU>
__global__ __launch_bounds__(128) __attribute__((amdgpu_waves_per_eu(1,1)))
void conv_k(const float* __restrict__ in, const float* __restrict__ w,
    const float* __restrict__ bias, float* __restrict__ out, int P){
  constexpr int PT = 32;
  constexpr int ROWS = PT + KW - 1;
  constexpr int RPAD = (ROWS + 3) & ~3;
  constexpr int CT = 8;
  constexpr int WT = CT*KW;            // 24 (KW3) or 8 (KW1)
  __shared__ __align__(16) float xs[256][RPAD];
  const int b = blockIdx.y;
  const int p0 = blockIdx.x * PT;
  const int o = threadIdx.x;           // 0..127; outputs o and o+128
  float acc0[PT], acc1[PT];
  const float bo0 = bias[o], bo1 = bias[o+128];
#pragma unroll
  for(int i=0;i<PT;i++){ acc0[i] = bo0; acc1[i] = bo1; }
  const float* inb = in + (size_t)b * P * CIN;
  const float* wo0 = w + (size_t)o * CIN * KW;
  const float* wo1 = w + (size_t)(o+128) * CIN * KW;
  for(int cc=0; cc<CIN; cc+=256){
    __syncthreads();
    for(int i=0;i<ROWS;i++){
      int p = p0 + i - (KW==3 ? 1 : 0);
      float v0 = 0.f, v1 = 0.f;
      if(p>=0 && p<P){
        v0 = inb[(size_t)p*CIN + cc + o];
        v1 = inb[(size_t)p*CIN + cc + o + 128];
      }
      xs[o][i] = v0;
      xs[o+128][i] = v1;
    }
    __syncthreads();
    float wA0[WT], wA1[WT], wB0[WT], wB1[WT];
#pragma unroll
    for(int q=0;q<WT/4;q++){
      ((float4*)wA0)[q] = ((const float4*)(wo0 + (size_t)cc*KW))[q];
      ((float4*)wA1)[q] = ((const float4*)(wo1 + (size_t)cc*KW))[q];
    }
    for(int c0=0; c0<256; c0+=2*CT){
#pragma unroll
      for(int q=0;q<WT/4;q++){
        ((float4*)wB0)[q] = ((const float4*)(wo0 + (size_t)(cc+c0+CT)*KW))[q];
        ((float4*)wB1)[q] = ((const float4*)(wo1 + (size_t)(cc+c0+CT)*KW))[q];
      }
#pragma unroll
      for(int c=0;c<CT;c++){
        float win[RPAD];
#pragma unroll
        for(int q=0;q<RPAD/4;q++) ((float4*)win)[q] = ((const float4*)&xs[c0+c][0])[q];
        if(KW==3){
          float a0=wA0[c*3], a1=wA0[c*3+1], a2=wA0[c*3+2];
          float b0=wA1[c*3], b1=wA1[c*3+1], b2=wA1[c*3+2];
#pragma unroll
          for(int i=0;i<PT;i++){
            acc0[i] = fmaf(a2,win[i+2],fmaf(a1,win[i+1],fmaf(a0,win[i],acc0[i])));
            acc1[i] = fmaf(b2,win[i+2],fmaf(b1,win[i+1],fmaf(b0,win[i],acc1[i])));
          }
        } else {
          float a0=wA0[c], b0=wA1[c];
#pragma unroll
          for(int i=0;i<PT;i++){
            acc0[i] = fmaf(a0,win[i],acc0[i]);
            acc1[i] = fmaf(b0,win[i],acc1[i]);
          }
        }
      }
      int cn = (c0+2*CT < 256)? (cc+c0+2*CT) : cc;   // clamp: dummy reload on last pair
#pragma unroll
      for(int q=0;q<WT/4;q++){
        ((float4*)wA0)[q] = ((const float4*)(wo0 + (size_t)cn*KW))[q];
        ((float4*)wA1)[q] = ((const float4*)(wo1 + (size_t)cn*KW))[q];
      }
#pragma unroll
      for(int c=0;c<CT;c++){
        float win[RPAD];
#pragma unroll
        for(int q=0;q<RPAD/4;q++) ((float4*)win)[q] = ((const float4*)&xs[c0+CT+c][0])[q];
        if(KW==3){
          float a0=wB0[c*3], a1=wB0[c*3+1], a2=wB0[c*3+2];
          float b0=wB1[c*3], b1=wB1[c*3+1], b2=wB1[c*3+2];
#pragma unroll
          for(int i=0;i<PT;i++){
            acc0[i] = fmaf(a2,win[i+2],fmaf(a1,win[i+1],fmaf(a0,win[i],acc0[i])));
            acc1[i] = fmaf(b2,win[i+2],fmaf(b1,win[i+1],fmaf(b0,win[i],acc1[i])));
          }
        } else {
          float a0=wB0[c], b0=wB1[c];
#pragma unroll
          for(int i=0;i<PT;i++){
            acc0[i] = fmaf(a0,win[i],acc0[i]);
            acc1[i] = fmaf(b0,win[i],acc1[i]);
          }
        }
      }
    }
  }
#pragma unroll
  for(int i=0;i<PT;i++){
    int p = p0+i;
    if(p<P){
      float v0 = acc0[i], v1 = acc1[i];
      if(RELU){ v0 = fmaxf(v0,0.f); v1 = fmaxf(v1,0.f); }
      out[((size_t)b*P+p)*256 + o] = v0;
      out[((size_t)b*P+p)*256 + o + 128] = v1;
    }
  }
}

// ---------------- row squared norms ----------------
__global__ __launch_bounds__(256) void norm2_k(const float* __restrict__ x, float* __restrict__ o, int rows){
  int r = blockIdx.x*4 + (threadIdx.x>>6);
  int lane = threadIdx.x & 63;
  if(r>=rows) return;
  float4 v = ((const float4*)(x + (size_t)r*256))[lane];
  float s = v.x*v.x + v.y*v.y + v.z*v.z + v.w*v.w;
  s = wsum(s);
  if(lane==0) o[r] = s;
}

// ---------------- score = -sqrt(max(||f||^2+||t||^2-2 f.t, 1e-12)) ----------------
__global__ __launch_bounds__(256) void score_gemm(const float* __restrict__ F, const float* __restrict__ Tn,
    const float* __restrict__ fn2, const float* __restrict__ tn2, float* __restrict__ outp){
  constexpr int KC = 32;
  __shared__ __align__(16) float As[KC][68];
  __shared__ __align__(16) float Bs[KC][68];
  const int b = blockIdx.z;
  const int t0 = blockIdx.y*64, s0 = blockIdx.x*64;
  const int tid = threadIdx.x, tx = tid&15, ty = tid>>4;
  const float* Fb = F  + (size_t)b*TF*256;
  const float* Tb = Tn + (size_t)b*TT*256;
  float acc[4][4] = {};
  const int lk = tid & 31, lt0 = (tid>>5)*8;
  for(int k0=0;k0<256;k0+=KC){
    __syncthreads();
#pragma unroll
    for(int i=0;i<8;i++){
      int t = t0 + lt0 + i;
      As[lk][lt0+i] = (t<TF)? Fb[(size_t)t*256 + k0 + lk] : 0.f;
      int s = s0 + lt0 + i;
      Bs[lk][lt0+i] = (s<TT)? Tb[(size_t)s*256 + k0 + lk] : 0.f;
    }
    __syncthreads();
#pragma unroll
    for(int k=0;k<KC;k++){
      float a0[4], b0[4];
      *(float4*)a0 = *(const float4*)&As[k][ty*4];
      *(float4*)b0 = *(const float4*)&Bs[k][tx*4];
#pragma unroll
      for(int i=0;i<4;i++)
#pragma unroll
        for(int j=0;j<4;j++) acc[i][j] = fmaf(a0[i], b0[j], acc[i][j]);
    }
  }
#pragma unroll
  for(int i=0;i<4;i++){
    int t = t0 + ty*4 + i;
    if(t<TF){
      float fn = fn2[b*TF + t];
#pragma unroll
      for(int j=0;j<4;j++){
        int s = s0 + tx*4 + j;
        if(s<TT){
          float d2 = fn + tn2[b*TT + s] - 2.f*acc[i][j];
          outp[((size_t)b*TF + t)*TT + s] = -sqrtf(fmaxf(d2, 1e-12f));
        }
      }
    }
  }
}

// ---------------- per-row log_softmax + prior, and Z2 = logsumexp([BLANK, row]) ----------------
__global__ __launch_bounds__(128) void softmax_prior_k(float* __restrict__ logp,
    const double* __restrict__ rowA, const double* __restrict__ colA, const double* __restrict__ sA,
    float* __restrict__ Z2){
  const int row = blockIdx.x;           // b*TF + t0
  const int t0 = row % TF;
  float* rp = logp + (size_t)row*TT;
  const int tid = threadIdx.x;
  __shared__ float sh2[2];
  float v[4]; int ix[4];
#pragma unroll
  for(int i=0;i<4;i++){ ix[i] = tid + i*128; v[i] = (ix[i]<TT)? rp[ix[i]] : BIGN; }
  float m = fmaxf(fmaxf(v[0],v[1]),fmaxf(v[2],v[3]));
#pragma unroll
  for(int o=32;o;o>>=1) m = fmaxf(m, __shfl_xor(m,o,64));
  if((tid&63)==0) sh2[tid>>6] = m;
  __syncthreads();
  m = fmaxf(sh2[0], sh2[1]);
  float s = 0.f;
#pragma unroll
  for(int i=0;i<4;i++) if(ix[i]<TT) s += __expf(v[i]-m);
  s = wsum(s);
  __syncthreads();
  if((tid&63)==0) sh2[tid>>6] = s;
  __syncthreads();
  s = sh2[0] + sh2[1];
  const float lse = m + __logf(s);
  const double rA = rowA[t0];
  float f[4]; float m2 = BIGN;
#pragma unroll
  for(int i=0;i<4;i++){
    if(ix[i]<TT){
      float pr = (float)(colA[ix[i]] + sA[t0+ix[i]] + rA);
      f[i] = (v[i]-lse) + pr;
      rp[ix[i]] = f[i];
      m2 = fmaxf(m2, f[i]);
    } else f[i] = BIGN;
  }
#pragma unroll
  for(int o=32;o;o>>=1) m2 = fmaxf(m2, __shfl_xor(m2,o,64));
  __syncthreads();
  if((tid&63)==0) sh2[tid>>6] = m2;
  __syncthreads();
  m2 = fmaxf(fmaxf(sh2[0],sh2[1]), -1.0f);
  float s2 = (tid==0)? __expf(-1.0f - m2) : 0.f;
#pragma unroll
  for(int i=0;i<4;i++) if(ix[i]<TT) s2 += __expf(f[i]-m2);
  s2 = wsum(s2);
  __syncthreads();
  if((tid&63)==0) sh2[tid>>6] = s2;
  __syncthreads();
  if(tid==0) Z2[row] = m2 + __logf(sh2[0]+sh2[1]);
}

// ---------------- scans ----------------
// CTC blocks (0..15): bidirectional, two waves (t=0..999 fwd, t=1999..1000 reversed lattice),
//   seam-combined via LDS. MAS blocks (16..31): wave 0, full 2000 steps, cmp bits 1B/lane/step.
#define LCTC_STEP(E) { \
  float n1 = __shfl_up(a[13], 1); \
  if(lane==0) n1 = BIGN; \
  a[13] = lse3b(a[13], a[12], a[11]) + (E)[6]; \
  a[12] = lse2b(a[12], a[11]) + EBL; \
  a[11] = lse3b(a[11], a[10], a[9]) + (E)[5]; \
  a[10] = lse2b(a[10], a[9]) + EBL; \
  a[9]  = lse3b(a[9],  a[8],  a[7]) + (E)[4]; \
  a[8]  = lse2b(a[8],  a[7]) + EBL; \
  a[7]  = lse3b(a[7],  a[6],  a[5]) + (E)[3]; \
  a[6]  = lse2b(a[6],  a[5]) + EBL; \
  a[5]  = lse3b(a[5],  a[4],  a[3]) + (E)[2]; \
  a[4]  = lse2b(a[4],  a[3]) + EBL; \
  a[3]  = lse3b(a[3],  a[2],  a[1]) + (E)[1]; \
  a[2]  = lse2b(a[2],  a[1]) + EBL; \
  a[1]  = lse3b(a[1],  a[0],  n1) + (E)[0]; \
  a[0]  = lse2b(a[0],  n1) + EBL; }

// step index K in 1..999; row = dir? TF-1-K : K
#define CPREF(E, K) { int kk=(K); if(kk>999) kk=999; int row = dir? (TF-1-kk) : kk; \
  const float* rpp = lp + (size_t)row*TT; \
  (E)[0]=rpp[jc[0]]*IL2; (E)[1]=rpp[jc[1]]*IL2; (E)[2]=rpp[jc[2]]*IL2; (E)[3]=rpp[jc[3]]*IL2; \
  (E)[4]=rpp[jc[4]]*IL2; (E)[5]=rpp[jc[5]]*IL2; (E)[6]=rpp[jc[6]]*IL2; }

#define MAS_STEP(E, TIDX) { \
  float n1 = __shfl_up(q[6],1); \
  u32 byte = 0; \
  if(lane>0 && n1 >= q[0]) byte |= 1u; \
  if(q[0] >= q[1]) byte |= 2u; \
  if(q[1] >= q[2]) byte |= 4u; \
  if(q[2] >= q[3]) byte |= 8u; \
  if(q[3] >= q[4]) byte |= 16u; \
  if(q[4] >= q[5]) byte |= 32u; \
  if(q[5] >= q[6]) byte |= 64u; \
  cb[(size_t)((TIDX)-1)*64 + lane] = (unsigned char)byte; \
  q[6] = fmaxf(q[6], q[5]) + (E)[6]; \
  q[5] = fmaxf(q[5], q[4]) + (E)[5]; \
  q[4] = fmaxf(q[4], q[3]) + (E)[4]; \
  q[3] = fmaxf(q[3], q[2]) + (E)[3]; \
  q[2] = fmaxf(q[2], q[1]) + (E)[2]; \
  q[1] = fmaxf(q[1], q[0]) + (E)[1]; \
  q[0] = fmaxf(q[0], (lane>0)? n1 : BIGN) + (E)[0]; }

#define MPREF(E, ROW) { int rr=(ROW); rr = (rr>TF-1)? (TF-1) : rr; const float* rpp = lp + (size_t)rr*TT; \
  (E)[0]=rpp[jc[0]]; (E)[1]=rpp[jc[1]]; (E)[2]=rpp[jc[2]]; (E)[3]=rpp[jc[3]]; \
  (E)[4]=rpp[jc[4]]; (E)[5]=rpp[jc[5]]; (E)[6]=rpp[jc[6]]; }

__global__ __launch_bounds__(128) __attribute__((amdgpu_waves_per_eu(1,1)))
void scan_k(const float* __restrict__ logp,
    const float* __restrict__ Z2, unsigned char* __restrict__ cmpb, float* __restrict__ nll){
  const int lane = threadIdx.x & 63;
  const int wave = threadIdx.x >> 6;
  constexpr float IL2 = 1.4426950408889634f;   // 1/ln2
  constexpr float L2  = 0.6931471805599453f;   // ln2
  if(blockIdx.x < NB){
    const int b = blockIdx.x;
    const float* lp = logp + (size_t)b*TF*TT;
    __shared__ float af[801], ag[801];
    const int dir = wave;                      // 0: t=0..999 ; 1: t=1999..1000 (state w=800-s)
    double zs = 0.0;
    if(wave==0){
      for(int t=lane; t<TF; t+=64) zs += (double)Z2[b*TF + t];
#pragma unroll
      for(int o=32;o;o>>=1) zs += __shfl_xor(zs, o, 64);
    }
    int jc[7];
#pragma unroll
    for(int i=0;i<7;i++){ int j = 7*lane + i; j = (j < TT)? j : (TT-1); jc[i] = dir? (TT-1-j) : j; }
    float a[14];
#pragma unroll
    for(int i=0;i<14;i++) a[i] = BIGN;
    if(lane==0){
      a[0] = -1.0f*IL2;                                           // blank end-state (s=0 / s=800)
      a[1] = (dir? lp[(size_t)(TF-1)*TT + (TT-1)] : lp[0]) * IL2; // emit end-state (s=1 / s=799)
    }
    const float EBL = -1.0f*IL2;
    float e0[7],e1[7],e2[7],e3[7],e4[7],e5[7],e6[7],e7[7];
    CPREF(e0,1); CPREF(e1,2); CPREF(e2,3); CPREF(e3,4);
    CPREF(e4,5); CPREF(e5,6); CPREF(e6,7); CPREF(e7,8);
    int k = 1;
    for(; k + 8 <= 993; k += 8){
      LCTC_STEP(e0); CPREF(e0, k+8);
      LCTC_STEP(e1); CPREF(e1, k+9);
      LCTC_STEP(e2); CPREF(e2, k+10);
      LCTC_STEP(e3); CPREF(e3, k+11);
      LCTC_STEP(e4); CPREF(e4, k+12);
      LCTC_STEP(e5); CPREF(e5, k+13);
      LCTC_STEP(e6); CPREF(e6, k+14);
      LCTC_STEP(e7); CPREF(e7, k+15);
    }
    for(; k<=999; k++){          // tail, direct loads
      float P[7];
      CPREF(P, k);
      LCTC_STEP(P);
    }
    float* dst = wave? ag : af;
#pragma unroll
    for(int i=0;i<14;i++){ int s = 14*lane+i; if(s<=800) dst[s] = a[i]; }
    __syncthreads();
    if(wave==0){
      float acc = BIGN;
#pragma unroll
      for(int i=0;i<14;i++){
        int s = 14*lane+i;
        if(s<=800){
          float x0 = af[s];
          float x1 = (s>=1)? af[s-1] : BIGN;
          float x2 = ((s&1) && s>=3)? af[s-2] : BIGN;
          float A1 = lse3b(x0,x1,x2);                 // one transition, no emission
          acc = lse2b(acc, A1 + ag[800-s]);
        }
      }
#pragma unroll
      for(int o=32;o;o>>=1) acc = lse2b(acc, __shfl_xor(acc,o,64));
      if(lane==0) nll[b] = -((acc*L2) - (float)zs);
    }
  } else {
    if(wave) return;
    const int b = blockIdx.x - NB;
    const float* lp = logp + (size_t)b*TF*TT;
    unsigned char* cb = cmpb + (size_t)b*TF*64;
    int jc[7];
#pragma unroll
    for(int i=0;i<7;i++){ int j = 7*lane + i; jc[i] = (j < TT)? j : (TT-1); }
    float q[7];
#pragma unroll
    for(int i=0;i<7;i++) q[i] = BIGN;
    if(lane==0) q[0] = lp[0];
    float e0[7],e1[7],e2[7],e3[7];
    MPREF(e0,1); MPREF(e1,2); MPREF(e2,3); MPREF(e3,4);
    int t0 = 1;
    for(; t0 + 4 <= TF; t0 += 4){
      MAS_STEP(e0, t0);   MPREF(e0, t0+4);
      MAS_STEP(e1, t0+1); MPREF(e1, t0+5);
      MAS_STEP(e2, t0+2); MPREF(e2, t0+6);
      MAS_STEP(e3, t0+3); MPREF(e3, t0+7);
    }
    for(; t0<TF; t0++){
      float P[7];
      MPREF(P, t0);
      MAS_STEP(P, t0);
    }
    // final row of cmp bits (row TF-1)
    {
      float n1 = __shfl_up(q[6],1);
      u32 byte = 0;
      if(lane>0 && n1 >= q[0]) byte |= 1u;
      if(q[0] >= q[1]) byte |= 2u;
      if(q[1] >= q[2]) byte |= 4u;
      if(q[2] >= q[3]) byte |= 8u;
      if(q[3] >= q[4]) byte |= 16u;
      if(q[4] >= q[5]) byte |= 32u;
      if(q[5] >= q[6]) byte |= 64u;
      cb[(size_t)(TF-1)*64 + lane] = (unsigned char)byte;
    }
  }
}

// ---------------- MAS backtrack + ds + gather ----------------
__global__ __launch_bounds__(256) void masback_k(const unsigned char* __restrict__ cmpb,
    const float* __restrict__ logp, float* __restrict__ ds, float* __restrict__ gsum){
  const int b = blockIdx.x;
  const unsigned char* cb = cmpb + (size_t)b*TF*64;
  __shared__ unsigned char bits[500*64];
  __shared__ short Ash[TF];
  __shared__ int cnt[TT];
  __shared__ float ps[4];
  int a = TT-1;
  for(int ch=3; ch>=0; ch--){
    const int tlo = ch*500;
    __syncthreads();
    for(int i=threadIdx.x;i<8000;i+=256) ((u32*)bits)[i] = ((const u32*)(cb + (size_t)tlo*64))[i];
    __syncthreads();
    if(threadIdx.x==0){
      int thi = tlo + 499;
      if(ch==3){ Ash[TF-1] = (short)(TT-1); thi = TF-2; }
      for(int t=thi;t>=tlo;t--){
        if(a > 0){
          unsigned char w = bits[(t-tlo)*64 + a/7];
          a -= (int)((w >> (a%7)) & 1u);
        }
        Ash[t] = (short)a;
      }
    }
  }
  __syncthreads();
  for(int i=threadIdx.x;i<TT;i+=256) cnt[i]=0;
  __syncthreads();
  float part = 0.f;
  const float* lp = logp + (size_t)b*TF*TT;
  for(int t=threadIdx.x;t<TF;t+=256){
    int at = Ash[t];
    atomicAdd(&cnt[at], 1);
    part += lp[(size_t)t*TT + at];
  }
  __syncthreads();
  for(int i=threadIdx.x;i<TT;i+=256) ds[(size_t)b*TT + i] = (float)cnt[i];
  part = wsum(part);
  if((threadIdx.x&63)==0) ps[threadIdx.x>>6] = part;
  __syncthreads();
  if(threadIdx.x==0) gsum[b] = ps[0]+ps[1]+ps[2]+ps[3];
}

__global__ void final_k(const float* __restrict__ nll, const float* __restrict__ gsum, float* __restrict__ out){
  if(threadIdx.x==0 && blockIdx.x==0){
    float fs=0.f, bs=0.f;
    for(int b=0;b<NB;b++){ fs += nll[b] / (float)TT; bs += gsum[b] / (float)TF; }
    out[6400] = -(bs / (float)NB);   // bin_loss
    out[6401] = fs / (float)NB;      // forwardsum_loss
  }
}

extern "C" void kernel_launch(void* const* d_in, const int* in_sizes, int n_in,
                              void* d_out, int out_size, void* d_ws, size_t ws_size,
                              hipStream_t stream){
  const float* speech = (const float*)d_in[0];
  const float* txt    = (const float*)d_in[1];
  const float* tw1 = (const float*)d_in[4];
  const float* tb1 = (const float*)d_in[5];
  const float* tw2 = (const float*)d_in[6];
  const float* tb2 = (const float*)d_in[7];
  const float* fw1 = (const float*)d_in[8];
  const float* fb1 = (const float*)d_in[9];
  const float* fw2 = (const float*)d_in[10];
  const float* fb2 = (const float*)d_in[11];
  const float* fw3 = (const float*)d_in[12];
  const float* fb3 = (const float*)d_in[13];
  float* out  = (float*)d_out;
  float* ds   = out;                 // (16,400)
  float* logp = out + 6402;          // (16,2000,400)
  char* ws = (char*)d_ws;
  double* lgt  = (double*)(ws + 0);
  double* rowA = (double*)(ws + 20480);
  double* colA = (double*)(ws + 36864);
  double* sA   = (double*)(ws + 40960);
  float*  nll  = (float*)(ws + 61440);
  float*  gsum = (float*)(ws + 61696);
  float*  Z2   = (float*)(ws + 65536);
  float*  fn2  = (float*)(ws + 196608);
  float*  tn2  = (float*)(ws + 327680);
  unsigned char* cmpb = (unsigned char*)(ws + 360448);
  float*  tenc = (float*)(ws + 2408448);
  float*  f1   = (float*)(ws + 8962048);
  float*  t1   = f1;      // t1 dead before f1 (f-conv1 out) is written
  float*  f2   = logp;    // f-conv2 intermediate; dead before scores written
  if(ws_size < 41730048) return;

  k_lgt  <<<10,256,0,stream>>>(lgt);
  k_terms<<<10,256,0,stream>>>(lgt,rowA,colA,sA);

  conv_k<256,3,true ><<<dim3(13,NB),128,0,stream>>>(txt, tw1, tb1, t1, TT);
  conv_k<256,1,false><<<dim3(13,NB),128,0,stream>>>(t1, tw2, tb2, tenc, TT);
  conv_k<512,3,true ><<<dim3(63,NB),128,0,stream>>>(speech, fw1, fb1, f1, TF);
  conv_k<256,3,true ><<<dim3(63,NB),128,0,stream>>>(f1, fw2, fb2, f2, TF);
  conv_k<256,1,false><<<dim3(63,NB),128,0,stream>>>(f2, fw3, fb3, f1, TF);

  norm2_k<<<(NB*TF)/4,256,0,stream>>>(f1, fn2, NB*TF);
  norm2_k<<<(NB*TT)/4,256,0,stream>>>(tenc, tn2, NB*TT);

  score_gemm<<<dim3(7,32,NB),256,0,stream>>>(f1, tenc, fn2, tn2, logp);
  softmax_prior_k<<<NB*TF,128,0,stream>>>(logp, rowA, colA, sA, Z2);

  scan_k<<<2*NB,128,0,stream>>>(logp, Z2, cmpb, nll);
  masback_k<<<NB,256,0,stream>>>(cmpb, logp, ds, gsum);
  final_k<<<1,64,0,stream>>>(nll, gsum, out);
}

// Round 11
// 1569.129 us; speedup vs baseline: 1.1276x; 1.0009x over previous
//
#include <hip/hip_runtime.h>
#include <math.h>

typedef unsigned int u32;
typedef unsigned long long u64;

#define BIGN (-1e30f)

static constexpr int NB = 16;     // batch
static constexpr int TF = 2000;   // T_FEATS
static constexpr int TT = 400;    // T_TEXT

__device__ __forceinline__ float wsum(float v){
#pragma unroll
  for(int o=32;o;o>>=1) v += __shfl_xor(v,o,64);
  return v;
}
// raw HW transcendentals: v_exp_f32 (2^x), v_log_f32 (log2 x)
__device__ __forceinline__ float EXP2(float x){ return __builtin_amdgcn_exp2f(x); }
__device__ __forceinline__ float LOG2(float x){ return __builtin_amdgcn_logf(x); }

// log-sum-exp in BASE-2 domain
__device__ __forceinline__ float lse2b(float x, float y){
  float m = fmaxf(x,y);
  return m + LOG2(1.0f + EXP2(-fabsf(x-y)));
}
__device__ __forceinline__ float lse3b(float x, float y, float z){
  float mx = fmaxf(fmaxf(x,y),z);
  float md = __builtin_amdgcn_fmed3f(x,y,z);
  float mn = fminf(fminf(x,y),z);
  return mx + LOG2(1.0f + EXP2(md-mx) + EXP2(mn-mx));
}

// ---------------- gammaln tables ----------------
__global__ void k_lgt(double* lgt){
  int m = blockIdx.x*blockDim.x + threadIdx.x;
  if(m < 2432) lgt[m] = (m>=1)? lgamma((double)m) : 0.0;
}
__global__ void k_terms(const double* __restrict__ lgt, double* rowA, double* colA, double* sA){
  int i = blockIdx.x*blockDim.x + threadIdx.x;
  if(i < TF)   rowA[i] = -lgt[2401] - lgt[i+1] - lgt[2000-i] + lgt[2001];
  if(i < TT)   colA[i] =  lgt[401]  - lgt[i+2] - lgt[400-i];
  if(i < 2399) sA[i]   =  lgt[i+2]  + lgt[2399-i];
}

// ---------------- conv1d (cross-correlation, pad=(KW-1)/2), OIH weights ----------------
// 128 threads, 2 output channels per thread (o, o+128): each LDS window read feeds 2x the FMAs.
// waves_per_eu(1,1): full VGPR budget (Round-9 lesson: (128,2) capped at 128 VGPR -> 883MB spill).
template<int CIN, int KW, bool RELU>
__global__ __launch_bounds__(128) __attribute__((amdgpu_waves_per_eu(1,1)))
void conv_k(const float* __restrict__ in, const float* __restrict__ w,
    const float* __restrict__ bias, float* __restrict__ out, int P){
  constexpr int PT = 32;
  constexpr int ROWS = PT + KW - 1;
  constexpr int RPAD = (ROWS + 3) & ~3;
  constexpr int CT = 8;
  constexpr int WT = CT*KW;            // 24 (KW3) or 8 (KW1)
  __shared__ __align__(16) float xs[256][RPAD];
  const int b = blockIdx.y;
  const int p0 = blockIdx.x * PT;
  const int o = threadIdx.x;           // 0..127; outputs o and o+128
  float acc0[PT], acc1[PT];
  const float bo0 = bias[o], bo1 = bias[o+128];
#pragma unroll
  for(int i=0;i<PT;i++){ acc0[i] = bo0; acc1[i] = bo1; }
  const float* inb = in + (size_t)b * P * CIN;
  const float* wo0 = w + (size_t)o * CIN * KW;
  const float* wo1 = w + (size_t)(o+128) * CIN * KW;
  for(int cc=0; cc<CIN; cc+=256){
    __syncthreads();
    for(int i=0;i<ROWS;i++){
      int p = p0 + i - (KW==3 ? 1 : 0);
      float v0 = 0.f, v1 = 0.f;
      if(p>=0 && p<P){
        v0 = inb[(size_t)p*CIN + cc + o];
        v1 = inb[(size_t)p*CIN + cc + o + 128];
      }
      xs[o][i] = v0;
      xs[o+128][i] = v1;
    }
    __syncthreads();
    float wA0[WT], wA1[WT], wB0[WT], wB1[WT];
#pragma unroll
    for(int q=0;q<WT/4;q++){
      ((float4*)wA0)[q] = ((const float4*)(wo0 + (size_t)cc*KW))[q];
      ((float4*)wA1)[q] = ((const float4*)(wo1 + (size_t)cc*KW))[q];
    }
    for(int c0=0; c0<256; c0+=2*CT){
#pragma unroll
      for(int q=0;q<WT/4;q++){
        ((float4*)wB0)[q] = ((const float4*)(wo0 + (size_t)(cc+c0+CT)*KW))[q];
        ((float4*)wB1)[q] = ((const float4*)(wo1 + (size_t)(cc+c0+CT)*KW))[q];
      }
#pragma unroll
      for(int c=0;c<CT;c++){
        float win[RPAD];
#pragma unroll
        for(int q=0;q<RPAD/4;q++) ((float4*)win)[q] = ((const float4*)&xs[c0+c][0])[q];
        if(KW==3){
          float a0=wA0[c*3], a1=wA0[c*3+1], a2=wA0[c*3+2];
          float b0=wA1[c*3], b1=wA1[c*3+1], b2=wA1[c*3+2];
#pragma unroll
          for(int i=0;i<PT;i++){
            acc0[i] = fmaf(a2,win[i+2],fmaf(a1,win[i+1],fmaf(a0,win[i],acc0[i])));
            acc1[i] = fmaf(b2,win[i+2],fmaf(b1,win[i+1],fmaf(b0,win[i],acc1[i])));
          }
        } else {
          float a0=wA0[c], b0=wA1[c];
#pragma unroll
          for(int i=0;i<PT;i++){
            acc0[i] = fmaf(a0,win[i],acc0[i]);
            acc1[i] = fmaf(b0,win[i],acc1[i]);
          }
        }
      }
      int cn = (c0+2*CT < 256)? (cc+c0+2*CT) : cc;   // clamp: dummy reload on last pair
#pragma unroll
      for(int q=0;q<WT/4;q++){
        ((float4*)wA0)[q] = ((const float4*)(wo0 + (size_t)cn*KW))[q];
        ((float4*)wA1)[q] = ((const float4*)(wo1 + (size_t)cn*KW))[q];
      }
#pragma unroll
      for(int c=0;c<CT;c++){
        float win[RPAD];
#pragma unroll
        for(int q=0;q<RPAD/4;q++) ((float4*)win)[q] = ((const float4*)&xs[c0+CT+c][0])[q];
        if(KW==3){
          float a0=wB0[c*3], a1=wB0[c*3+1], a2=wB0[c*3+2];
          float b0=wB1[c*3], b1=wB1[c*3+1], b2=wB1[c*3+2];
#pragma unroll
          for(int i=0;i<PT;i++){
            acc0[i] = fmaf(a2,win[i+2],fmaf(a1,win[i+1],fmaf(a0,win[i],acc0[i])));
            acc1[i] = fmaf(b2,win[i+2],fmaf(b1,win[i+1],fmaf(b0,win[i],acc1[i])));
          }
        } else {
          float a0=wB0[c], b0=wB1[c];
#pragma unroll
          for(int i=0;i<PT;i++){
            acc0[i] = fmaf(a0,win[i],acc0[i]);
            acc1[i] = fmaf(b0,win[i],acc1[i]);
          }
        }
      }
    }
  }
#pragma unroll
  for(int i=0;i<PT;i++){
    int p = p0+i;
    if(p<P){
      float v0 = acc0[i], v1 = acc1[i];
      if(RELU){ v0 = fmaxf(v0,0.f); v1 = fmaxf(v1,0.f); }
      out[((size_t)b*P+p)*256 + o] = v0;
      out[((size_t)b*P+p)*256 + o + 128] = v1;
    }
  }
}

// ---------------- row squared norms ----------------
__global__ __launch_bounds__(256) void norm2_k(const float* __restrict__ x, float* __restrict__ o, int rows){
  int r = blockIdx.x*4 + (threadIdx.x>>6);
  int lane = threadIdx.x & 63;
  if(r>=rows) return;
  float4 v = ((const float4*)(x + (size_t)r*256))[lane];
  float s = v.x*v.x + v.y*v.y + v.z*v.z + v.w*v.w;
  s = wsum(s);
  if(lane==0) o[r] = s;
}

// ---------------- score = -sqrt(max(||f||^2+||t||^2-2 f.t, 1e-12)) ----------------
__global__ __launch_bounds__(256) void score_gemm(const float* __restrict__ F, const float* __restrict__ Tn,
    const float* __restrict__ fn2, const float* __restrict__ tn2, float* __restrict__ outp){
  constexpr int KC = 32;
  __shared__ __align__(16) float As[KC][68];
  __shared__ __align__(16) float Bs[KC][68];
  const int b = blockIdx.z;
  const int t0 = blockIdx.y*64, s0 = blockIdx.x*64;
  const int tid = threadIdx.x, tx = tid&15, ty = tid>>4;
  const float* Fb = F  + (size_t)b*TF*256;
  const float* Tb = Tn + (size_t)b*TT*256;
  float acc[4][4] = {};
  const int lk = tid & 31, lt0 = (tid>>5)*8;
  for(int k0=0;k0<256;k0+=KC){
    __syncthreads();
#pragma unroll
    for(int i=0;i<8;i++){
      int t = t0 + lt0 + i;
      As[lk][lt0+i] = (t<TF)? Fb[(size_t)t*256 + k0 + lk] : 0.f;
      int s = s0 + lt0 + i;
      Bs[lk][lt0+i] = (s<TT)? Tb[(size_t)s*256 + k0 + lk] : 0.f;
    }
    __syncthreads();
#pragma unroll
    for(int k=0;k<KC;k++){
      float a0[4], b0[4];
      *(float4*)a0 = *(const float4*)&As[k][ty*4];
      *(float4*)b0 = *(const float4*)&Bs[k][tx*4];
#pragma unroll
      for(int i=0;i<4;i++)
#pragma unroll
        for(int j=0;j<4;j++) acc[i][j] = fmaf(a0[i], b0[j], acc[i][j]);
    }
  }
#pragma unroll
  for(int i=0;i<4;i++){
    int t = t0 + ty*4 + i;
    if(t<TF){
      float fn = fn2[b*TF + t];
#pragma unroll
      for(int j=0;j<4;j++){
        int s = s0 + tx*4 + j;
        if(s<TT){
          float d2 = fn + tn2[b*TT + s] - 2.f*acc[i][j];
          outp[((size_t)b*TF + t)*TT + s] = -sqrtf(fmaxf(d2, 1e-12f));
        }
      }
    }
  }
}

// ---------------- per-row log_softmax + prior, and Z2 = logsumexp([BLANK, row]) ----------------
__global__ __launch_bounds__(128) void softmax_prior_k(float* __restrict__ logp,
    const double* __restrict__ rowA, const double* __restrict__ colA, const double* __restrict__ sA,
    float* __restrict__ Z2){
  const int row = blockIdx.x;           // b*TF + t0
  const int t0 = row % TF;
  float* rp = logp + (size_t)row*TT;
  const int tid = threadIdx.x;
  __shared__ float sh2[2];
  float v[4]; int ix[4];
#pragma unroll
  for(int i=0;i<4;i++){ ix[i] = tid + i*128; v[i] = (ix[i]<TT)? rp[ix[i]] : BIGN; }
  float m = fmaxf(fmaxf(v[0],v[1]),fmaxf(v[2],v[3]));
#pragma unroll
  for(int o=32;o;o>>=1) m = fmaxf(m, __shfl_xor(m,o,64));
  if((tid&63)==0) sh2[tid>>6] = m;
  __syncthreads();
  m = fmaxf(sh2[0], sh2[1]);
  float s = 0.f;
#pragma unroll
  for(int i=0;i<4;i++) if(ix[i]<TT) s += __expf(v[i]-m);
  s = wsum(s);
  __syncthreads();
  if((tid&63)==0) sh2[tid>>6] = s;
  __syncthreads();
  s = sh2[0] + sh2[1];
  const float lse = m + __logf(s);
  const double rA = rowA[t0];
  float f[4]; float m2 = BIGN;
#pragma unroll
  for(int i=0;i<4;i++){
    if(ix[i]<TT){
      float pr = (float)(colA[ix[i]] + sA[t0+ix[i]] + rA);
      f[i] = (v[i]-lse) + pr;
      rp[ix[i]] = f[i];
      m2 = fmaxf(m2, f[i]);
    } else f[i] = BIGN;
  }
#pragma unroll
  for(int o=32;o;o>>=1) m2 = fmaxf(m2, __shfl_xor(m2,o,64));
  __syncthreads();
  if((tid&63)==0) sh2[tid>>6] = m2;
  __syncthreads();
  m2 = fmaxf(fmaxf(sh2[0],sh2[1]), -1.0f);
  float s2 = (tid==0)? __expf(-1.0f - m2) : 0.f;
#pragma unroll
  for(int i=0;i<4;i++) if(ix[i]<TT) s2 += __expf(f[i]-m2);
  s2 = wsum(s2);
  __syncthreads();
  if((tid&63)==0) sh2[tid>>6] = s2;
  __syncthreads();
  if(tid==0) Z2[row] = m2 + __logf(sh2[0]+sh2[1]);
}

// ---------------- scans ----------------
// CTC blocks (0..15): bidirectional, two waves (t=0..999 fwd, t=1999..1000 reversed lattice),
//   seam-combined via LDS. MAS blocks (16..31): wave 0, full 2000 steps, cmp bits 1B/lane/step.
#define LCTC_STEP(E) { \
  float n1 = __shfl_up(a[13], 1); \
  if(lane==0) n1 = BIGN; \
  a[13] = lse3b(a[13], a[12], a[11]) + (E)[6]; \
  a[12] = lse2b(a[12], a[11]) + EBL; \
  a[11] = lse3b(a[11], a[10], a[9]) + (E)[5]; \
  a[10] = lse2b(a[10], a[9]) + EBL; \
  a[9]  = lse3b(a[9],  a[8],  a[7]) + (E)[4]; \
  a[8]  = lse2b(a[8],  a[7]) + EBL; \
  a[7]  = lse3b(a[7],  a[6],  a[5]) + (E)[3]; \
  a[6]  = lse2b(a[6],  a[5]) + EBL; \
  a[5]  = lse3b(a[5],  a[4],  a[3]) + (E)[2]; \
  a[4]  = lse2b(a[4],  a[3]) + EBL; \
  a[3]  = lse3b(a[3],  a[2],  a[1]) + (E)[1]; \
  a[2]  = lse2b(a[2],  a[1]) + EBL; \
  a[1]  = lse3b(a[1],  a[0],  n1) + (E)[0]; \
  a[0]  = lse2b(a[0],  n1) + EBL; }

// step index K in 1..999; row = dir? TF-1-K : K
#define CPREF(E, K) { int kk=(K); if(kk>999) kk=999; int row = dir? (TF-1-kk) : kk; \
  const float* rpp = lp + (size_t)row*TT; \
  (E)[0]=rpp[jc[0]]*IL2; (E)[1]=rpp[jc[1]]*IL2; (E)[2]=rpp[jc[2]]*IL2; (E)[3]=rpp[jc[3]]*IL2; \
  (E)[4]=rpp[jc[4]]*IL2; (E)[5]=rpp[jc[5]]*IL2; (E)[6]=rpp[jc[6]]*IL2; }

#define MAS_STEP(E, TIDX) { \
  float n1 = __shfl_up(q[6],1); \
  u32 byte = 0; \
  if(lane>0 && n1 >= q[0]) byte |= 1u; \
  if(q[0] >= q[1]) byte |= 2u; \
  if(q[1] >= q[2]) byte |= 4u; \
  if(q[2] >= q[3]) byte |= 8u; \
  if(q[3] >= q[4]) byte |= 16u; \
  if(q[4] >= q[5]) byte |= 32u; \
  if(q[5] >= q[6]) byte |= 64u; \
  cb[(size_t)((TIDX)-1)*64 + lane] = (unsigned char)byte; \
  q[6] = fmaxf(q[6], q[5]) + (E)[6]; \
  q[5] = fmaxf(q[5], q[4]) + (E)[5]; \
  q[4] = fmaxf(q[4], q[3]) + (E)[4]; \
  q[3] = fmaxf(q[3], q[2]) + (E)[3]; \
  q[2] = fmaxf(q[2], q[1]) + (E)[2]; \
  q[1] = fmaxf(q[1], q[0]) + (E)[1]; \
  q[0] = fmaxf(q[0], (lane>0)? n1 : BIGN) + (E)[0]; }

#define MPREF(E, ROW) { int rr=(ROW); rr = (rr>TF-1)? (TF-1) : rr; const float* rpp = lp + (size_t)rr*TT; \
  (E)[0]=rpp[jc[0]]; (E)[1]=rpp[jc[1]]; (E)[2]=rpp[jc[2]]; (E)[3]=rpp[jc[3]]; \
  (E)[4]=rpp[jc[4]]; (E)[5]=rpp[jc[5]]; (E)[6]=rpp[jc[6]]; }

__global__ __launch_bounds__(128) __attribute__((amdgpu_waves_per_eu(1,1)))
void scan_k(const float* __restrict__ logp,
    const float* __restrict__ Z2, unsigned char* __restrict__ cmpb, float* __restrict__ nll){
  const int lane = threadIdx.x & 63;
  const int wave = threadIdx.x >> 6;
  constexpr float IL2 = 1.4426950408889634f;   // 1/ln2
  constexpr float L2  = 0.6931471805599453f;   // ln2
  if(blockIdx.x < NB){
    const int b = blockIdx.x;
    const float* lp = logp + (size_t)b*TF*TT;
    __shared__ float af[801], ag[801];
    const int dir = wave;                      // 0: t=0..999 ; 1: t=1999..1000 (state w=800-s)
    double zs = 0.0;
    if(wave==0){
      for(int t=lane; t<TF; t+=64) zs += (double)Z2[b*TF + t];
#pragma unroll
      for(int o=32;o;o>>=1) zs += __shfl_xor(zs, o, 64);
    }
    int jc[7];
#pragma unroll
    for(int i=0;i<7;i++){ int j = 7*lane + i; j = (j < TT)? j : (TT-1); jc[i] = dir? (TT-1-j) : j; }
    float a[14];
#pragma unroll
    for(int i=0;i<14;i++) a[i] = BIGN;
    if(lane==0){
      a[0] = -1.0f*IL2;                                           // blank end-state (s=0 / s=800)
      a[1] = (dir? lp[(size_t)(TF-1)*TT + (TT-1)] : lp[0]) * IL2; // emit end-state (s=1 / s=799)
    }
    const float EBL = -1.0f*IL2;
    float e0[7],e1[7],e2[7],e3[7],e4[7],e5[7],e6[7],e7[7];
    CPREF(e0,1); CPREF(e1,2); CPREF(e2,3); CPREF(e3,4);
    CPREF(e4,5); CPREF(e5,6); CPREF(e6,7); CPREF(e7,8);
    int k = 1;
    for(; k + 8 <= 993; k += 8){
      LCTC_STEP(e0); CPREF(e0, k+8);
      LCTC_STEP(e1); CPREF(e1, k+9);
      LCTC_STEP(e2); CPREF(e2, k+10);
      LCTC_STEP(e3); CPREF(e3, k+11);
      LCTC_STEP(e4); CPREF(e4, k+12);
      LCTC_STEP(e5); CPREF(e5, k+13);
      LCTC_STEP(e6); CPREF(e6, k+14);
      LCTC_STEP(e7); CPREF(e7, k+15);
    }
    for(; k<=999; k++){          // tail, direct loads
      float P[7];
      CPREF(P, k);
      LCTC_STEP(P);
    }
    float* dst = wave? ag : af;
#pragma unroll
    for(int i=0;i<14;i++){ int s = 14*lane+i; if(s<=800) dst[s] = a[i]; }
    __syncthreads();
    if(wave==0){
      float acc = BIGN;
#pragma unroll
      for(int i=0;i<14;i++){
        int s = 14*lane+i;
        if(s<=800){
          float x0 = af[s];
          float x1 = (s>=1)? af[s-1] : BIGN;
          float x2 = ((s&1) && s>=3)? af[s-2] : BIGN;
          float A1 = lse3b(x0,x1,x2);                 // one transition, no emission
          acc = lse2b(acc, A1 + ag[800-s]);
        }
      }
#pragma unroll
      for(int o=32;o;o>>=1) acc = lse2b(acc, __shfl_xor(acc,o,64));
      if(lane==0) nll[b] = -((acc*L2) - (float)zs);
    }
  } else {
    if(wave) return;
    const int b = blockIdx.x - NB;
    const float* lp = logp + (size_t)b*TF*TT;
    unsigned char* cb = cmpb + (size_t)b*TF*64;
    int jc[7];
#pragma unroll
    for(int i=0;i<7;i++){ int j = 7*lane + i; jc[i] = (j < TT)? j : (TT-1); }
    float q[7];
#pragma unroll
    for(int i=0;i<7;i++) q[i] = BIGN;
    if(lane==0) q[0] = lp[0];
    float e0[7],e1[7],e2[7],e3[7];
    MPREF(e0,1); MPREF(e1,2); MPREF(e2,3); MPREF(e3,4);
    int t0 = 1;
    for(; t0 + 4 <= TF; t0 += 4){
      MAS_STEP(e0, t0);   MPREF(e0, t0+4);
      MAS_STEP(e1, t0+1); MPREF(e1, t0+5);
      MAS_STEP(e2, t0+2); MPREF(e2, t0+6);
      MAS_STEP(e3, t0+3); MPREF(e3, t0+7);
    }
    for(; t0<TF; t0++){
      float P[7];
      MPREF(P, t0);
      MAS_STEP(P, t0);
    }
    // final row of cmp bits (row TF-1)
    {
      float n1 = __shfl_up(q[6],1);
      u32 byte = 0;
      if(lane>0 && n1 >= q[0]) byte |= 1u;
      if(q[0] >= q[1]) byte |= 2u;
      if(q[1] >= q[2]) byte |= 4u;
      if(q[2] >= q[3]) byte |= 8u;
      if(q[3] >= q[4]) byte |= 16u;
      if(q[4] >= q[5]) byte |= 32u;
      if(q[5] >= q[6]) byte |= 64u;
      cb[(size_t)(TF-1)*64 + lane] = (unsigned char)byte;
    }
  }
}

// ---------------- MAS backtrack + ds + gather ----------------
__global__ __launch_bounds__(256) void masback_k(const unsigned char* __restrict__ cmpb,
    const float* __restrict__ logp, float* __restrict__ ds, float* __restrict__ gsum){
  const int b = blockIdx.x;
  const unsigned char* cb = cmpb + (size_t)b*TF*64;
  __shared__ unsigned char bits[500*64];
  __shared__ short Ash[TF];
  __shared__ int cnt[TT];
  __shared__ float ps[4];
  int a = TT-1;
  for(int ch=3; ch>=0; ch--){
    const int tlo = ch*500;
    __syncthreads();
    for(int i=threadIdx.x;i<8000;i+=256) ((u32*)bits)[i] = ((const u32*)(cb + (size_t)tlo*64))[i];
    __syncthreads();
    if(threadIdx.x==0){
      int thi = tlo + 499;
      if(ch==3){ Ash[TF-1] = (short)(TT-1); thi = TF-2; }
      for(int t=thi;t>=tlo;t--){
        if(a > 0){
          unsigned char w = bits[(t-tlo)*64 + a/7];
          a -= (int)((w >> (a%7)) & 1u);
        }
        Ash[t] = (short)a;
      }
    }
  }
  __syncthreads();
  for(int i=threadIdx.x;i<TT;i+=256) cnt[i]=0;
  __syncthreads();
  float part = 0.f;
  const float* lp = logp + (size_t)b*TF*TT;
  for(int t=threadIdx.x;t<TF;t+=256){
    int at = Ash[t];
    atomicAdd(&cnt[at], 1);
    part += lp[(size_t)t*TT + at];
  }
  __syncthreads();
  for(int i=threadIdx.x;i<TT;i+=256) ds[(size_t)b*TT + i] = (float)cnt[i];
  part = wsum(part);
  if((threadIdx.x&63)==0) ps[threadIdx.x>>6] = part;
  __syncthreads();
  if(threadIdx.x==0) gsum[b] = ps[0]+ps[1]+ps[2]+ps[3];
}

__global__ void final_k(const float* __restrict__ nll, const float* __restrict__ gsum, float* __restrict__ out){
  if(threadIdx.x==0 && blockIdx.x==0){
    float fs=0.f, bs=0.f;
    for(int b=0;b<NB;b++){ fs += nll[b] / (float)TT; bs += gsum[b] / (float)TF; }
    out[6400] = -(bs / (float)NB);   // bin_loss
    out[6401] = fs / (float)NB;      // forwardsum_loss
  }
}

extern "C" void kernel_launch(void* const* d_in, const int* in_sizes, int n_in,
                              void* d_out, int out_size, void* d_ws, size_t ws_size,
                              hipStream_t stream){
  const float* speech = (const float*)d_in[0];
  const float* txt    = (const float*)d_in[1];
  const float* tw1 = (const float*)d_in[4];
  const float* tb1 = (const float*)d_in[5];
  const float* tw2 = (const float*)d_in[6];
  const float* tb2 = (const float*)d_in[7];
  const float* fw1 = (const float*)d_in[8];
  const float* fb1 = (const float*)d_in[9];
  const float* fw2 = (const float*)d_in[10];
  const float* fb2 = (const float*)d_in[11];
  const float* fw3 = (const float*)d_in[12];
  const float* fb3 = (const float*)d_in[13];
  float* out  = (float*)d_out;
  float* ds   = out;                 // (16,400)
  float* logp = out + 6402;          // (16,2000,400)
  char* ws = (char*)d_ws;
  double* lgt  = (double*)(ws + 0);
  double* rowA = (double*)(ws + 20480);
  double* colA = (double*)(ws + 36864);
  double* sA   = (double*)(ws + 40960);
  float*  nll  = (float*)(ws + 61440);
  float*  gsum = (float*)(ws + 61696);
  float*  Z2   = (float*)(ws + 65536);
  float*  fn2  = (float*)(ws + 196608);
  float*  tn2  = (float*)(ws + 327680);
  unsigned char* cmpb = (unsigned char*)(ws + 360448);
  float*  tenc = (float*)(ws + 2408448);
  float*  f1   = (float*)(ws + 8962048);
  float*  t1   = f1;      // t1 dead before f1 (f-conv1 out) is written
  float*  f2   = logp;    // f-conv2 intermediate; dead before scores written
  if(ws_size < 41730048) return;

  k_lgt  <<<10,256,0,stream>>>(lgt);
  k_terms<<<10,256,0,stream>>>(lgt,rowA,colA,sA);

  conv_k<256,3,true ><<<dim3(13,NB),128,0,stream>>>(txt, tw1, tb1, t1, TT);
  conv_k<256,1,false><<<dim3(13,NB),128,0,stream>>>(t1, tw2, tb2, tenc, TT);
  conv_k<512,3,true ><<<dim3(63,NB),128,0,stream>>>(speech, fw1, fb1, f1, TF);
  conv_k<256,3,true ><<<dim3(63,NB),128,0,stream>>>(f1, fw2, fb2, f2, TF);
  conv_k<256,1,false><<<dim3(63,NB),128,0,stream>>>(f2, fw3, fb3, f1, TF);

  norm2_k<<<(NB*TF)/4,256,0,stream>>>(f1, fn2, NB*TF);
  norm2_k<<<(NB*TT)/4,256,0,stream>>>(tenc, tn2, NB*TT);

  score_gemm<<<dim3(7,32,NB),256,0,stream>>>(f1, tenc, fn2, tn2, logp);
  softmax_prior_k<<<NB*TF,128,0,stream>>>(logp, rowA, colA, sA, Z2);

  scan_k<<<2*NB,128,0,stream>>>(logp, Z2, cmpb, nll);
  masback_k<<<NB,256,0,stream>>>(cmpb, logp, ds, gsum);
  final_k<<<1,64,0,stream>>>(nll, gsum, out);
}

// Round 14
// 973.378 us; speedup vs baseline: 1.8178x; 1.6120x over previous
//
#include <hip/hip_runtime.h>
#include <math.h>

typedef unsigned int u32;
typedef unsigned long long u64;
typedef unsigned short u16;
typedef __attribute__((ext_vector_type(8))) _Float16 f16x8;  // 8 fp16 (4 VGPR)
typedef __attribute__((ext_vector_type(4))) float f32x4;

#define BIGN (-1e30f)

static constexpr int NB = 16;     // batch
static constexpr int TF = 2000;   // T_FEATS
static constexpr int TT = 400;    // T_TEXT

__device__ __forceinline__ float wsum(float v){
#pragma unroll
  for(int o=32;o;o>>=1) v += __shfl_xor(v,o,64);
  return v;
}
__device__ __forceinline__ float EXP2(float x){ return __builtin_amdgcn_exp2f(x); }
__device__ __forceinline__ float LOG2(float x){ return __builtin_amdgcn_logf(x); }
__device__ __forceinline__ float lse2b(float x, float y){
  float m = fmaxf(x,y);
  return m + LOG2(1.0f + EXP2(-fabsf(x-y)));
}
__device__ __forceinline__ float lse3b(float x, float y, float z){
  float mx = fmaxf(fmaxf(x,y),z);
  float md = __builtin_amdgcn_fmed3f(x,y,z);
  float mn = fminf(fminf(x,y),z);
  return mx + LOG2(1.0f + EXP2(md-mx) + EXP2(mn-mx));
}
__device__ __forceinline__ u16 f2h(float v){
  _Float16 h = (_Float16)v;              // round-nearest-even
  return *(u16*)&h;
}

// ---------------- gammaln tables ----------------
__global__ void k_lgt(double* lgt){
  int m = blockIdx.x*blockDim.x + threadIdx.x;
  if(m < 2432) lgt[m] = (m>=1)? lgamma((double)m) : 0.0;
}
__global__ void k_terms(const double* __restrict__ lgt, double* rowA, double* colA, double* sA){
  int i = blockIdx.x*blockDim.x + threadIdx.x;
  if(i < TF)   rowA[i] = -lgt[2401] - lgt[i+1] - lgt[2000-i] + lgt[2001];
  if(i < TT)   colA[i] =  lgt[401]  - lgt[i+2] - lgt[400-i];
  if(i < 2399) sA[i]   =  lgt[i+2]  + lgt[2399-i];
}

// ---------------- fp32 -> padded fp16 (rows 0 and P+1 zero) ----------------
__global__ __launch_bounds__(256) void cvt_pad_k(const float* __restrict__ src, u16* __restrict__ dst,
    int P, int C){
  int n = NB*(P+2)*C;
  for(int i = blockIdx.x*256 + threadIdx.x; i < n; i += gridDim.x*256){
    int c = i % C;
    int rem = i / C;
    int p = rem % (P+2);
    int b = rem / (P+2);
    float v = 0.f;
    if(p>=1 && p<=P) v = src[((size_t)b*P + (p-1))*C + c];
    dst[i] = f2h(v);
  }
}

// ---------------- pack weights OIH (256,CIN,KW) fp32 -> [k][o][c] fp16 ----------------
__global__ __launch_bounds__(256) void pack_w_k(const float* __restrict__ w, u16* __restrict__ dst,
    int CIN, int KW){
  int n = 256*CIN*KW;
  for(int i = blockIdx.x*256 + threadIdx.x; i < n; i += gridDim.x*256){
    int k = i % KW;
    int c = (i / KW) % CIN;
    int o = i / (KW*CIN);
    dst[((size_t)k*256 + o)*CIN + c] = f2h(w[i]);
  }
}

// ---------------- zero pad rows (0 and P+1) of a padded fp16 buffer ----------------
__global__ __launch_bounds__(256) void zpad_k(u16* __restrict__ buf, int P, int C){
  int n = NB*2*C;
  for(int i = blockIdx.x*256 + threadIdx.x; i < n; i += gridDim.x*256){
    int c = i % C;
    int s = (i / C) & 1;
    int b = i / (2*C);
    buf[((size_t)b*(P+2) + (s? P+1 : 0))*C + c] = 0;
  }
}

// ---------------- conv1d via MFMA fp16 ----------------
// out[p][o] = bias[o] + sum_{k,c} in[p+k-pad][c] * w[o][c][k],  pad=(KW-1)/2
// in: padded fp16 (B, P+2, CIN).  wp: [k][o][c] fp16.  out: OBF? padded fp16 (B,P+2,256) : fp32 (B,P,256)
// Tile: BM=64 rows x BN=256 cols, BK=32. 4 waves, wave w -> cols [64w,64w+64). acc[4][4] f32x4.
// LDS group-major: A[g(4)][66][8], B[k][g(4)][256][8] -- every ds op is an aligned, conflict-free b128.
template<int CIN, int KW, bool RELU, bool OBF>
__global__ __launch_bounds__(256) void mfconv_k(const u16* __restrict__ inb,
    const u16* __restrict__ wp, const float* __restrict__ bias, void* __restrict__ outp, int P){
  __shared__ __align__(16) u16 Al[4*66*8];            // 4224 B
  __shared__ __align__(16) u16 Bl[KW*4*256*8];        // KW3: 49152 B, KW1: 16384 B
  const int b = blockIdx.y;
  const int m0 = blockIdx.x * 64;
  const int tid = threadIdx.x;
  const int lane = tid & 63, wv = tid >> 6;
  const int lo16 = lane & 15, hi = lane >> 4;
  constexpr int K1 = (KW==1)? 1 : 0;
  const u16* inB = inb + (size_t)b*(P+2)*CIN;
  f32x4 acc[4][4];
#pragma unroll
  for(int i=0;i<4;i++)
#pragma unroll
    for(int j=0;j<4;j++) acc[i][j] = (f32x4){0.f,0.f,0.f,0.f};

  for(int c0=0; c0<CIN; c0+=32){
    __syncthreads();
    // stage A: 66 window rows x 32 ch (4 groups of 8) = 264 (r,q) pairs; 256 threads, strided
    for(int idx = tid; idx < 264; idx += 256){
      int r = idx >> 2, q = idx & 3;
      int rowp = m0 + r;
      f16x8 v = (f16x8){0,0,0,0,0,0,0,0};
      if(rowp <= P+1) v = *(const f16x8*)&inB[(size_t)rowp*CIN + c0 + q*8];
      *(f16x8*)&Al[(q*66 + r)*8] = v;
    }
    // stage B: per k, 256 o-rows x 32 ch
#pragma unroll
    for(int k=0;k<KW;k++){
      const u16* wr = &wp[((size_t)(k*256) + tid)*CIN + c0];
      f16x8 w0 = *(const f16x8*)&wr[0];
      f16x8 w1 = *(const f16x8*)&wr[8];
      f16x8 w2 = *(const f16x8*)&wr[16];
      f16x8 w3 = *(const f16x8*)&wr[24];
      *(f16x8*)&Bl[((k*4+0)*256 + tid)*8] = w0;
      *(f16x8*)&Bl[((k*4+1)*256 + tid)*8] = w1;
      *(f16x8*)&Bl[((k*4+2)*256 + tid)*8] = w2;
      *(f16x8*)&Bl[((k*4+3)*256 + tid)*8] = w3;
    }
    __syncthreads();
#pragma unroll
    for(int k=0;k<KW;k++){
      f16x8 af[4];
#pragma unroll
      for(int rf=0;rf<4;rf++)
        af[rf] = *(const f16x8*)&Al[(hi*66 + rf*16 + lo16 + k + K1)*8];
#pragma unroll
      for(int cf=0;cf<4;cf++){
        int o = wv*64 + cf*16 + lo16;
        f16x8 bf = *(const f16x8*)&Bl[((k*4+hi)*256 + o)*8];
#pragma unroll
        for(int rf=0;rf<4;rf++)
          acc[rf][cf] = __builtin_amdgcn_mfma_f32_16x16x32_f16(af[rf], bf, acc[rf][cf], 0, 0, 0);
      }
    }
  }
  // epilogue: D[row=(hi*4+j)][col=lo16] per 16x16 frag
#pragma unroll
  for(int cf=0;cf<4;cf++){
    int o = wv*64 + cf*16 + lo16;
    float bs = bias[o];
#pragma unroll
    for(int rf=0;rf<4;rf++){
#pragma unroll
      for(int j=0;j<4;j++){
        int p = m0 + rf*16 + hi*4 + j;
        if(p < P){
          float v = acc[rf][cf][j] + bs;
          if(RELU) v = fmaxf(v, 0.f);
          if(OBF) ((u16*)outp)[((size_t)b*(P+2) + p + 1)*256 + o] = f2h(v);
          else    ((float*)outp)[((size_t)b*P + p)*256 + o] = v;
        }
      }
    }
  }
}

// ---------------- row squared norms ----------------
__global__ __launch_bounds__(256) void norm2_k(const float* __restrict__ x, float* __restrict__ o, int rows){
  int r = blockIdx.x*4 + (threadIdx.x>>6);
  int lane = threadIdx.x & 63;
  if(r>=rows) return;
  float4 v = ((const float4*)(x + (size_t)r*256))[lane];
  float s = v.x*v.x + v.y*v.y + v.z*v.z + v.w*v.w;
  s = wsum(s);
  if(lane==0) o[r] = s;
}

// ---------------- score = -sqrt(max(||f||^2+||t||^2-2 f.t, 1e-12)) ----------------
__global__ __launch_bounds__(256) void score_gemm(const float* __restrict__ F, const float* __restrict__ Tn,
    const float* __restrict__ fn2, const float* __restrict__ tn2, float* __restrict__ outp){
  constexpr int KC = 32;
  __shared__ __align__(16) float As[KC][68];
  __shared__ __align__(16) float Bs[KC][68];
  const int b = blockIdx.z;
  const int t0 = blockIdx.y*64, s0 = blockIdx.x*64;
  const int tid = threadIdx.x, tx = tid&15, ty = tid>>4;
  const float* Fb = F  + (size_t)b*TF*256;
  const float* Tb = Tn + (size_t)b*TT*256;
  float acc[4][4] = {};
  const int lk = tid & 31, lt0 = (tid>>5)*8;
  for(int k0=0;k0<256;k0+=KC){
    __syncthreads();
#pragma unroll
    for(int i=0;i<8;i++){
      int t = t0 + lt0 + i;
      As[lk][lt0+i] = (t<TF)? Fb[(size_t)t*256 + k0 + lk] : 0.f;
      int s = s0 + lt0 + i;
      Bs[lk][lt0+i] = (s<TT)? Tb[(size_t)s*256 + k0 + lk] : 0.f;
    }
    __syncthreads();
#pragma unroll
    for(int k=0;k<KC;k++){
      float a0[4], b0[4];
      *(float4*)a0 = *(const float4*)&As[k][ty*4];
      *(float4*)b0 = *(const float4*)&Bs[k][tx*4];
#pragma unroll
      for(int i=0;i<4;i++)
#pragma unroll
        for(int j=0;j<4;j++) acc[i][j] = fmaf(a0[i], b0[j], acc[i][j]);
    }
  }
#pragma unroll
  for(int i=0;i<4;i++){
    int t = t0 + ty*4 + i;
    if(t<TF){
      float fn = fn2[b*TF + t];
#pragma unroll
      for(int j=0;j<4;j++){
        int s = s0 + tx*4 + j;
        if(s<TT){
          float d2 = fn + tn2[b*TT + s] - 2.f*acc[i][j];
          outp[((size_t)b*TF + t)*TT + s] = -sqrtf(fmaxf(d2, 1e-12f));
        }
      }
    }
  }
}

// ---------------- per-row log_softmax + prior, and Z2 = logsumexp([BLANK, row]) ----------------
__global__ __launch_bounds__(128) void softmax_prior_k(float* __restrict__ logp,
    const double* __restrict__ rowA, const double* __restrict__ colA, const double* __restrict__ sA,
    float* __restrict__ Z2){
  const int row = blockIdx.x;           // b*TF + t0
  const int t0 = row % TF;
  float* rp = logp + (size_t)row*TT;
  const int tid = threadIdx.x;
  __shared__ float sh2[2];
  float v[4]; int ix[4];
#pragma unroll
  for(int i=0;i<4;i++){ ix[i] = tid + i*128; v[i] = (ix[i]<TT)? rp[ix[i]] : BIGN; }
  float m = fmaxf(fmaxf(v[0],v[1]),fmaxf(v[2],v[3]));
#pragma unroll
  for(int o=32;o;o>>=1) m = fmaxf(m, __shfl_xor(m,o,64));
  if((tid&63)==0) sh2[tid>>6] = m;
  __syncthreads();
  m = fmaxf(sh2[0], sh2[1]);
  float s = 0.f;
#pragma unroll
  for(int i=0;i<4;i++) if(ix[i]<TT) s += __expf(v[i]-m);
  s = wsum(s);
  __syncthreads();
  if((tid&63)==0) sh2[tid>>6] = s;
  __syncthreads();
  s = sh2[0] + sh2[1];
  const float lse = m + __logf(s);
  const double rA = rowA[t0];
  float f[4]; float m2 = BIGN;
#pragma unroll
  for(int i=0;i<4;i++){
    if(ix[i]<TT){
      float pr = (float)(colA[ix[i]] + sA[t0+ix[i]] + rA);
      f[i] = (v[i]-lse) + pr;
      rp[ix[i]] = f[i];
      m2 = fmaxf(m2, f[i]);
    } else f[i] = BIGN;
  }
#pragma unroll
  for(int o=32;o;o>>=1) m2 = fmaxf(m2, __shfl_xor(m2,o,64));
  __syncthreads();
  if((tid&63)==0) sh2[tid>>6] = m2;
  __syncthreads();
  m2 = fmaxf(fmaxf(sh2[0],sh2[1]), -1.0f);
  float s2 = (tid==0)? __expf(-1.0f - m2) : 0.f;
#pragma unroll
  for(int i=0;i<4;i++) if(ix[i]<TT) s2 += __expf(f[i]-m2);
  s2 = wsum(s2);
  __syncthreads();
  if((tid&63)==0) sh2[tid>>6] = s2;
  __syncthreads();
  if(tid==0) Z2[row] = m2 + __logf(sh2[0]+sh2[1]);
}

// ---------------- scans ----------------
#define LCTC_STEP(E) { \
  float n1 = __shfl_up(a[13], 1); \
  if(lane==0) n1 = BIGN; \
  a[13] = lse3b(a[13], a[12], a[11]) + (E)[6]; \
  a[12] = lse2b(a[12], a[11]) + EBL; \
  a[11] = lse3b(a[11], a[10], a[9]) + (E)[5]; \
  a[10] = lse2b(a[10], a[9]) + EBL; \
  a[9]  = lse3b(a[9],  a[8],  a[7]) + (E)[4]; \
  a[8]  = lse2b(a[8],  a[7]) + EBL; \
  a[7]  = lse3b(a[7],  a[6],  a[5]) + (E)[3]; \
  a[6]  = lse2b(a[6],  a[5]) + EBL; \
  a[5]  = lse3b(a[5],  a[4],  a[3]) + (E)[2]; \
  a[4]  = lse2b(a[4],  a[3]) + EBL; \
  a[3]  = lse3b(a[3],  a[2],  a[1]) + (E)[1]; \
  a[2]  = lse2b(a[2],  a[1]) + EBL; \
  a[1]  = lse3b(a[1],  a[0],  n1) + (E)[0]; \
  a[0]  = lse2b(a[0],  n1) + EBL; }

#define CPREF(E, K) { int kk=(K); if(kk>999) kk=999; int row = dir? (TF-1-kk) : kk; \
  const float* rpp = lp + (size_t)row*TT; \
  (E)[0]=rpp[jc[0]]*IL2; (E)[1]=rpp[jc[1]]*IL2; (E)[2]=rpp[jc[2]]*IL2; (E)[3]=rpp[jc[3]]*IL2; \
  (E)[4]=rpp[jc[4]]*IL2; (E)[5]=rpp[jc[5]]*IL2; (E)[6]=rpp[jc[6]]*IL2; }

#define MAS_STEP(E, TIDX) { \
  float n1 = __shfl_up(q[6],1); \
  u32 byte = 0; \
  if(lane>0 && n1 >= q[0]) byte |= 1u; \
  if(q[0] >= q[1]) byte |= 2u; \
  if(q[1] >= q[2]) byte |= 4u; \
  if(q[2] >= q[3]) byte |= 8u; \
  if(q[3] >= q[4]) byte |= 16u; \
  if(q[4] >= q[5]) byte |= 32u; \
  if(q[5] >= q[6]) byte |= 64u; \
  cb[(size_t)((TIDX)-1)*64 + lane] = (unsigned char)byte; \
  q[6] = fmaxf(q[6], q[5]) + (E)[6]; \
  q[5] = fmaxf(q[5], q[4]) + (E)[5]; \
  q[4] = fmaxf(q[4], q[3]) + (E)[4]; \
  q[3] = fmaxf(q[3], q[2]) + (E)[3]; \
  q[2] = fmaxf(q[2], q[1]) + (E)[2]; \
  q[1] = fmaxf(q[1], q[0]) + (E)[1]; \
  q[0] = fmaxf(q[0], (lane>0)? n1 : BIGN) + (E)[0]; }

#define MPREF(E, ROW) { int rr=(ROW); rr = (rr>TF-1)? (TF-1) : rr; const float* rpp = lp + (size_t)rr*TT; \
  (E)[0]=rpp[jc[0]]; (E)[1]=rpp[jc[1]]; (E)[2]=rpp[jc[2]]; (E)[3]=rpp[jc[3]]; \
  (E)[4]=rpp[jc[4]]; (E)[5]=rpp[jc[5]]; (E)[6]=rpp[jc[6]]; }

__global__ __launch_bounds__(128) __attribute__((amdgpu_waves_per_eu(1,1)))
void scan_k(const float* __restrict__ logp,
    const float* __restrict__ Z2, unsigned char* __restrict__ cmpb, float* __restrict__ nll){
  const int lane = threadIdx.x & 63;
  const int wave = threadIdx.x >> 6;
  constexpr float IL2 = 1.4426950408889634f;
  constexpr float L2  = 0.6931471805599453f;
  if(blockIdx.x < NB){
    const int b = blockIdx.x;
    const float* lp = logp + (size_t)b*TF*TT;
    __shared__ float af[801], ag[801];
    const int dir = wave;
    double zs = 0.0;
    if(wave==0){
      for(int t=lane; t<TF; t+=64) zs += (double)Z2[b*TF + t];
#pragma unroll
      for(int o=32;o;o>>=1) zs += __shfl_xor(zs, o, 64);
    }
    int jc[7];
#pragma unroll
    for(int i=0;i<7;i++){ int j = 7*lane + i; j = (j < TT)? j : (TT-1); jc[i] = dir? (TT-1-j) : j; }
    float a[14];
#pragma unroll
    for(int i=0;i<14;i++) a[i] = BIGN;
    if(lane==0){
      a[0] = -1.0f*IL2;
      a[1] = (dir? lp[(size_t)(TF-1)*TT + (TT-1)] : lp[0]) * IL2;
    }
    const float EBL = -1.0f*IL2;
    float e0[7],e1[7],e2[7],e3[7],e4[7],e5[7],e6[7],e7[7];
    CPREF(e0,1); CPREF(e1,2); CPREF(e2,3); CPREF(e3,4);
    CPREF(e4,5); CPREF(e5,6); CPREF(e6,7); CPREF(e7,8);
    int k = 1;
    for(; k + 8 <= 993; k += 8){
      LCTC_STEP(e0); CPREF(e0, k+8);
      LCTC_STEP(e1); CPREF(e1, k+9);
      LCTC_STEP(e2); CPREF(e2, k+10);
      LCTC_STEP(e3); CPREF(e3, k+11);
      LCTC_STEP(e4); CPREF(e4, k+12);
      LCTC_STEP(e5); CPREF(e5, k+13);
      LCTC_STEP(e6); CPREF(e6, k+14);
      LCTC_STEP(e7); CPREF(e7, k+15);
    }
    for(; k<=999; k++){
      float P[7];
      CPREF(P, k);
      LCTC_STEP(P);
    }
    float* dst = wave? ag : af;
#pragma unroll
    for(int i=0;i<14;i++){ int s = 14*lane+i; if(s<=800) dst[s] = a[i]; }
    __syncthreads();
    if(wave==0){
      float acc = BIGN;
#pragma unroll
      for(int i=0;i<14;i++){
        int s = 14*lane+i;
        if(s<=800){
          float x0 = af[s];
          float x1 = (s>=1)? af[s-1] : BIGN;
          float x2 = ((s&1) && s>=3)? af[s-2] : BIGN;
          float A1 = lse3b(x0,x1,x2);
          acc = lse2b(acc, A1 + ag[800-s]);
        }
      }
#pragma unroll
      for(int o=32;o;o>>=1) acc = lse2b(acc, __shfl_xor(acc,o,64));
      if(lane==0) nll[b] = -((acc*L2) - (float)zs);
    }
  } else {
    if(wave) return;
    const int b = blockIdx.x - NB;
    const float* lp = logp + (size_t)b*TF*TT;
    unsigned char* cb = cmpb + (size_t)b*TF*64;
    int jc[7];
#pragma unroll
    for(int i=0;i<7;i++){ int j = 7*lane + i; jc[i] = (j < TT)? j : (TT-1); }
    float q[7];
#pragma unroll
    for(int i=0;i<7;i++) q[i] = BIGN;
    if(lane==0) q[0] = lp[0];
    float e0[7],e1[7],e2[7],e3[7];
    MPREF(e0,1); MPREF(e1,2); MPREF(e2,3); MPREF(e3,4);
    int t0 = 1;
    for(; t0 + 4 <= TF; t0 += 4){
      MAS_STEP(e0, t0);   MPREF(e0, t0+4);
      MAS_STEP(e1, t0+1); MPREF(e1, t0+5);
      MAS_STEP(e2, t0+2); MPREF(e2, t0+6);
      MAS_STEP(e3, t0+3); MPREF(e3, t0+7);
    }
    for(; t0<TF; t0++){
      float P[7];
      MPREF(P, t0);
      MAS_STEP(P, t0);
    }
    {
      float n1 = __shfl_up(q[6],1);
      u32 byte = 0;
      if(lane>0 && n1 >= q[0]) byte |= 1u;
      if(q[0] >= q[1]) byte |= 2u;
      if(q[1] >= q[2]) byte |= 4u;
      if(q[2] >= q[3]) byte |= 8u;
      if(q[3] >= q[4]) byte |= 16u;
      if(q[4] >= q[5]) byte |= 32u;
      if(q[5] >= q[6]) byte |= 64u;
      cb[(size_t)(TF-1)*64 + lane] = (unsigned char)byte;
    }
  }
}

// ---------------- MAS backtrack + ds + gather ----------------
__global__ __launch_bounds__(256) void masback_k(const unsigned char* __restrict__ cmpb,
    const float* __restrict__ logp, float* __restrict__ ds, float* __restrict__ gsum){
  const int b = blockIdx.x;
  const unsigned char* cb = cmpb + (size_t)b*TF*64;
  __shared__ unsigned char bits[500*64];
  __shared__ short Ash[TF];
  __shared__ int cnt[TT];
  __shared__ float ps[4];
  int a = TT-1;
  for(int ch=3; ch>=0; ch--){
    const int tlo = ch*500;
    __syncthreads();
    for(int i=threadIdx.x;i<8000;i+=256) ((u32*)bits)[i] = ((const u32*)(cb + (size_t)tlo*64))[i];
    __syncthreads();
    if(threadIdx.x==0){
      int thi = tlo + 499;
      if(ch==3){ Ash[TF-1] = (short)(TT-1); thi = TF-2; }
      for(int t=thi;t>=tlo;t--){
        if(a > 0){
          unsigned char w = bits[(t-tlo)*64 + a/7];
          a -= (int)((w >> (a%7)) & 1u);
        }
        Ash[t] = (short)a;
      }
    }
  }
  __syncthreads();
  for(int i=threadIdx.x;i<TT;i+=256) cnt[i]=0;
  __syncthreads();
  float part = 0.f;
  const float* lp = logp + (size_t)b*TF*TT;
  for(int t=threadIdx.x;t<TF;t+=256){
    int at = Ash[t];
    atomicAdd(&cnt[at], 1);
    part += lp[(size_t)t*TT + at];
  }
  __syncthreads();
  for(int i=threadIdx.x;i<TT;i+=256) ds[(size_t)b*TT + i] = (float)cnt[i];
  part = wsum(part);
  if((threadIdx.x&63)==0) ps[threadIdx.x>>6] = part;
  __syncthreads();
  if(threadIdx.x==0) gsum[b] = ps[0]+ps[1]+ps[2]+ps[3];
}

__global__ void final_k(const float* __restrict__ nll, const float* __restrict__ gsum, float* __restrict__ out){
  if(threadIdx.x==0 && blockIdx.x==0){
    float fs=0.f, bs=0.f;
    for(int b=0;b<NB;b++){ fs += nll[b] / (float)TT; bs += gsum[b] / (float)TF; }
    out[6400] = -(bs / (float)NB);   // bin_loss
    out[6401] = fs / (float)NB;      // forwardsum_loss
  }
}

extern "C" void kernel_launch(void* const* d_in, const int* in_sizes, int n_in,
                              void* d_out, int out_size, void* d_ws, size_t ws_size,
                              hipStream_t stream){
  const float* speech = (const float*)d_in[0];
  const float* txt    = (const float*)d_in[1];
  const float* tw1 = (const float*)d_in[4];
  const float* tb1 = (const float*)d_in[5];
  const float* tw2 = (const float*)d_in[6];
  const float* tb2 = (const float*)d_in[7];
  const float* fw1 = (const float*)d_in[8];
  const float* fb1 = (const float*)d_in[9];
  const float* fw2 = (const float*)d_in[10];
  const float* fb2 = (const float*)d_in[11];
  const float* fw3 = (const float*)d_in[12];
  const float* fb3 = (const float*)d_in[13];
  float* out  = (float*)d_out;
  float* ds   = out;                 // (16,400)
  float* logp = out + 6402;          // (16,2000,400) -- also conv scratch until score_gemm
  char* ws = (char*)d_ws;
  double* lgt  = (double*)(ws + 0);
  double* rowA = (double*)(ws + 20480);
  double* colA = (double*)(ws + 36864);
  double* sA   = (double*)(ws + 40960);
  float*  nll  = (float*)(ws + 61440);
  float*  gsum = (float*)(ws + 61696);
  float*  Z2   = (float*)(ws + 65536);
  float*  fn2  = (float*)(ws + 196608);
  float*  tn2  = (float*)(ws + 327680);
  unsigned char* cmpb = (unsigned char*)(ws + 360448);
  float*  tenc = (float*)(ws + 2408448);
  float*  f1   = (float*)(ws + 8962048);   // f_enc fp32 (16,2000,256)
  if(ws_size < 41730048) return;

  // conv scratch inside the (dead until score_gemm) logp region; 256B-aligned base
  char* lr = (char*)(((uintptr_t)logp + 255) & ~(uintptr_t)255);
  u16* inbfT = (u16*)lr;                    // (16,402,256)  3.29MB   [txt phase]
  u16* tout1 = (u16*)(lr + 4000000);        // (16,402,256)  3.29MB   [txt phase]
  u16* inbfA = (u16*)lr;                    // (16,2002,512) 32.80MB  [f phase 1]
  u16* out2  = (u16*)lr;                    // (16,2002,256) 16.40MB  [f phase 3, after inbfA dead]
  u16* wbase = (u16*)(lr + 32900000);       // packs, 1.84MB, live all conv phases
  u16* fw1p = wbase;
  u16* fw2p = wbase + 393216;
  u16* fw3p = wbase + 589824;
  u16* tw1p = wbase + 655360;
  u16* tw2p = wbase + 851968;
  u16* out1  = (u16*)(lr + 34750000);       // (16,2002,256) 16.40MB

  k_lgt  <<<10,256,0,stream>>>(lgt);
  k_terms<<<10,256,0,stream>>>(lgt,rowA,colA,sA);

  // weight packs
  pack_w_k<<<768,256,0,stream>>>(fw1, fw1p, 512, 3);
  pack_w_k<<<384,256,0,stream>>>(fw2, fw2p, 256, 3);
  pack_w_k<<<128,256,0,stream>>>(fw3, fw3p, 256, 1);
  pack_w_k<<<384,256,0,stream>>>(tw1, tw1p, 256, 3);
  pack_w_k<<<128,256,0,stream>>>(tw2, tw2p, 256, 1);

  // txt path
  cvt_pad_k<<<2048,256,0,stream>>>(txt, inbfT, TT, 256);
  zpad_k<<<32,256,0,stream>>>(tout1, TT, 256);
  mfconv_k<256,3,true ,true ><<<dim3(7,NB),256,0,stream>>>(inbfT, tw1p, tb1, tout1, TT);
  mfconv_k<256,1,false,false><<<dim3(7,NB),256,0,stream>>>(tout1, tw2p, tb2, tenc, TT);

  // f path
  cvt_pad_k<<<4096,256,0,stream>>>(speech, inbfA, TF, 512);
  zpad_k<<<32,256,0,stream>>>(out1, TF, 256);
  mfconv_k<512,3,true ,true ><<<dim3(32,NB),256,0,stream>>>(inbfA, fw1p, fb1, out1, TF);
  zpad_k<<<32,256,0,stream>>>(out2, TF, 256);          // after fconv1: inbfA region dead
  mfconv_k<256,3,true ,true ><<<dim3(32,NB),256,0,stream>>>(out1, fw2p, fb2, out2, TF);
  mfconv_k<256,1,false,false><<<dim3(32,NB),256,0,stream>>>(out2, fw3p, fb3, f1, TF);

  norm2_k<<<(NB*TF)/4,256,0,stream>>>(f1, fn2, NB*TF);
  norm2_k<<<(NB*TT)/4,256,0,stream>>>(tenc, tn2, NB*TT);

  score_gemm<<<dim3(7,32,NB),256,0,stream>>>(f1, tenc, fn2, tn2, logp);
  softmax_prior_k<<<NB*TF,128,0,stream>>>(logp, rowA, colA, sA, Z2);

  scan_k<<<2*NB,128,0,stream>>>(logp, Z2, cmpb, nll);
  masback_k<<<NB,256,0,stream>>>(cmpb, logp, ds, gsum);
  final_k<<<1,64,0,stream>>>(nll, gsum, out);
}

// Round 15
// 895.902 us; speedup vs baseline: 1.9750x; 1.0865x over previous
//
#include <hip/hip_runtime.h>
#include <math.h>

typedef unsigned int u32;
typedef unsigned long long u64;
typedef unsigned short u16;
typedef __attribute__((ext_vector_type(8))) _Float16 f16x8;  // 8 fp16 (4 VGPR)
typedef __attribute__((ext_vector_type(4))) float f32x4;

#define BIGN (-1e30f)

static constexpr int NB = 16;     // batch
static constexpr int TF = 2000;   // T_FEATS
static constexpr int TT = 400;    // T_TEXT

__device__ __forceinline__ float wsum(float v){
#pragma unroll
  for(int o=32;o;o>>=1) v += __shfl_xor(v,o,64);
  return v;
}
__device__ __forceinline__ float EXP2(float x){ return __builtin_amdgcn_exp2f(x); }
__device__ __forceinline__ float LOG2(float x){ return __builtin_amdgcn_logf(x); }
__device__ __forceinline__ float lse2b(float x, float y){
  float m = fmaxf(x,y);
  return m + LOG2(1.0f + EXP2(-fabsf(x-y)));
}
__device__ __forceinline__ float lse3b(float x, float y, float z){
  float mx = fmaxf(fmaxf(x,y),z);
  float md = __builtin_amdgcn_fmed3f(x,y,z);
  float mn = fminf(fminf(x,y),z);
  return mx + LOG2(1.0f + EXP2(md-mx) + EXP2(mn-mx));
}
__device__ __forceinline__ u16 f2h(float v){
  _Float16 h = (_Float16)v;              // round-nearest-even
  return *(u16*)&h;
}

// ---------------- gammaln tables ----------------
__global__ void k_lgt(double* lgt){
  int m = blockIdx.x*blockDim.x + threadIdx.x;
  if(m < 2432) lgt[m] = (m>=1)? lgamma((double)m) : 0.0;
}
__global__ void k_terms(const double* __restrict__ lgt, double* rowA, double* colA, double* sA){
  int i = blockIdx.x*blockDim.x + threadIdx.x;
  if(i < TF)   rowA[i] = -lgt[2401] - lgt[i+1] - lgt[2000-i] + lgt[2001];
  if(i < TT)   colA[i] =  lgt[401]  - lgt[i+2] - lgt[400-i];
  if(i < 2399) sA[i]   =  lgt[i+2]  + lgt[2399-i];
}

// ---------------- consolidated prep: 5 weight packs + txt cvt + zpad(tout1,out1) ----------------
__device__ __forceinline__ void packf(const float* __restrict__ w, u16* __restrict__ dst,
    int CIN, int KW, int i){
  int k = i % KW;
  int c = (i / KW) % CIN;
  int o = i / (KW*CIN);
  dst[((size_t)k*256 + o)*CIN + c] = f2h(w[i]);
}
__device__ __forceinline__ void cvtp(const float* __restrict__ src, u16* __restrict__ dst,
    int P, int C, int i){
  int c = i % C;
  int p = (i / C) % (P+2);
  int b = i / (C*(P+2));
  float v = 0.f;
  if(p>=1 && p<=P) v = src[((size_t)b*P + (p-1))*C + c];
  dst[i] = f2h(v);
}
__device__ __forceinline__ void zpr(u16* __restrict__ buf, int P, int j){
  int c = j % 256;
  int s = (j / 256) & 1;
  int b = j / 512;
  buf[((size_t)b*(P+2) + (s? P+1 : 0))*256 + c] = 0;
}
__global__ __launch_bounds__(256) void prep1_k(
    const float* __restrict__ fw1, const float* __restrict__ fw2, const float* __restrict__ fw3,
    const float* __restrict__ tw1, const float* __restrict__ tw2, const float* __restrict__ txt,
    u16* fw1p, u16* fw2p, u16* fw3p, u16* tw1p, u16* tw2p,
    u16* inbfT, u16* tout1, u16* out1){
  constexpr int N = 393216+196608+65536+196608+65536+1646592+8192+8192;
  for(int i = blockIdx.x*256 + threadIdx.x; i < N; i += gridDim.x*256){
    int j = i;
    if(j < 393216){ packf(fw1, fw1p, 512, 3, j); continue; } j -= 393216;
    if(j < 196608){ packf(fw2, fw2p, 256, 3, j); continue; } j -= 196608;
    if(j < 65536) { packf(fw3, fw3p, 256, 1, j); continue; } j -= 65536;
    if(j < 196608){ packf(tw1, tw1p, 256, 3, j); continue; } j -= 196608;
    if(j < 65536) { packf(tw2, tw2p, 256, 1, j); continue; } j -= 65536;
    if(j < 1646592){ cvtp(txt, inbfT, TT, 256, j); continue; } j -= 1646592;
    if(j < 8192) { zpr(tout1, TT, j); continue; } j -= 8192;
    zpr(out1, TF, j);
  }
}

// ---------------- fp32 -> padded fp16 (rows 0 and P+1 zero) ----------------
__global__ __launch_bounds__(256) void cvt_pad_k(const float* __restrict__ src, u16* __restrict__ dst,
    int P, int C){
  int n = NB*(P+2)*C;
  for(int i = blockIdx.x*256 + threadIdx.x; i < n; i += gridDim.x*256) cvtp(src, dst, P, C, i);
}
// ---------------- zero pad rows (0 and P+1) ----------------
__global__ __launch_bounds__(256) void zpad_k(u16* __restrict__ buf, int P){
  int n = NB*2*256;
  for(int i = blockIdx.x*256 + threadIdx.x; i < n; i += gridDim.x*256) zpr(buf, P, i);
}

// ---------------- conv1d via MFMA fp16 ----------------
// out[p][o] = bias[o] + sum_{k,c} in[p+k-pad][c] * w[o][c][k],  pad=(KW-1)/2
// Tile: BM=64 x BN=256, BK=32. 4 waves. LDS group-major, conflict-free b128 ops.
template<int CIN, int KW, bool RELU, bool OBF>
__global__ __launch_bounds__(256) void mfconv_k(const u16* __restrict__ inb,
    const u16* __restrict__ wp, const float* __restrict__ bias, void* __restrict__ outp, int P){
  __shared__ __align__(16) u16 Al[4*66*8];            // 4224 B
  __shared__ __align__(16) u16 Bl[KW*4*256*8];        // KW3: 49152 B, KW1: 16384 B
  const int b = blockIdx.y;
  const int m0 = blockIdx.x * 64;
  const int tid = threadIdx.x;
  const int lane = tid & 63, wv = tid >> 6;
  const int lo16 = lane & 15, hi = lane >> 4;
  constexpr int K1 = (KW==1)? 1 : 0;
  const u16* inB = inb + (size_t)b*(P+2)*CIN;
  f32x4 acc[4][4];
#pragma unroll
  for(int i=0;i<4;i++)
#pragma unroll
    for(int j=0;j<4;j++) acc[i][j] = (f32x4){0.f,0.f,0.f,0.f};

  for(int c0=0; c0<CIN; c0+=32){
    __syncthreads();
    // stage A: 66 window rows x 32 ch (4 groups of 8) = 264 pairs, strided over 256 threads
    for(int idx = tid; idx < 264; idx += 256){
      int r = idx >> 2, q = idx & 3;
      int rowp = m0 + r;
      f16x8 v = (f16x8){0,0,0,0,0,0,0,0};
      if(rowp <= P+1) v = *(const f16x8*)&inB[(size_t)rowp*CIN + c0 + q*8];
      *(f16x8*)&Al[(q*66 + r)*8] = v;
    }
    // stage B: per k, 256 o-rows x 32 ch
#pragma unroll
    for(int k=0;k<KW;k++){
      const u16* wr = &wp[((size_t)(k*256) + tid)*CIN + c0];
      f16x8 w0 = *(const f16x8*)&wr[0];
      f16x8 w1 = *(const f16x8*)&wr[8];
      f16x8 w2 = *(const f16x8*)&wr[16];
      f16x8 w3 = *(const f16x8*)&wr[24];
      *(f16x8*)&Bl[((k*4+0)*256 + tid)*8] = w0;
      *(f16x8*)&Bl[((k*4+1)*256 + tid)*8] = w1;
      *(f16x8*)&Bl[((k*4+2)*256 + tid)*8] = w2;
      *(f16x8*)&Bl[((k*4+3)*256 + tid)*8] = w3;
    }
    __syncthreads();
#pragma unroll
    for(int k=0;k<KW;k++){
      f16x8 af[4];
#pragma unroll
      for(int rf=0;rf<4;rf++)
        af[rf] = *(const f16x8*)&Al[(hi*66 + rf*16 + lo16 + k + K1)*8];
#pragma unroll
      for(int cf=0;cf<4;cf++){
        int o = wv*64 + cf*16 + lo16;
        f16x8 bf = *(const f16x8*)&Bl[((k*4+hi)*256 + o)*8];
#pragma unroll
        for(int rf=0;rf<4;rf++)
          acc[rf][cf] = __builtin_amdgcn_mfma_f32_16x16x32_f16(af[rf], bf, acc[rf][cf], 0, 0, 0);
      }
    }
  }
#pragma unroll
  for(int cf=0;cf<4;cf++){
    int o = wv*64 + cf*16 + lo16;
    float bs = bias[o];
#pragma unroll
    for(int rf=0;rf<4;rf++){
#pragma unroll
      for(int j=0;j<4;j++){
        int p = m0 + rf*16 + hi*4 + j;
        if(p < P){
          float v = acc[rf][cf][j] + bs;
          if(RELU) v = fmaxf(v, 0.f);
          if(OBF) ((u16*)outp)[((size_t)b*(P+2) + p + 1)*256 + o] = f2h(v);
          else    ((float*)outp)[((size_t)b*P + p)*256 + o] = v;
        }
      }
    }
  }
}

// ---------------- row squared norms (f1 and tenc merged) ----------------
__global__ __launch_bounds__(256) void norm2b_k(const float* __restrict__ x1, const float* __restrict__ x2,
    float* __restrict__ o1, float* __restrict__ o2){
  int r = blockIdx.x*4 + (threadIdx.x>>6);
  int lane = threadIdx.x & 63;
  const float* src; float* dst; int rr;
  if(r < NB*TF){ src = x1; dst = o1; rr = r; }
  else { rr = r - NB*TF; if(rr >= NB*TT) return; src = x2; dst = o2; }
  float4 v = ((const float4*)(src + (size_t)rr*256))[lane];
  float s = v.x*v.x + v.y*v.y + v.z*v.z + v.w*v.w;
  s = wsum(s);
  if(lane==0) dst[rr] = s;
}

// ---------------- score = -sqrt(max(||f||^2+||t||^2-2 f.t, 1e-12)) ----------------
__global__ __launch_bounds__(256) void score_gemm(const float* __restrict__ F, const float* __restrict__ Tn,
    const float* __restrict__ fn2, const float* __restrict__ tn2, float* __restrict__ outp){
  constexpr int KC = 32;
  __shared__ __align__(16) float As[KC][68];
  __shared__ __align__(16) float Bs[KC][68];
  const int b = blockIdx.z;
  const int t0 = blockIdx.y*64, s0 = blockIdx.x*64;
  const int tid = threadIdx.x, tx = tid&15, ty = tid>>4;
  const float* Fb = F  + (size_t)b*TF*256;
  const float* Tb = Tn + (size_t)b*TT*256;
  float acc[4][4] = {};
  const int lk = tid & 31, lt0 = (tid>>5)*8;
  for(int k0=0;k0<256;k0+=KC){
    __syncthreads();
#pragma unroll
    for(int i=0;i<8;i++){
      int t = t0 + lt0 + i;
      As[lk][lt0+i] = (t<TF)? Fb[(size_t)t*256 + k0 + lk] : 0.f;
      int s = s0 + lt0 + i;
      Bs[lk][lt0+i] = (s<TT)? Tb[(size_t)s*256 + k0 + lk] : 0.f;
    }
    __syncthreads();
#pragma unroll
    for(int k=0;k<KC;k++){
      float a0[4], b0[4];
      *(float4*)a0 = *(const float4*)&As[k][ty*4];
      *(float4*)b0 = *(const float4*)&Bs[k][tx*4];
#pragma unroll
      for(int i=0;i<4;i++)
#pragma unroll
        for(int j=0;j<4;j++) acc[i][j] = fmaf(a0[i], b0[j], acc[i][j]);
    }
  }
#pragma unroll
  for(int i=0;i<4;i++){
    int t = t0 + ty*4 + i;
    if(t<TF){
      float fn = fn2[b*TF + t];
#pragma unroll
      for(int j=0;j<4;j++){
        int s = s0 + tx*4 + j;
        if(s<TT){
          float d2 = fn + tn2[b*TT + s] - 2.f*acc[i][j];
          outp[((size_t)b*TF + t)*TT + s] = -sqrtf(fmaxf(d2, 1e-12f));
        }
      }
    }
  }
}

// ---------------- per-row log_softmax + prior, and Z2 = logsumexp([BLANK, row]) ----------------
__global__ __launch_bounds__(128) void softmax_prior_k(float* __restrict__ logp,
    const double* __restrict__ rowA, const double* __restrict__ colA, const double* __restrict__ sA,
    float* __restrict__ Z2){
  const int row = blockIdx.x;           // b*TF + t0
  const int t0 = row % TF;
  float* rp = logp + (size_t)row*TT;
  const int tid = threadIdx.x;
  __shared__ float sh2[2];
  float v[4]; int ix[4];
#pragma unroll
  for(int i=0;i<4;i++){ ix[i] = tid + i*128; v[i] = (ix[i]<TT)? rp[ix[i]] : BIGN; }
  float m = fmaxf(fmaxf(v[0],v[1]),fmaxf(v[2],v[3]));
#pragma unroll
  for(int o=32;o;o>>=1) m = fmaxf(m, __shfl_xor(m,o,64));
  if((tid&63)==0) sh2[tid>>6] = m;
  __syncthreads();
  m = fmaxf(sh2[0], sh2[1]);
  float s = 0.f;
#pragma unroll
  for(int i=0;i<4;i++) if(ix[i]<TT) s += __expf(v[i]-m);
  s = wsum(s);
  __syncthreads();
  if((tid&63)==0) sh2[tid>>6] = s;
  __syncthreads();
  s = sh2[0] + sh2[1];
  const float lse = m + __logf(s);
  const double rA = rowA[t0];
  float f[4]; float m2 = BIGN;
#pragma unroll
  for(int i=0;i<4;i++){
    if(ix[i]<TT){
      float pr = (float)(colA[ix[i]] + sA[t0+ix[i]] + rA);
      f[i] = (v[i]-lse) + pr;
      rp[ix[i]] = f[i];
      m2 = fmaxf(m2, f[i]);
    } else f[i] = BIGN;
  }
#pragma unroll
  for(int o=32;o;o>>=1) m2 = fmaxf(m2, __shfl_xor(m2,o,64));
  __syncthreads();
  if((tid&63)==0) sh2[tid>>6] = m2;
  __syncthreads();
  m2 = fmaxf(fmaxf(sh2[0],sh2[1]), -1.0f);
  float s2 = (tid==0)? __expf(-1.0f - m2) : 0.f;
#pragma unroll
  for(int i=0;i<4;i++) if(ix[i]<TT) s2 += __expf(f[i]-m2);
  s2 = wsum(s2);
  __syncthreads();
  if((tid&63)==0) sh2[tid>>6] = s2;
  __syncthreads();
  if(tid==0) Z2[row] = m2 + __logf(sh2[0]+sh2[1]);
}

// ---------------- scans ----------------
// CTC step, pairwise-factored (EXACT): lse3b(x,y,z) == lse2b(x, lse2b(y,z)), and the inner
// lse2b(y,z) IS the even state's update value w. 28 trans/step (was 35), ~60 VALU (was ~105).
#define LCTC_STEP(E) { \
  float n1 = __shfl_up(a[13], 1); \
  if(lane==0) n1 = BIGN; \
  float w6 = lse2b(a[12], a[11]); \
  a[13] = lse2b(a[13], w6) + (E)[6];  a[12] = w6 + EBL; \
  float w5 = lse2b(a[10], a[9]); \
  a[11] = lse2b(a[11], w5) + (E)[5];  a[10] = w5 + EBL; \
  float w4 = lse2b(a[8], a[7]); \
  a[9]  = lse2b(a[9],  w4) + (E)[4];  a[8]  = w4 + EBL; \
  float w3 = lse2b(a[6], a[5]); \
  a[7]  = lse2b(a[7],  w3) + (E)[3];  a[6]  = w3 + EBL; \
  float w2 = lse2b(a[4], a[3]); \
  a[5]  = lse2b(a[5],  w2) + (E)[2];  a[4]  = w2 + EBL; \
  float w1 = lse2b(a[2], a[1]); \
  a[3]  = lse2b(a[3],  w1) + (E)[1];  a[2]  = w1 + EBL; \
  float w0 = lse2b(a[0], n1); \
  a[1]  = lse2b(a[1],  w0) + (E)[0];  a[0]  = w0 + EBL; }

#define CPREF(E, K) { int kk=(K); if(kk>999) kk=999; int row = dir? (TF-1-kk) : kk; \
  const float* rpp = lp + (size_t)row*TT; \
  (E)[0]=rpp[jc[0]]*IL2; (E)[1]=rpp[jc[1]]*IL2; (E)[2]=rpp[jc[2]]*IL2; (E)[3]=rpp[jc[3]]*IL2; \
  (E)[4]=rpp[jc[4]]*IL2; (E)[5]=rpp[jc[5]]*IL2; (E)[6]=rpp[jc[6]]*IL2; }

#define MAS_STEP(E, TIDX) { \
  float n1 = __shfl_up(q[6],1); \
  u32 byte = 0; \
  if(lane>0 && n1 >= q[0]) byte |= 1u; \
  if(q[0] >= q[1]) byte |= 2u; \
  if(q[1] >= q[2]) byte |= 4u; \
  if(q[2] >= q[3]) byte |= 8u; \
  if(q[3] >= q[4]) byte |= 16u; \
  if(q[4] >= q[5]) byte |= 32u; \
  if(q[5] >= q[6]) byte |= 64u; \
  cb[(size_t)((TIDX)-1)*64 + lane] = (unsigned char)byte; \
  q[6] = fmaxf(q[6], q[5]) + (E)[6]; \
  q[5] = fmaxf(q[5], q[4]) + (E)[5]; \
  q[4] = fmaxf(q[4], q[3]) + (E)[4]; \
  q[3] = fmaxf(q[3], q[2]) + (E)[3]; \
  q[2] = fmaxf(q[2], q[1]) + (E)[2]; \
  q[1] = fmaxf(q[1], q[0]) + (E)[1]; \
  q[0] = fmaxf(q[0], (lane>0)? n1 : BIGN) + (E)[0]; }

#define MPREF(E, ROW) { int rr=(ROW); rr = (rr>TF-1)? (TF-1) : rr; const float* rpp = lp + (size_t)rr*TT; \
  (E)[0]=rpp[jc[0]]; (E)[1]=rpp[jc[1]]; (E)[2]=rpp[jc[2]]; (E)[3]=rpp[jc[3]]; \
  (E)[4]=rpp[jc[4]]; (E)[5]=rpp[jc[5]]; (E)[6]=rpp[jc[6]]; }

__global__ __launch_bounds__(128) __attribute__((amdgpu_waves_per_eu(1,1)))
void scan_k(const float* __restrict__ logp,
    const float* __restrict__ Z2, unsigned char* __restrict__ cmpb, float* __restrict__ nll){
  const int lane = threadIdx.x & 63;
  const int wave = threadIdx.x >> 6;
  constexpr float IL2 = 1.4426950408889634f;
  constexpr float L2  = 0.6931471805599453f;
  if(blockIdx.x < NB){
    const int b = blockIdx.x;
    const float* lp = logp + (size_t)b*TF*TT;
    __shared__ float af[801], ag[801];
    const int dir = wave;
    double zs = 0.0;
    if(wave==0){
      for(int t=lane; t<TF; t+=64) zs += (double)Z2[b*TF + t];
#pragma unroll
      for(int o=32;o;o>>=1) zs += __shfl_xor(zs, o, 64);
    }
    int jc[7];
#pragma unroll
    for(int i=0;i<7;i++){ int j = 7*lane + i; j = (j < TT)? j : (TT-1); jc[i] = dir? (TT-1-j) : j; }
    float a[14];
#pragma unroll
    for(int i=0;i<14;i++) a[i] = BIGN;
    if(lane==0){
      a[0] = -1.0f*IL2;
      a[1] = (dir? lp[(size_t)(TF-1)*TT + (TT-1)] : lp[0]) * IL2;
    }
    const float EBL = -1.0f*IL2;
    float e0[7],e1[7],e2[7],e3[7],e4[7],e5[7],e6[7],e7[7];
    CPREF(e0,1); CPREF(e1,2); CPREF(e2,3); CPREF(e3,4);
    CPREF(e4,5); CPREF(e5,6); CPREF(e6,7); CPREF(e7,8);
    int k = 1;
    for(; k + 8 <= 993; k += 8){
      LCTC_STEP(e0); CPREF(e0, k+8);
      LCTC_STEP(e1); CPREF(e1, k+9);
      LCTC_STEP(e2); CPREF(e2, k+10);
      LCTC_STEP(e3); CPREF(e3, k+11);
      LCTC_STEP(e4); CPREF(e4, k+12);
      LCTC_STEP(e5); CPREF(e5, k+13);
      LCTC_STEP(e6); CPREF(e6, k+14);
      LCTC_STEP(e7); CPREF(e7, k+15);
    }
    for(; k<=999; k++){
      float P[7];
      CPREF(P, k);
      LCTC_STEP(P);
    }
    float* dst = wave? ag : af;
#pragma unroll
    for(int i=0;i<14;i++){ int s = 14*lane+i; if(s<=800) dst[s] = a[i]; }
    __syncthreads();
    if(wave==0){
      float acc = BIGN;
#pragma unroll
      for(int i=0;i<14;i++){
        int s = 14*lane+i;
        if(s<=800){
          float x0 = af[s];
          float x1 = (s>=1)? af[s-1] : BIGN;
          float x2 = ((s&1) && s>=3)? af[s-2] : BIGN;
          float A1 = lse3b(x0,x1,x2);
          acc = lse2b(acc, A1 + ag[800-s]);
        }
      }
#pragma unroll
      for(int o=32;o;o>>=1) acc = lse2b(acc, __shfl_xor(acc,o,64));
      if(lane==0) nll[b] = -((acc*L2) - (float)zs);
    }
  } else {
    if(wave) return;
    const int b = blockIdx.x - NB;
    const float* lp = logp + (size_t)b*TF*TT;
    unsigned char* cb = cmpb + (size_t)b*TF*64;
    int jc[7];
#pragma unroll
    for(int i=0;i<7;i++){ int j = 7*lane + i; jc[i] = (j < TT)? j : (TT-1); }
    float q[7];
#pragma unroll
    for(int i=0;i<7;i++) q[i] = BIGN;
    if(lane==0) q[0] = lp[0];
    float e0[7],e1[7],e2[7],e3[7];
    MPREF(e0,1); MPREF(e1,2); MPREF(e2,3); MPREF(e3,4);
    int t0 = 1;
    for(; t0 + 4 <= TF; t0 += 4){
      MAS_STEP(e0, t0);   MPREF(e0, t0+4);
      MAS_STEP(e1, t0+1); MPREF(e1, t0+5);
      MAS_STEP(e2, t0+2); MPREF(e2, t0+6);
      MAS_STEP(e3, t0+3); MPREF(e3, t0+7);
    }
    for(; t0<TF; t0++){
      float P[7];
      MPREF(P, t0);
      MAS_STEP(P, t0);
    }
    {
      float n1 = __shfl_up(q[6],1);
      u32 byte = 0;
      if(lane>0 && n1 >= q[0]) byte |= 1u;
      if(q[0] >= q[1]) byte |= 2u;
      if(q[1] >= q[2]) byte |= 4u;
      if(q[2] >= q[3]) byte |= 8u;
      if(q[3] >= q[4]) byte |= 16u;
      if(q[4] >= q[5]) byte |= 32u;
      if(q[5] >= q[6]) byte |= 64u;
      cb[(size_t)(TF-1)*64 + lane] = (unsigned char)byte;
    }
  }
}

// ---------------- MAS backtrack + ds + gather ----------------
__global__ __launch_bounds__(256) void masback_k(const unsigned char* __restrict__ cmpb,
    const float* __restrict__ logp, float* __restrict__ ds, float* __restrict__ gsum){
  const int b = blockIdx.x;
  const unsigned char* cb = cmpb + (size_t)b*TF*64;
  __shared__ unsigned char bits[500*64];
  __shared__ short Ash[TF];
  __shared__ int cnt[TT];
  __shared__ float ps[4];
  int a = TT-1;
  for(int ch=3; ch>=0; ch--){
    const int tlo = ch*500;
    __syncthreads();
    for(int i=threadIdx.x;i<8000;i+=256) ((u32*)bits)[i] = ((const u32*)(cb + (size_t)tlo*64))[i];
    __syncthreads();
    if(threadIdx.x==0){
      int thi = tlo + 499;
      if(ch==3){ Ash[TF-1] = (short)(TT-1); thi = TF-2; }
      for(int t=thi;t>=tlo;t--){
        if(a > 0){
          unsigned char w = bits[(t-tlo)*64 + a/7];
          a -= (int)((w >> (a%7)) & 1u);
        }
        Ash[t] = (short)a;
      }
    }
  }
  __syncthreads();
  for(int i=threadIdx.x;i<TT;i+=256) cnt[i]=0;
  __syncthreads();
  float part = 0.f;
  const float* lp = logp + (size_t)b*TF*TT;
  for(int t=threadIdx.x;t<TF;t+=256){
    int at = Ash[t];
    atomicAdd(&cnt[at], 1);
    part += lp[(size_t)t*TT + at];
  }
  __syncthreads();
  for(int i=threadIdx.x;i<TT;i+=256) ds[(size_t)b*TT + i] = (float)cnt[i];
  part = wsum(part);
  if((threadIdx.x&63)==0) ps[threadIdx.x>>6] = part;
  __syncthreads();
  if(threadIdx.x==0) gsum[b] = ps[0]+ps[1]+ps[2]+ps[3];
}

__global__ void final_k(const float* __restrict__ nll, const float* __restrict__ gsum, float* __restrict__ out){
  if(threadIdx.x==0 && blockIdx.x==0){
    float fs=0.f, bs=0.f;
    for(int b=0;b<NB;b++){ fs += nll[b] / (float)TT; bs += gsum[b] / (float)TF; }
    out[6400] = -(bs / (float)NB);   // bin_loss
    out[6401] = fs / (float)NB;      // forwardsum_loss
  }
}

extern "C" void kernel_launch(void* const* d_in, const int* in_sizes, int n_in,
                              void* d_out, int out_size, void* d_ws, size_t ws_size,
                              hipStream_t stream){
  const float* speech = (const float*)d_in[0];
  const float* txt    = (const float*)d_in[1];
  const float* tw1 = (const float*)d_in[4];
  const float* tb1 = (const float*)d_in[5];
  const float* tw2 = (const float*)d_in[6];
  const float* tb2 = (const float*)d_in[7];
  const float* fw1 = (const float*)d_in[8];
  const float* fb1 = (const float*)d_in[9];
  const float* fw2 = (const float*)d_in[10];
  const float* fb2 = (const float*)d_in[11];
  const float* fw3 = (const float*)d_in[12];
  const float* fb3 = (const float*)d_in[13];
  float* out  = (float*)d_out;
  float* ds   = out;                 // (16,400)
  float* logp = out + 6402;          // (16,2000,400) -- also conv scratch until score_gemm
  char* ws = (char*)d_ws;
  double* lgt  = (double*)(ws + 0);
  double* rowA = (double*)(ws + 20480);
  double* colA = (double*)(ws + 36864);
  double* sA   = (double*)(ws + 40960);
  float*  nll  = (float*)(ws + 61440);
  float*  gsum = (float*)(ws + 61696);
  float*  Z2   = (float*)(ws + 65536);
  float*  fn2  = (float*)(ws + 196608);
  float*  tn2  = (float*)(ws + 327680);
  unsigned char* cmpb = (unsigned char*)(ws + 360448);
  float*  tenc = (float*)(ws + 2408448);
  float*  f1   = (float*)(ws + 8962048);   // f_enc fp32 (16,2000,256)
  if(ws_size < 41730048) return;

  // conv scratch inside the (dead until score_gemm) logp region; 256B-aligned base
  char* lr = (char*)(((uintptr_t)logp + 255) & ~(uintptr_t)255);
  u16* inbfT = (u16*)lr;                    // (16,402,256)  3.29MB   [txt phase]
  u16* tout1 = (u16*)(lr + 4000000);        // (16,402,256)  3.29MB   [txt phase]
  u16* inbfA = (u16*)lr;                    // (16,2002,512) 32.80MB  [f phase 1; AFTER txt phase]
  u16* out2  = (u16*)lr;                    // (16,2002,256) 16.40MB  [f phase 3, after inbfA dead]
  u16* wbase = (u16*)(lr + 32900000);       // packs, 1.84MB, live all conv phases
  u16* fw1p = wbase;
  u16* fw2p = wbase + 393216;
  u16* fw3p = wbase + 589824;
  u16* tw1p = wbase + 655360;
  u16* tw2p = wbase + 851968;
  u16* out1  = (u16*)(lr + 34750000);       // (16,2002,256) 16.40MB

  k_lgt  <<<10,256,0,stream>>>(lgt);
  k_terms<<<10,256,0,stream>>>(lgt,rowA,colA,sA);

  // consolidated prep: weight packs + txt convert + zpad(tout1,out1)
  prep1_k<<<2048,256,0,stream>>>(fw1,fw2,fw3,tw1,tw2, txt,
                                 fw1p,fw2p,fw3p,tw1p,tw2p, inbfT, tout1, out1);

  // txt path
  mfconv_k<256,3,true ,true ><<<dim3(7,NB),256,0,stream>>>(inbfT, tw1p, tb1, tout1, TT);
  mfconv_k<256,1,false,false><<<dim3(7,NB),256,0,stream>>>(tout1, tw2p, tb2, tenc, TT);

  // f path (speech convert must run AFTER txt phase: inbfA overlaps inbfT/tout1)
  cvt_pad_k<<<4096,256,0,stream>>>(speech, inbfA, TF, 512);
  mfconv_k<512,3,true ,true ><<<dim3(32,NB),256,0,stream>>>(inbfA, fw1p, fb1, out1, TF);
  zpad_k<<<32,256,0,stream>>>(out2, TF);               // after fconv1: inbfA region dead
  mfconv_k<256,3,true ,true ><<<dim3(32,NB),256,0,stream>>>(out1, fw2p, fb2, out2, TF);
  mfconv_k<256,1,false,false><<<dim3(32,NB),256,0,stream>>>(out2, fw3p, fb3, f1, TF);

  norm2b_k<<<(NB*TF+NB*TT)/4,256,0,stream>>>(f1, tenc, fn2, tn2);

  score_gemm<<<dim3(7,32,NB),256,0,stream>>>(f1, tenc, fn2, tn2, logp);
  softmax_prior_k<<<NB*TF,128,0,stream>>>(logp, rowA, colA, sA, Z2);

  scan_k<<<2*NB,128,0,stream>>>(logp, Z2, cmpb, nll);
  masback_k<<<NB,256,0,stream>>>(cmpb, logp, ds, gsum);
  final_k<<<1,64,0,stream>>>(nll, gsum, out);
}

// Round 16
// 883.043 us; speedup vs baseline: 2.0038x; 1.0146x over previous
//
#include <hip/hip_runtime.h>
#include <math.h>

typedef unsigned int u32;
typedef unsigned long long u64;
typedef unsigned short u16;
typedef __attribute__((ext_vector_type(8))) _Float16 f16x8;  // 8 fp16 (4 VGPR)
typedef __attribute__((ext_vector_type(4))) float f32x4;

#define BIGN (-1e30f)

static constexpr int NB = 16;     // batch
static constexpr int TF = 2000;   // T_FEATS
static constexpr int TT = 400;    // T_TEXT

__device__ __forceinline__ float wsum(float v){
#pragma unroll
  for(int o=32;o;o>>=1) v += __shfl_xor(v,o,64);
  return v;
}
__device__ __forceinline__ float EXP2(float x){ return __builtin_amdgcn_exp2f(x); }
__device__ __forceinline__ float LOG2(float x){ return __builtin_amdgcn_logf(x); }
__device__ __forceinline__ float lse2b(float x, float y){
  float m = fmaxf(x,y);
  return m + LOG2(1.0f + EXP2(-fabsf(x-y)));
}
__device__ __forceinline__ float lse3b(float x, float y, float z){
  float mx = fmaxf(fmaxf(x,y),z);
  float md = __builtin_amdgcn_fmed3f(x,y,z);
  float mn = fminf(fminf(x,y),z);
  return mx + LOG2(1.0f + EXP2(md-mx) + EXP2(mn-mx));
}
__device__ __forceinline__ u16 f2h(float v){
  _Float16 h = (_Float16)v;              // round-nearest-even
  return *(u16*)&h;
}
// lane i <- lane i-1, lane 0 <- BIGN. DPP wave_shr1 (0x138): pure VALU, no LDS/lgkmcnt.
__device__ __forceinline__ float shup1(float v){
  int r = __builtin_amdgcn_update_dpp(__float_as_int(BIGN), __float_as_int(v),
                                      0x138, 0xf, 0xf, false);
  return __int_as_float(r);
}

// ---------------- gammaln tables ----------------
__global__ void k_lgt(double* lgt){
  int m = blockIdx.x*blockDim.x + threadIdx.x;
  if(m < 2432) lgt[m] = (m>=1)? lgamma((double)m) : 0.0;
}
__global__ void k_terms(const double* __restrict__ lgt, double* rowA, double* colA, double* sA){
  int i = blockIdx.x*blockDim.x + threadIdx.x;
  if(i < TF)   rowA[i] = -lgt[2401] - lgt[i+1] - lgt[2000-i] + lgt[2001];
  if(i < TT)   colA[i] =  lgt[401]  - lgt[i+2] - lgt[400-i];
  if(i < 2399) sA[i]   =  lgt[i+2]  + lgt[2399-i];
}

// ---------------- consolidated prep: 5 weight packs + txt cvt + zpad(tout1,out1) ----------------
__device__ __forceinline__ void packf(const float* __restrict__ w, u16* __restrict__ dst,
    int CIN, int KW, int i){
  int k = i % KW;
  int c = (i / KW) % CIN;
  int o = i / (KW*CIN);
  dst[((size_t)k*256 + o)*CIN + c] = f2h(w[i]);
}
__device__ __forceinline__ void cvtp(const float* __restrict__ src, u16* __restrict__ dst,
    int P, int C, int i){
  int c = i % C;
  int p = (i / C) % (P+2);
  int b = i / (C*(P+2));
  float v = 0.f;
  if(p>=1 && p<=P) v = src[((size_t)b*P + (p-1))*C + c];
  dst[i] = f2h(v);
}
__device__ __forceinline__ void zpr(u16* __restrict__ buf, int P, int j){
  int c = j % 256;
  int s = (j / 256) & 1;
  int b = j / 512;
  buf[((size_t)b*(P+2) + (s? P+1 : 0))*256 + c] = 0;
}
__global__ __launch_bounds__(256) void prep1_k(
    const float* __restrict__ fw1, const float* __restrict__ fw2, const float* __restrict__ fw3,
    const float* __restrict__ tw1, const float* __restrict__ tw2, const float* __restrict__ txt,
    u16* fw1p, u16* fw2p, u16* fw3p, u16* tw1p, u16* tw2p,
    u16* inbfT, u16* tout1, u16* out1){
  constexpr int N = 393216+196608+65536+196608+65536+1646592+8192+8192;
  for(int i = blockIdx.x*256 + threadIdx.x; i < N; i += gridDim.x*256){
    int j = i;
    if(j < 393216){ packf(fw1, fw1p, 512, 3, j); continue; } j -= 393216;
    if(j < 196608){ packf(fw2, fw2p, 256, 3, j); continue; } j -= 196608;
    if(j < 65536) { packf(fw3, fw3p, 256, 1, j); continue; } j -= 65536;
    if(j < 196608){ packf(tw1, tw1p, 256, 3, j); continue; } j -= 196608;
    if(j < 65536) { packf(tw2, tw2p, 256, 1, j); continue; } j -= 65536;
    if(j < 1646592){ cvtp(txt, inbfT, TT, 256, j); continue; } j -= 1646592;
    if(j < 8192) { zpr(tout1, TT, j); continue; } j -= 8192;
    zpr(out1, TF, j);
  }
}

// ---------------- fp32 -> padded fp16 (rows 0 and P+1 zero) ----------------
__global__ __launch_bounds__(256) void cvt_pad_k(const float* __restrict__ src, u16* __restrict__ dst,
    int P, int C){
  int n = NB*(P+2)*C;
  for(int i = blockIdx.x*256 + threadIdx.x; i < n; i += gridDim.x*256) cvtp(src, dst, P, C, i);
}
// ---------------- zero pad rows (0 and P+1) ----------------
__global__ __launch_bounds__(256) void zpad_k(u16* __restrict__ buf, int P){
  int n = NB*2*256;
  for(int i = blockIdx.x*256 + threadIdx.x; i < n; i += gridDim.x*256) zpr(buf, P, i);
}

// ---------------- conv1d via MFMA fp16 ----------------
template<int CIN, int KW, bool RELU, bool OBF>
__global__ __launch_bounds__(256) void mfconv_k(const u16* __restrict__ inb,
    const u16* __restrict__ wp, const float* __restrict__ bias, void* __restrict__ outp, int P){
  __shared__ __align__(16) u16 Al[4*66*8];            // 4224 B
  __shared__ __align__(16) u16 Bl[KW*4*256*8];        // KW3: 49152 B, KW1: 16384 B
  const int b = blockIdx.y;
  const int m0 = blockIdx.x * 64;
  const int tid = threadIdx.x;
  const int lane = tid & 63, wv = tid >> 6;
  const int lo16 = lane & 15, hi = lane >> 4;
  constexpr int K1 = (KW==1)? 1 : 0;
  const u16* inB = inb + (size_t)b*(P+2)*CIN;
  f32x4 acc[4][4];
#pragma unroll
  for(int i=0;i<4;i++)
#pragma unroll
    for(int j=0;j<4;j++) acc[i][j] = (f32x4){0.f,0.f,0.f,0.f};

  for(int c0=0; c0<CIN; c0+=32){
    __syncthreads();
    for(int idx = tid; idx < 264; idx += 256){
      int r = idx >> 2, q = idx & 3;
      int rowp = m0 + r;
      f16x8 v = (f16x8){0,0,0,0,0,0,0,0};
      if(rowp <= P+1) v = *(const f16x8*)&inB[(size_t)rowp*CIN + c0 + q*8];
      *(f16x8*)&Al[(q*66 + r)*8] = v;
    }
#pragma unroll
    for(int k=0;k<KW;k++){
      const u16* wr = &wp[((size_t)(k*256) + tid)*CIN + c0];
      f16x8 w0 = *(const f16x8*)&wr[0];
      f16x8 w1 = *(const f16x8*)&wr[8];
      f16x8 w2 = *(const f16x8*)&wr[16];
      f16x8 w3 = *(const f16x8*)&wr[24];
      *(f16x8*)&Bl[((k*4+0)*256 + tid)*8] = w0;
      *(f16x8*)&Bl[((k*4+1)*256 + tid)*8] = w1;
      *(f16x8*)&Bl[((k*4+2)*256 + tid)*8] = w2;
      *(f16x8*)&Bl[((k*4+3)*256 + tid)*8] = w3;
    }
    __syncthreads();
#pragma unroll
    for(int k=0;k<KW;k++){
      f16x8 af[4];
#pragma unroll
      for(int rf=0;rf<4;rf++)
        af[rf] = *(const f16x8*)&Al[(hi*66 + rf*16 + lo16 + k + K1)*8];
#pragma unroll
      for(int cf=0;cf<4;cf++){
        int o = wv*64 + cf*16 + lo16;
        f16x8 bf = *(const f16x8*)&Bl[((k*4+hi)*256 + o)*8];
#pragma unroll
        for(int rf=0;rf<4;rf++)
          acc[rf][cf] = __builtin_amdgcn_mfma_f32_16x16x32_f16(af[rf], bf, acc[rf][cf], 0, 0, 0);
      }
    }
  }
#pragma unroll
  for(int cf=0;cf<4;cf++){
    int o = wv*64 + cf*16 + lo16;
    float bs = bias[o];
#pragma unroll
    for(int rf=0;rf<4;rf++){
#pragma unroll
      for(int j=0;j<4;j++){
        int p = m0 + rf*16 + hi*4 + j;
        if(p < P){
          float v = acc[rf][cf][j] + bs;
          if(RELU) v = fmaxf(v, 0.f);
          if(OBF) ((u16*)outp)[((size_t)b*(P+2) + p + 1)*256 + o] = f2h(v);
          else    ((float*)outp)[((size_t)b*P + p)*256 + o] = v;
        }
      }
    }
  }
}

// ---------------- row squared norms (f1 and tenc merged) ----------------
__global__ __launch_bounds__(256) void norm2b_k(const float* __restrict__ x1, const float* __restrict__ x2,
    float* __restrict__ o1, float* __restrict__ o2){
  int r = blockIdx.x*4 + (threadIdx.x>>6);
  int lane = threadIdx.x & 63;
  const float* src; float* dst; int rr;
  if(r < NB*TF){ src = x1; dst = o1; rr = r; }
  else { rr = r - NB*TF; if(rr >= NB*TT) return; src = x2; dst = o2; }
  float4 v = ((const float4*)(src + (size_t)rr*256))[lane];
  float s = v.x*v.x + v.y*v.y + v.z*v.z + v.w*v.w;
  s = wsum(s);
  if(lane==0) dst[rr] = s;
}

// ---------------- score = -sqrt(max(||f||^2+||t||^2-2 f.t, 1e-12)) ----------------
__global__ __launch_bounds__(256) void score_gemm(const float* __restrict__ F, const float* __restrict__ Tn,
    const float* __restrict__ fn2, const float* __restrict__ tn2, float* __restrict__ outp){
  constexpr int KC = 32;
  __shared__ __align__(16) float As[KC][68];
  __shared__ __align__(16) float Bs[KC][68];
  const int b = blockIdx.z;
  const int t0 = blockIdx.y*64, s0 = blockIdx.x*64;
  const int tid = threadIdx.x, tx = tid&15, ty = tid>>4;
  const float* Fb = F  + (size_t)b*TF*256;
  const float* Tb = Tn + (size_t)b*TT*256;
  float acc[4][4] = {};
  const int lk = tid & 31, lt0 = (tid>>5)*8;
  for(int k0=0;k0<256;k0+=KC){
    __syncthreads();
#pragma unroll
    for(int i=0;i<8;i++){
      int t = t0 + lt0 + i;
      As[lk][lt0+i] = (t<TF)? Fb[(size_t)t*256 + k0 + lk] : 0.f;
      int s = s0 + lt0 + i;
      Bs[lk][lt0+i] = (s<TT)? Tb[(size_t)s*256 + k0 + lk] : 0.f;
    }
    __syncthreads();
#pragma unroll
    for(int k=0;k<KC;k++){
      float a0[4], b0[4];
      *(float4*)a0 = *(const float4*)&As[k][ty*4];
      *(float4*)b0 = *(const float4*)&Bs[k][tx*4];
#pragma unroll
      for(int i=0;i<4;i++)
#pragma unroll
        for(int j=0;j<4;j++) acc[i][j] = fmaf(a0[i], b0[j], acc[i][j]);
    }
  }
#pragma unroll
  for(int i=0;i<4;i++){
    int t = t0 + ty*4 + i;
    if(t<TF){
      float fn = fn2[b*TF + t];
#pragma unroll
      for(int j=0;j<4;j++){
        int s = s0 + tx*4 + j;
        if(s<TT){
          float d2 = fn + tn2[b*TT + s] - 2.f*acc[i][j];
          outp[((size_t)b*TF + t)*TT + s] = -sqrtf(fmaxf(d2, 1e-12f));
        }
      }
    }
  }
}

// ---------------- per-row log_softmax + prior, and Z2 = logsumexp([BLANK, row]) ----------------
__global__ __launch_bounds__(128) void softmax_prior_k(float* __restrict__ logp,
    const double* __restrict__ rowA, const double* __restrict__ colA, const double* __restrict__ sA,
    float* __restrict__ Z2){
  const int row = blockIdx.x;           // b*TF + t0
  const int t0 = row % TF;
  float* rp = logp + (size_t)row*TT;
  const int tid = threadIdx.x;
  __shared__ float sh2[2];
  float v[4]; int ix[4];
#pragma unroll
  for(int i=0;i<4;i++){ ix[i] = tid + i*128; v[i] = (ix[i]<TT)? rp[ix[i]] : BIGN; }
  float m = fmaxf(fmaxf(v[0],v[1]),fmaxf(v[2],v[3]));
#pragma unroll
  for(int o=32;o;o>>=1) m = fmaxf(m, __shfl_xor(m,o,64));
  if((tid&63)==0) sh2[tid>>6] = m;
  __syncthreads();
  m = fmaxf(sh2[0], sh2[1]);
  float s = 0.f;
#pragma unroll
  for(int i=0;i<4;i++) if(ix[i]<TT) s += __expf(v[i]-m);
  s = wsum(s);
  __syncthreads();
  if((tid&63)==0) sh2[tid>>6] = s;
  __syncthreads();
  s = sh2[0] + sh2[1];
  const float lse = m + __logf(s);
  const double rA = rowA[t0];
  float f[4]; float m2 = BIGN;
#pragma unroll
  for(int i=0;i<4;i++){
    if(ix[i]<TT){
      float pr = (float)(colA[ix[i]] + sA[t0+ix[i]] + rA);
      f[i] = (v[i]-lse) + pr;
      rp[ix[i]] = f[i];
      m2 = fmaxf(m2, f[i]);
    } else f[i] = BIGN;
  }
#pragma unroll
  for(int o=32;o;o>>=1) m2 = fmaxf(m2, __shfl_xor(m2,o,64));
  __syncthreads();
  if((tid&63)==0) sh2[tid>>6] = m2;
  __syncthreads();
  m2 = fmaxf(fmaxf(sh2[0],sh2[1]), -1.0f);
  float s2 = (tid==0)? __expf(-1.0f - m2) : 0.f;
#pragma unroll
  for(int i=0;i<4;i++) if(ix[i]<TT) s2 += __expf(f[i]-m2);
  s2 = wsum(s2);
  __syncthreads();
  if((tid&63)==0) sh2[tid>>6] = s2;
  __syncthreads();
  if(tid==0) Z2[row] = m2 + __logf(sh2[0]+sh2[1]);
}

// ---------------- scans ----------------
// CTC step, pairwise-factored; neighbor handoff via DPP wave_shr1 (no LDS, no lgkmcnt).
#define LCTC_STEP(E) { \
  float n1 = shup1(a[13]); \
  float w6 = lse2b(a[12], a[11]); \
  a[13] = lse2b(a[13], w6) + (E)[6];  a[12] = w6 + EBL; \
  float w5 = lse2b(a[10], a[9]); \
  a[11] = lse2b(a[11], w5) + (E)[5];  a[10] = w5 + EBL; \
  float w4 = lse2b(a[8], a[7]); \
  a[9]  = lse2b(a[9],  w4) + (E)[4];  a[8]  = w4 + EBL; \
  float w3 = lse2b(a[6], a[5]); \
  a[7]  = lse2b(a[7],  w3) + (E)[3];  a[6]  = w3 + EBL; \
  float w2 = lse2b(a[4], a[3]); \
  a[5]  = lse2b(a[5],  w2) + (E)[2];  a[4]  = w2 + EBL; \
  float w1 = lse2b(a[2], a[1]); \
  a[3]  = lse2b(a[3],  w1) + (E)[1];  a[2]  = w1 + EBL; \
  float w0 = lse2b(a[0], n1); \
  a[1]  = lse2b(a[1],  w0) + (E)[0];  a[0]  = w0 + EBL; }

#define CPREF(E, K) { int kk=(K); if(kk>999) kk=999; int row = dir? (TF-1-kk) : kk; \
  const float* rpp = lp + (size_t)row*TT; \
  (E)[0]=rpp[jc[0]]*IL2; (E)[1]=rpp[jc[1]]*IL2; (E)[2]=rpp[jc[2]]*IL2; (E)[3]=rpp[jc[3]]*IL2; \
  (E)[4]=rpp[jc[4]]*IL2; (E)[5]=rpp[jc[5]]*IL2; (E)[6]=rpp[jc[6]]*IL2; }

#define MAS_STEP(E, TIDX) { \
  float n1 = shup1(q[6]); \
  u32 byte = 0; \
  if(lane>0 && n1 >= q[0]) byte |= 1u; \
  if(q[0] >= q[1]) byte |= 2u; \
  if(q[1] >= q[2]) byte |= 4u; \
  if(q[2] >= q[3]) byte |= 8u; \
  if(q[3] >= q[4]) byte |= 16u; \
  if(q[4] >= q[5]) byte |= 32u; \
  if(q[5] >= q[6]) byte |= 64u; \
  cb[(size_t)((TIDX)-1)*64 + lane] = (unsigned char)byte; \
  q[6] = fmaxf(q[6], q[5]) + (E)[6]; \
  q[5] = fmaxf(q[5], q[4]) + (E)[5]; \
  q[4] = fmaxf(q[4], q[3]) + (E)[4]; \
  q[3] = fmaxf(q[3], q[2]) + (E)[3]; \
  q[2] = fmaxf(q[2], q[1]) + (E)[2]; \
  q[1] = fmaxf(q[1], q[0]) + (E)[1]; \
  q[0] = fmaxf(q[0], n1) + (E)[0]; }

#define MPREF(E, ROW) { int rr=(ROW); rr = (rr>TF-1)? (TF-1) : rr; const float* rpp = lp + (size_t)rr*TT; \
  (E)[0]=rpp[jc[0]]; (E)[1]=rpp[jc[1]]; (E)[2]=rpp[jc[2]]; (E)[3]=rpp[jc[3]]; \
  (E)[4]=rpp[jc[4]]; (E)[5]=rpp[jc[5]]; (E)[6]=rpp[jc[6]]; }

__global__ __launch_bounds__(128) __attribute__((amdgpu_waves_per_eu(1,1)))
void scan_k(const float* __restrict__ logp,
    const float* __restrict__ Z2, unsigned char* __restrict__ cmpb, float* __restrict__ nll){
  const int lane = threadIdx.x & 63;
  const int wave = threadIdx.x >> 6;
  constexpr float IL2 = 1.4426950408889634f;
  constexpr float L2  = 0.6931471805599453f;
  if(blockIdx.x < NB){
    const int b = blockIdx.x;
    const float* lp = logp + (size_t)b*TF*TT;
    __shared__ float af[801], ag[801];
    const int dir = wave;
    double zs = 0.0;
    if(wave==0){
      for(int t=lane; t<TF; t+=64) zs += (double)Z2[b*TF + t];
#pragma unroll
      for(int o=32;o;o>>=1) zs += __shfl_xor(zs, o, 64);
    }
    int jc[7];
#pragma unroll
    for(int i=0;i<7;i++){ int j = 7*lane + i; j = (j < TT)? j : (TT-1); jc[i] = dir? (TT-1-j) : j; }
    float a[14];
#pragma unroll
    for(int i=0;i<14;i++) a[i] = BIGN;
    if(lane==0){
      a[0] = -1.0f*IL2;
      a[1] = (dir? lp[(size_t)(TF-1)*TT + (TT-1)] : lp[0]) * IL2;
    }
    const float EBL = -1.0f*IL2;
    float e0[7],e1[7],e2[7],e3[7],e4[7],e5[7],e6[7],e7[7];
    CPREF(e0,1); CPREF(e1,2); CPREF(e2,3); CPREF(e3,4);
    CPREF(e4,5); CPREF(e5,6); CPREF(e6,7); CPREF(e7,8);
    int k = 1;
    for(; k + 8 <= 993; k += 8){
      LCTC_STEP(e0); CPREF(e0, k+8);
      LCTC_STEP(e1); CPREF(e1, k+9);
      LCTC_STEP(e2); CPREF(e2, k+10);
      LCTC_STEP(e3); CPREF(e3, k+11);
      LCTC_STEP(e4); CPREF(e4, k+12);
      LCTC_STEP(e5); CPREF(e5, k+13);
      LCTC_STEP(e6); CPREF(e6, k+14);
      LCTC_STEP(e7); CPREF(e7, k+15);
    }
    for(; k<=999; k++){
      float P[7];
      CPREF(P, k);
      LCTC_STEP(P);
    }
    float* dst = wave? ag : af;
#pragma unroll
    for(int i=0;i<14;i++){ int s = 14*lane+i; if(s<=800) dst[s] = a[i]; }
    __syncthreads();
    if(wave==0){
      float acc = BIGN;
#pragma unroll
      for(int i=0;i<14;i++){
        int s = 14*lane+i;
        if(s<=800){
          float x0 = af[s];
          float x1 = (s>=1)? af[s-1] : BIGN;
          float x2 = ((s&1) && s>=3)? af[s-2] : BIGN;
          float A1 = lse3b(x0,x1,x2);
          acc = lse2b(acc, A1 + ag[800-s]);
        }
      }
#pragma unroll
      for(int o=32;o;o>>=1) acc = lse2b(acc, __shfl_xor(acc,o,64));
      if(lane==0) nll[b] = -((acc*L2) - (float)zs);
    }
  } else {
    if(wave) return;
    const int b = blockIdx.x - NB;
    const float* lp = logp + (size_t)b*TF*TT;
    unsigned char* cb = cmpb + (size_t)b*TF*64;
    int jc[7];
#pragma unroll
    for(int i=0;i<7;i++){ int j = 7*lane + i; jc[i] = (j < TT)? j : (TT-1); }
    float q[7];
#pragma unroll
    for(int i=0;i<7;i++) q[i] = BIGN;
    if(lane==0) q[0] = lp[0];
    float e0[7],e1[7],e2[7],e3[7];
    MPREF(e0,1); MPREF(e1,2); MPREF(e2,3); MPREF(e3,4);
    int t0 = 1;
    for(; t0 + 4 <= TF; t0 += 4){
      MAS_STEP(e0, t0);   MPREF(e0, t0+4);
      MAS_STEP(e1, t0+1); MPREF(e1, t0+5);
      MAS_STEP(e2, t0+2); MPREF(e2, t0+6);
      MAS_STEP(e3, t0+3); MPREF(e3, t0+7);
    }
    for(; t0<TF; t0++){
      float P[7];
      MPREF(P, t0);
      MAS_STEP(P, t0);
    }
    {
      float n1 = shup1(q[6]);
      u32 byte = 0;
      if(lane>0 && n1 >= q[0]) byte |= 1u;
      if(q[0] >= q[1]) byte |= 2u;
      if(q[1] >= q[2]) byte |= 4u;
      if(q[2] >= q[3]) byte |= 8u;
      if(q[3] >= q[4]) byte |= 16u;
      if(q[4] >= q[5]) byte |= 32u;
      if(q[5] >= q[6]) byte |= 64u;
      cb[(size_t)(TF-1)*64 + lane] = (unsigned char)byte;
    }
  }
}

// ---------------- MAS backtrack + ds + gather ----------------
__global__ __launch_bounds__(256) void masback_k(const unsigned char* __restrict__ cmpb,
    const float* __restrict__ logp, float* __restrict__ ds, float* __restrict__ gsum){
  const int b = blockIdx.x;
  const unsigned char* cb = cmpb + (size_t)b*TF*64;
  __shared__ unsigned char bits[500*64];
  __shared__ short Ash[TF];
  __shared__ int cnt[TT];
  __shared__ float ps[4];
  int a = TT-1;
  for(int ch=3; ch>=0; ch--){
    const int tlo = ch*500;
    __syncthreads();
    for(int i=threadIdx.x;i<8000;i+=256) ((u32*)bits)[i] = ((const u32*)(cb + (size_t)tlo*64))[i];
    __syncthreads();
    if(threadIdx.x==0){
      int thi = tlo + 499;
      if(ch==3){ Ash[TF-1] = (short)(TT-1); thi = TF-2; }
      for(int t=thi;t>=tlo;t--){
        if(a > 0){
          unsigned char w = bits[(t-tlo)*64 + a/7];
          a -= (int)((w >> (a%7)) & 1u);
        }
        Ash[t] = (short)a;
      }
    }
  }
  __syncthreads();
  for(int i=threadIdx.x;i<TT;i+=256) cnt[i]=0;
  __syncthreads();
  float part = 0.f;
  const float* lp = logp + (size_t)b*TF*TT;
  for(int t=threadIdx.x;t<TF;t+=256){
    int at = Ash[t];
    atomicAdd(&cnt[at], 1);
    part += lp[(size_t)t*TT + at];
  }
  __syncthreads();
  for(int i=threadIdx.x;i<TT;i+=256) ds[(size_t)b*TT + i] = (float)cnt[i];
  part = wsum(part);
  if((threadIdx.x&63)==0) ps[threadIdx.x>>6] = part;
  __syncthreads();
  if(threadIdx.x==0) gsum[b] = ps[0]+ps[1]+ps[2]+ps[3];
}

__global__ void final_k(const float* __restrict__ nll, const float* __restrict__ gsum, float* __restrict__ out){
  if(threadIdx.x==0 && blockIdx.x==0){
    float fs=0.f, bs=0.f;
    for(int b=0;b<NB;b++){ fs += nll[b] / (float)TT; bs += gsum[b] / (float)TF; }
    out[6400] = -(bs / (float)NB);   // bin_loss
    out[6401] = fs / (float)NB;      // forwardsum_loss
  }
}

extern "C" void kernel_launch(void* const* d_in, const int* in_sizes, int n_in,
                              void* d_out, int out_size, void* d_ws, size_t ws_size,
                              hipStream_t stream){
  const float* speech = (const float*)d_in[0];
  const float* txt    = (const float*)d_in[1];
  const float* tw1 = (const float*)d_in[4];
  const float* tb1 = (const float*)d_in[5];
  const float* tw2 = (const float*)d_in[6];
  const float* tb2 = (const float*)d_in[7];
  const float* fw1 = (const float*)d_in[8];
  const float* fb1 = (const float*)d_in[9];
  const float* fw2 = (const float*)d_in[10];
  const float* fb2 = (const float*)d_in[11];
  const float* fw3 = (const float*)d_in[12];
  const float* fb3 = (const float*)d_in[13];
  float* out  = (float*)d_out;
  float* ds   = out;                 // (16,400)
  float* logp = out + 6402;          // (16,2000,400) -- also conv scratch until score_gemm
  char* ws = (char*)d_ws;
  double* lgt  = (double*)(ws + 0);
  double* rowA = (double*)(ws + 20480);
  double* colA = (double*)(ws + 36864);
  double* sA   = (double*)(ws + 40960);
  float*  nll  = (float*)(ws + 61440);
  float*  gsum = (float*)(ws + 61696);
  float*  Z2   = (float*)(ws + 65536);
  float*  fn2  = (float*)(ws + 196608);
  float*  tn2  = (float*)(ws + 327680);
  unsigned char* cmpb = (unsigned char*)(ws + 360448);
  float*  tenc = (float*)(ws + 2408448);
  float*  f1   = (float*)(ws + 8962048);   // f_enc fp32 (16,2000,256)
  if(ws_size < 41730048) return;

  // conv scratch inside the (dead until score_gemm) logp region; 256B-aligned base
  char* lr = (char*)(((uintptr_t)logp + 255) & ~(uintptr_t)255);
  u16* inbfT = (u16*)lr;                    // (16,402,256)  3.29MB   [txt phase]
  u16* tout1 = (u16*)(lr + 4000000);        // (16,402,256)  3.29MB   [txt phase]
  u16* inbfA = (u16*)lr;                    // (16,2002,512) 32.80MB  [f phase 1; AFTER txt phase]
  u16* out2  = (u16*)lr;                    // (16,2002,256) 16.40MB  [f phase 3, after inbfA dead]
  u16* wbase = (u16*)(lr + 32900000);       // packs, 1.84MB, live all conv phases
  u16* fw1p = wbase;
  u16* fw2p = wbase + 393216;
  u16* fw3p = wbase + 589824;
  u16* tw1p = wbase + 655360;
  u16* tw2p = wbase + 851968;
  u16* out1  = (u16*)(lr + 34750000);       // (16,2002,256) 16.40MB

  k_lgt  <<<10,256,0,stream>>>(lgt);
  k_terms<<<10,256,0,stream>>>(lgt,rowA,colA,sA);

  prep1_k<<<2048,256,0,stream>>>(fw1,fw2,fw3,tw1,tw2, txt,
                                 fw1p,fw2p,fw3p,tw1p,tw2p, inbfT, tout1, out1);

  // txt path
  mfconv_k<256,3,true ,true ><<<dim3(7,NB),256,0,stream>>>(inbfT, tw1p, tb1, tout1, TT);
  mfconv_k<256,1,false,false><<<dim3(7,NB),256,0,stream>>>(tout1, tw2p, tb2, tenc, TT);

  // f path (speech convert must run AFTER txt phase: inbfA overlaps inbfT/tout1)
  cvt_pad_k<<<4096,256,0,stream>>>(speech, inbfA, TF, 512);
  mfconv_k<512,3,true ,true ><<<dim3(32,NB),256,0,stream>>>(inbfA, fw1p, fb1, out1, TF);
  zpad_k<<<32,256,0,stream>>>(out2, TF);               // after fconv1: inbfA region dead
  mfconv_k<256,3,true ,true ><<<dim3(32,NB),256,0,stream>>>(out1, fw2p, fb2, out2, TF);
  mfconv_k<256,1,false,false><<<dim3(32,NB),256,0,stream>>>(out2, fw3p, fb3, f1, TF);

  norm2b_k<<<(NB*TF+NB*TT)/4,256,0,stream>>>(f1, tenc, fn2, tn2);

  score_gemm<<<dim3(7,32,NB),256,0,stream>>>(f1, tenc, fn2, tn2, logp);
  softmax_prior_k<<<NB*TF,128,0,stream>>>(logp, rowA, colA, sA, Z2);

  scan_k<<<2*NB,128,0,stream>>>(logp, Z2, cmpb, nll);
  masback_k<<<NB,256,0,stream>>>(cmpb, logp, ds, gsum);
  final_k<<<1,64,0,stream>>>(nll, gsum, out);
}

// Round 17
// 818.606 us; speedup vs baseline: 2.1615x; 1.0787x over previous
//
#include <hip/hip_runtime.h>
#include <math.h>

typedef unsigned int u32;
typedef unsigned long long u64;
typedef unsigned short u16;
typedef __attribute__((ext_vector_type(8))) _Float16 f16x8;  // 8 fp16 (4 VGPR)
typedef __attribute__((ext_vector_type(4))) float f32x4;

#define BIGN (-1e30f)

static constexpr int NB = 16;     // batch
static constexpr int TF = 2000;   // T_FEATS
static constexpr int TT = 400;    // T_TEXT

__device__ __forceinline__ float wsum(float v){
#pragma unroll
  for(int o=32;o;o>>=1) v += __shfl_xor(v,o,64);
  return v;
}
__device__ __forceinline__ float EXP2(float x){ return __builtin_amdgcn_exp2f(x); }
__device__ __forceinline__ float LOG2(float x){ return __builtin_amdgcn_logf(x); }
__device__ __forceinline__ float lse2b(float x, float y){
  float m = fmaxf(x,y);
  return m + LOG2(1.0f + EXP2(-fabsf(x-y)));
}
__device__ __forceinline__ float lse3b(float x, float y, float z){
  float mx = fmaxf(fmaxf(x,y),z);
  float md = __builtin_amdgcn_fmed3f(x,y,z);
  float mn = fminf(fminf(x,y),z);
  return mx + LOG2(1.0f + EXP2(md-mx) + EXP2(mn-mx));
}
__device__ __forceinline__ u16 f2h(float v){
  _Float16 h = (_Float16)v;              // round-nearest-even
  return *(u16*)&h;
}
// lane i <- lane i-1, lane 0 <- BIGN. DPP wave_shr1 (0x138): pure VALU, no LDS/lgkmcnt.
__device__ __forceinline__ float shup1(float v){
  int r = __builtin_amdgcn_update_dpp(__float_as_int(BIGN), __float_as_int(v),
                                      0x138, 0xf, 0xf, false);
  return __int_as_float(r);
}

// ---------------- gammaln tables ----------------
__global__ void k_lgt(double* lgt){
  int m = blockIdx.x*blockDim.x + threadIdx.x;
  if(m < 2432) lgt[m] = (m>=1)? lgamma((double)m) : 0.0;
}
__global__ void k_terms(const double* __restrict__ lgt, double* rowA, double* colA, double* sA){
  int i = blockIdx.x*blockDim.x + threadIdx.x;
  if(i < TF)   rowA[i] = -lgt[2401] - lgt[i+1] - lgt[2000-i] + lgt[2001];
  if(i < TT)   colA[i] =  lgt[401]  - lgt[i+2] - lgt[400-i];
  if(i < 2399) sA[i]   =  lgt[i+2]  + lgt[2399-i];
}

// ---------------- consolidated prep: 5 weight packs + txt cvt + zpad(tout1,out1) ----------------
__device__ __forceinline__ void packf(const float* __restrict__ w, u16* __restrict__ dst,
    int CIN, int KW, int i){
  int k = i % KW;
  int c = (i / KW) % CIN;
  int o = i / (KW*CIN);
  dst[((size_t)k*256 + o)*CIN + c] = f2h(w[i]);
}
__device__ __forceinline__ void cvtp(const float* __restrict__ src, u16* __restrict__ dst,
    int P, int C, int i){
  int c = i % C;
  int p = (i / C) % (P+2);
  int b = i / (C*(P+2));
  float v = 0.f;
  if(p>=1 && p<=P) v = src[((size_t)b*P + (p-1))*C + c];
  dst[i] = f2h(v);
}
__device__ __forceinline__ void zpr(u16* __restrict__ buf, int P, int j){
  int c = j % 256;
  int s = (j / 256) & 1;
  int b = j / 512;
  buf[((size_t)b*(P+2) + (s? P+1 : 0))*256 + c] = 0;
}
__global__ __launch_bounds__(256) void prep1_k(
    const float* __restrict__ fw1, const float* __restrict__ fw2, const float* __restrict__ fw3,
    const float* __restrict__ tw1, const float* __restrict__ tw2, const float* __restrict__ txt,
    u16* fw1p, u16* fw2p, u16* fw3p, u16* tw1p, u16* tw2p,
    u16* inbfT, u16* tout1, u16* out1){
  constexpr int N = 393216+196608+65536+196608+65536+1646592+8192+8192;
  for(int i = blockIdx.x*256 + threadIdx.x; i < N; i += gridDim.x*256){
    int j = i;
    if(j < 393216){ packf(fw1, fw1p, 512, 3, j); continue; } j -= 393216;
    if(j < 196608){ packf(fw2, fw2p, 256, 3, j); continue; } j -= 196608;
    if(j < 65536) { packf(fw3, fw3p, 256, 1, j); continue; } j -= 65536;
    if(j < 196608){ packf(tw1, tw1p, 256, 3, j); continue; } j -= 196608;
    if(j < 65536) { packf(tw2, tw2p, 256, 1, j); continue; } j -= 65536;
    if(j < 1646592){ cvtp(txt, inbfT, TT, 256, j); continue; } j -= 1646592;
    if(j < 8192) { zpr(tout1, TT, j); continue; } j -= 8192;
    zpr(out1, TF, j);
  }
}

// ---------------- fp32 -> padded fp16 (rows 0 and P+1 zero) ----------------
__global__ __launch_bounds__(256) void cvt_pad_k(const float* __restrict__ src, u16* __restrict__ dst,
    int P, int C){
  int n = NB*(P+2)*C;
  for(int i = blockIdx.x*256 + threadIdx.x; i < n; i += gridDim.x*256) cvtp(src, dst, P, C, i);
}
// ---------------- zero pad rows (0 and P+1) ----------------
__global__ __launch_bounds__(256) void zpad_k(u16* __restrict__ buf, int P){
  int n = NB*2*256;
  for(int i = blockIdx.x*256 + threadIdx.x; i < n; i += gridDim.x*256) zpr(buf, P, i);
}

// ---------------- conv1d via MFMA fp16 ----------------
template<int CIN, int KW, bool RELU, bool OBF>
__global__ __launch_bounds__(256) void mfconv_k(const u16* __restrict__ inb,
    const u16* __restrict__ wp, const float* __restrict__ bias, void* __restrict__ outp, int P){
  __shared__ __align__(16) u16 Al[4*66*8];            // 4224 B
  __shared__ __align__(16) u16 Bl[KW*4*256*8];        // KW3: 49152 B, KW1: 16384 B
  const int b = blockIdx.y;
  const int m0 = blockIdx.x * 64;
  const int tid = threadIdx.x;
  const int lane = tid & 63, wv = tid >> 6;
  const int lo16 = lane & 15, hi = lane >> 4;
  constexpr int K1 = (KW==1)? 1 : 0;
  const u16* inB = inb + (size_t)b*(P+2)*CIN;
  f32x4 acc[4][4];
#pragma unroll
  for(int i=0;i<4;i++)
#pragma unroll
    for(int j=0;j<4;j++) acc[i][j] = (f32x4){0.f,0.f,0.f,0.f};

  for(int c0=0; c0<CIN; c0+=32){
    __syncthreads();
    for(int idx = tid; idx < 264; idx += 256){
      int r = idx >> 2, q = idx & 3;
      int rowp = m0 + r;
      f16x8 v = (f16x8){0,0,0,0,0,0,0,0};
      if(rowp <= P+1) v = *(const f16x8*)&inB[(size_t)rowp*CIN + c0 + q*8];
      *(f16x8*)&Al[(q*66 + r)*8] = v;
    }
#pragma unroll
    for(int k=0;k<KW;k++){
      const u16* wr = &wp[((size_t)(k*256) + tid)*CIN + c0];
      f16x8 w0 = *(const f16x8*)&wr[0];
      f16x8 w1 = *(const f16x8*)&wr[8];
      f16x8 w2 = *(const f16x8*)&wr[16];
      f16x8 w3 = *(const f16x8*)&wr[24];
      *(f16x8*)&Bl[((k*4+0)*256 + tid)*8] = w0;
      *(f16x8*)&Bl[((k*4+1)*256 + tid)*8] = w1;
      *(f16x8*)&Bl[((k*4+2)*256 + tid)*8] = w2;
      *(f16x8*)&Bl[((k*4+3)*256 + tid)*8] = w3;
    }
    __syncthreads();
#pragma unroll
    for(int k=0;k<KW;k++){
      f16x8 af[4];
#pragma unroll
      for(int rf=0;rf<4;rf++)
        af[rf] = *(const f16x8*)&Al[(hi*66 + rf*16 + lo16 + k + K1)*8];
#pragma unroll
      for(int cf=0;cf<4;cf++){
        int o = wv*64 + cf*16 + lo16;
        f16x8 bf = *(const f16x8*)&Bl[((k*4+hi)*256 + o)*8];
#pragma unroll
        for(int rf=0;rf<4;rf++)
          acc[rf][cf] = __builtin_amdgcn_mfma_f32_16x16x32_f16(af[rf], bf, acc[rf][cf], 0, 0, 0);
      }
    }
  }
#pragma unroll
  for(int cf=0;cf<4;cf++){
    int o = wv*64 + cf*16 + lo16;
    float bs = bias[o];
#pragma unroll
    for(int rf=0;rf<4;rf++){
#pragma unroll
      for(int j=0;j<4;j++){
        int p = m0 + rf*16 + hi*4 + j;
        if(p < P){
          float v = acc[rf][cf][j] + bs;
          if(RELU) v = fmaxf(v, 0.f);
          if(OBF) ((u16*)outp)[((size_t)b*(P+2) + p + 1)*256 + o] = f2h(v);
          else    ((float*)outp)[((size_t)b*P + p)*256 + o] = v;
        }
      }
    }
  }
}

// ---------------- row squared norms (f1 and tenc merged) ----------------
__global__ __launch_bounds__(256) void norm2b_k(const float* __restrict__ x1, const float* __restrict__ x2,
    float* __restrict__ o1, float* __restrict__ o2){
  int r = blockIdx.x*4 + (threadIdx.x>>6);
  int lane = threadIdx.x & 63;
  const float* src; float* dst; int rr;
  if(r < NB*TF){ src = x1; dst = o1; rr = r; }
  else { rr = r - NB*TF; if(rr >= NB*TT) return; src = x2; dst = o2; }
  float4 v = ((const float4*)(src + (size_t)rr*256))[lane];
  float s = v.x*v.x + v.y*v.y + v.z*v.z + v.w*v.w;
  s = wsum(s);
  if(lane==0) dst[rr] = s;
}

// ---------------- score = -sqrt(max(||f||^2+||t||^2-2 f.t, 1e-12)) ----------------
__global__ __launch_bounds__(256) void score_gemm(const float* __restrict__ F, const float* __restrict__ Tn,
    const float* __restrict__ fn2, const float* __restrict__ tn2, float* __restrict__ outp){
  constexpr int KC = 32;
  __shared__ __align__(16) float As[KC][68];
  __shared__ __align__(16) float Bs[KC][68];
  const int b = blockIdx.z;
  const int t0 = blockIdx.y*64, s0 = blockIdx.x*64;
  const int tid = threadIdx.x, tx = tid&15, ty = tid>>4;
  const float* Fb = F  + (size_t)b*TF*256;
  const float* Tb = Tn + (size_t)b*TT*256;
  float acc[4][4] = {};
  const int lk = tid & 31, lt0 = (tid>>5)*8;
  for(int k0=0;k0<256;k0+=KC){
    __syncthreads();
#pragma unroll
    for(int i=0;i<8;i++){
      int t = t0 + lt0 + i;
      As[lk][lt0+i] = (t<TF)? Fb[(size_t)t*256 + k0 + lk] : 0.f;
      int s = s0 + lt0 + i;
      Bs[lk][lt0+i] = (s<TT)? Tb[(size_t)s*256 + k0 + lk] : 0.f;
    }
    __syncthreads();
#pragma unroll
    for(int k=0;k<KC;k++){
      float a0[4], b0[4];
      *(float4*)a0 = *(const float4*)&As[k][ty*4];
      *(float4*)b0 = *(const float4*)&Bs[k][tx*4];
#pragma unroll
      for(int i=0;i<4;i++)
#pragma unroll
        for(int j=0;j<4;j++) acc[i][j] = fmaf(a0[i], b0[j], acc[i][j]);
    }
  }
#pragma unroll
  for(int i=0;i<4;i++){
    int t = t0 + ty*4 + i;
    if(t<TF){
      float fn = fn2[b*TF + t];
#pragma unroll
      for(int j=0;j<4;j++){
        int s = s0 + tx*4 + j;
        if(s<TT){
          float d2 = fn + tn2[b*TT + s] - 2.f*acc[i][j];
          outp[((size_t)b*TF + t)*TT + s] = -sqrtf(fmaxf(d2, 1e-12f));
        }
      }
    }
  }
}

// ---------------- per-row log_softmax + prior, and Z2 = logsumexp([BLANK, row]) ----------------
__global__ __launch_bounds__(128) void softmax_prior_k(float* __restrict__ logp,
    const double* __restrict__ rowA, const double* __restrict__ colA, const double* __restrict__ sA,
    float* __restrict__ Z2){
  const int row = blockIdx.x;           // b*TF + t0
  const int t0 = row % TF;
  float* rp = logp + (size_t)row*TT;
  const int tid = threadIdx.x;
  __shared__ float sh2[2];
  float v[4]; int ix[4];
#pragma unroll
  for(int i=0;i<4;i++){ ix[i] = tid + i*128; v[i] = (ix[i]<TT)? rp[ix[i]] : BIGN; }
  float m = fmaxf(fmaxf(v[0],v[1]),fmaxf(v[2],v[3]));
#pragma unroll
  for(int o=32;o;o>>=1) m = fmaxf(m, __shfl_xor(m,o,64));
  if((tid&63)==0) sh2[tid>>6] = m;
  __syncthreads();
  m = fmaxf(sh2[0], sh2[1]);
  float s = 0.f;
#pragma unroll
  for(int i=0;i<4;i++) if(ix[i]<TT) s += __expf(v[i]-m);
  s = wsum(s);
  __syncthreads();
  if((tid&63)==0) sh2[tid>>6] = s;
  __syncthreads();
  s = sh2[0] + sh2[1];
  const float lse = m + __logf(s);
  const double rA = rowA[t0];
  float f[4]; float m2 = BIGN;
#pragma unroll
  for(int i=0;i<4;i++){
    if(ix[i]<TT){
      float pr = (float)(colA[ix[i]] + sA[t0+ix[i]] + rA);
      f[i] = (v[i]-lse) + pr;
      rp[ix[i]] = f[i];
      m2 = fmaxf(m2, f[i]);
    } else f[i] = BIGN;
  }
#pragma unroll
  for(int o=32;o;o>>=1) m2 = fmaxf(m2, __shfl_xor(m2,o,64));
  __syncthreads();
  if((tid&63)==0) sh2[tid>>6] = m2;
  __syncthreads();
  m2 = fmaxf(fmaxf(sh2[0],sh2[1]), -1.0f);
  float s2 = (tid==0)? __expf(-1.0f - m2) : 0.f;
#pragma unroll
  for(int i=0;i<4;i++) if(ix[i]<TT) s2 += __expf(f[i]-m2);
  s2 = wsum(s2);
  __syncthreads();
  if((tid&63)==0) sh2[tid>>6] = s2;
  __syncthreads();
  if(tid==0) Z2[row] = m2 + __logf(sh2[0]+sh2[1]);
}

// ---------------- scans ----------------
// CTC: 4 waves/block: {fwd,rev} x {lo: states 0..423, hi: 424..800}. 8 states/lane (base even ->
// lane-uniform pairing, 8 lse2b = 16 trans/step/wave, half the single-wave cost; separate SIMDs
// have separate trans pipes). One scalar crosses the seam per step (lo's a[423]) via
// double-buffered LDS slot + one barrier per step.
#define LCTC8(E, KV) { \
  float bv = bnd[dir][((KV)-1)&1]; \
  float n1 = shup1(a[7]); \
  if(half && lane==0) n1 = bv; \
  float w0 = lse2b(a[0], n1); \
  float w1 = lse2b(a[2], a[1]); \
  float w2 = lse2b(a[4], a[3]); \
  float w3 = lse2b(a[6], a[5]); \
  a[7] = lse2b(a[7], w3) + (E)[3]; \
  a[5] = lse2b(a[5], w2) + (E)[2]; \
  a[3] = lse2b(a[3], w1) + (E)[1]; \
  a[1] = lse2b(a[1], w0) + (E)[0]; \
  a[6] = w3 + EBL; a[4] = w2 + EBL; a[2] = w1 + EBL; a[0] = w0 + EBL; \
  if(half==0 && lane==52) bnd[dir][(KV)&1] = a[7]; \
  __syncthreads(); }

#define CPREF4(E, K) { int kk=(K); if(kk>999) kk=999; int row = dir? (TF-1-kk) : kk; \
  const float* rpp = lp + (size_t)row*TT; \
  (E)[0]=rpp[jc[0]]*IL2; (E)[1]=rpp[jc[1]]*IL2; (E)[2]=rpp[jc[2]]*IL2; (E)[3]=rpp[jc[3]]*IL2; }

#define MAS_STEP(E, TIDX) { \
  float n1 = shup1(q[6]); \
  u32 byte = 0; \
  if(lane>0 && n1 >= q[0]) byte |= 1u; \
  if(q[0] >= q[1]) byte |= 2u; \
  if(q[1] >= q[2]) byte |= 4u; \
  if(q[2] >= q[3]) byte |= 8u; \
  if(q[3] >= q[4]) byte |= 16u; \
  if(q[4] >= q[5]) byte |= 32u; \
  if(q[5] >= q[6]) byte |= 64u; \
  cb[(size_t)((TIDX)-1)*64 + lane] = (unsigned char)byte; \
  q[6] = fmaxf(q[6], q[5]) + (E)[6]; \
  q[5] = fmaxf(q[5], q[4]) + (E)[5]; \
  q[4] = fmaxf(q[4], q[3]) + (E)[4]; \
  q[3] = fmaxf(q[3], q[2]) + (E)[3]; \
  q[2] = fmaxf(q[2], q[1]) + (E)[2]; \
  q[1] = fmaxf(q[1], q[0]) + (E)[1]; \
  q[0] = fmaxf(q[0], n1) + (E)[0]; }

#define MPREF(E, ROW) { int rr=(ROW); rr = (rr>TF-1)? (TF-1) : rr; const float* rpp = lp + (size_t)rr*TT; \
  (E)[0]=rpp[jc[0]]; (E)[1]=rpp[jc[1]]; (E)[2]=rpp[jc[2]]; (E)[3]=rpp[jc[3]]; \
  (E)[4]=rpp[jc[4]]; (E)[5]=rpp[jc[5]]; (E)[6]=rpp[jc[6]]; }

__global__ __launch_bounds__(256) __attribute__((amdgpu_waves_per_eu(1,1)))
void scan_k(const float* __restrict__ logp,
    const float* __restrict__ Z2, unsigned char* __restrict__ cmpb, float* __restrict__ nll){
  const int lane = threadIdx.x & 63;
  const int wave = threadIdx.x >> 6;
  constexpr float IL2 = 1.4426950408889634f;
  constexpr float L2  = 0.6931471805599453f;
  if(blockIdx.x < NB){
    const int b = blockIdx.x;
    const float* lp = logp + (size_t)b*TF*TT;
    __shared__ float af[801], ag[801];
    __shared__ float bnd[2][2];          // [dir][t&1] seam value a[423] (old)
    const int dir  = wave >> 1;          // 0: t=0..999 ; 1: t=1999..1000 (state w=800-s)
    const int half = wave & 1;           // 0: states 0..423 ; 1: 424..800
    const int base = half ? 424 : 0;
    double zs = 0.0;
    if(wave==0){
      for(int t=lane; t<TF; t+=64) zs += (double)Z2[b*TF + t];
#pragma unroll
      for(int o=32;o;o>>=1) zs += __shfl_xor(zs, o, 64);
    }
    // emission cols: per-lane odd states i=1,3,5,7 -> j = base/2 + 4*lane + (i-1)/2
    int jc[4];
#pragma unroll
    for(int i=0;i<4;i++){
      int j = base/2 + 4*lane + i;
      if(dir) j = TT-1-j;
      jc[i] = (j < 0)? 0 : ((j > TT-1)? TT-1 : j);
    }
    float a[8];
#pragma unroll
    for(int i=0;i<8;i++) a[i] = BIGN;
    if(half==0 && lane==0){
      a[0] = -1.0f*IL2;
      a[1] = (dir? lp[(size_t)(TF-1)*TT + (TT-1)] : lp[0]) * IL2;
    }
    const float EBL = -1.0f*IL2;
    if(half==0 && lane==52) bnd[dir][0] = a[7];   // step-0 boundary (BIGN)
    float e0[4],e1[4],e2[4],e3[4],e4[4],e5[4],e6[4],e7[4];
    CPREF4(e0,1); CPREF4(e1,2); CPREF4(e2,3); CPREF4(e3,4);
    CPREF4(e4,5); CPREF4(e5,6); CPREF4(e6,7); CPREF4(e7,8);
    __syncthreads();
    int k = 1;
    for(; k + 8 <= 993; k += 8){
      LCTC8(e0, k);   CPREF4(e0, k+8);
      LCTC8(e1, k+1); CPREF4(e1, k+9);
      LCTC8(e2, k+2); CPREF4(e2, k+10);
      LCTC8(e3, k+3); CPREF4(e3, k+11);
      LCTC8(e4, k+4); CPREF4(e4, k+12);
      LCTC8(e5, k+5); CPREF4(e5, k+13);
      LCTC8(e6, k+6); CPREF4(e6, k+14);
      LCTC8(e7, k+7); CPREF4(e7, k+15);
    }
    for(; k<=999; k++){
      float P[4];
      CPREF4(P, k);
      LCTC8(P, k);
    }
    float* dst = dir? ag : af;
#pragma unroll
    for(int i=0;i<8;i++){
      int s = base + 8*lane + i;
      if(half){ if(s<=800) dst[s] = a[i]; }
      else    { if(s<=423) dst[s] = a[i]; }
    }
    __syncthreads();
    if(wave==0){
      float acc = BIGN;
      for(int s = lane; s <= 800; s += 64){
        float x0 = af[s];
        float x1 = (s>=1)? af[s-1] : BIGN;
        float x2 = ((s&1) && s>=3)? af[s-2] : BIGN;
        float A1 = lse3b(x0,x1,x2);                 // one transition, no emission
        acc = lse2b(acc, A1 + ag[800-s]);
      }
#pragma unroll
      for(int o=32;o;o>>=1) acc = lse2b(acc, __shfl_xor(acc,o,64));
      if(lane==0) nll[b] = -((acc*L2) - (float)zs);
    }
  } else {
    if(wave) return;
    const int b = blockIdx.x - NB;
    const float* lp = logp + (size_t)b*TF*TT;
    unsigned char* cb = cmpb + (size_t)b*TF*64;
    int jc[7];
#pragma unroll
    for(int i=0;i<7;i++){ int j = 7*lane + i; jc[i] = (j < TT)? j : (TT-1); }
    float q[7];
#pragma unroll
    for(int i=0;i<7;i++) q[i] = BIGN;
    if(lane==0) q[0] = lp[0];
    float e0[7],e1[7],e2[7],e3[7];
    MPREF(e0,1); MPREF(e1,2); MPREF(e2,3); MPREF(e3,4);
    int t0 = 1;
    for(; t0 + 4 <= TF; t0 += 4){
      MAS_STEP(e0, t0);   MPREF(e0, t0+4);
      MAS_STEP(e1, t0+1); MPREF(e1, t0+5);
      MAS_STEP(e2, t0+2); MPREF(e2, t0+6);
      MAS_STEP(e3, t0+3); MPREF(e3, t0+7);
    }
    for(; t0<TF; t0++){
      float P[7];
      MPREF(P, t0);
      MAS_STEP(P, t0);
    }
    {
      float n1 = shup1(q[6]);
      u32 byte = 0;
      if(lane>0 && n1 >= q[0]) byte |= 1u;
      if(q[0] >= q[1]) byte |= 2u;
      if(q[1] >= q[2]) byte |= 4u;
      if(q[2] >= q[3]) byte |= 8u;
      if(q[3] >= q[4]) byte |= 16u;
      if(q[4] >= q[5]) byte |= 32u;
      if(q[5] >= q[6]) byte |= 64u;
      cb[(size_t)(TF-1)*64 + lane] = (unsigned char)byte;
    }
  }
}

// ---------------- MAS backtrack + ds + gather ----------------
__global__ __launch_bounds__(256) void masback_k(const unsigned char* __restrict__ cmpb,
    const float* __restrict__ logp, float* __restrict__ ds, float* __restrict__ gsum){
  const int b = blockIdx.x;
  const unsigned char* cb = cmpb + (size_t)b*TF*64;
  __shared__ unsigned char bits[500*64];
  __shared__ short Ash[TF];
  __shared__ int cnt[TT];
  __shared__ float ps[4];
  int a = TT-1;
  for(int ch=3; ch>=0; ch--){
    const int tlo = ch*500;
    __syncthreads();
    for(int i=threadIdx.x;i<8000;i+=256) ((u32*)bits)[i] = ((const u32*)(cb + (size_t)tlo*64))[i];
    __syncthreads();
    if(threadIdx.x==0){
      int thi = tlo + 499;
      if(ch==3){ Ash[TF-1] = (short)(TT-1); thi = TF-2; }
      for(int t=thi;t>=tlo;t--){
        if(a > 0){
          unsigned char w = bits[(t-tlo)*64 + a/7];
          a -= (int)((w >> (a%7)) & 1u);
        }
        Ash[t] = (short)a;
      }
    }
  }
  __syncthreads();
  for(int i=threadIdx.x;i<TT;i+=256) cnt[i]=0;
  __syncthreads();
  float part = 0.f;
  const float* lp = logp + (size_t)b*TF*TT;
  for(int t=threadIdx.x;t<TF;t+=256){
    int at = Ash[t];
    atomicAdd(&cnt[at], 1);
    part += lp[(size_t)t*TT + at];
  }
  __syncthreads();
  for(int i=threadIdx.x;i<TT;i+=256) ds[(size_t)b*TT + i] = (float)cnt[i];
  part = wsum(part);
  if((threadIdx.x&63)==0) ps[threadIdx.x>>6] = part;
  __syncthreads();
  if(threadIdx.x==0) gsum[b] = ps[0]+ps[1]+ps[2]+ps[3];
}

__global__ void final_k(const float* __restrict__ nll, const float* __restrict__ gsum, float* __restrict__ out){
  if(threadIdx.x==0 && blockIdx.x==0){
    float fs=0.f, bs=0.f;
    for(int b=0;b<NB;b++){ fs += nll[b] / (float)TT; bs += gsum[b] / (float)TF; }
    out[6400] = -(bs / (float)NB);   // bin_loss
    out[6401] = fs / (float)NB;      // forwardsum_loss
  }
}

extern "C" void kernel_launch(void* const* d_in, const int* in_sizes, int n_in,
                              void* d_out, int out_size, void* d_ws, size_t ws_size,
                              hipStream_t stream){
  const float* speech = (const float*)d_in[0];
  const float* txt    = (const float*)d_in[1];
  const float* tw1 = (const float*)d_in[4];
  const float* tb1 = (const float*)d_in[5];
  const float* tw2 = (const float*)d_in[6];
  const float* tb2 = (const float*)d_in[7];
  const float* fw1 = (const float*)d_in[8];
  const float* fb1 = (const float*)d_in[9];
  const float* fw2 = (const float*)d_in[10];
  const float* fb2 = (const float*)d_in[11];
  const float* fw3 = (const float*)d_in[12];
  const float* fb3 = (const float*)d_in[13];
  float* out  = (float*)d_out;
  float* ds   = out;                 // (16,400)
  float* logp = out + 6402;          // (16,2000,400) -- also conv scratch until score_gemm
  char* ws = (char*)d_ws;
  double* lgt  = (double*)(ws + 0);
  double* rowA = (double*)(ws + 20480);
  double* colA = (double*)(ws + 36864);
  double* sA   = (double*)(ws + 40960);
  float*  nll  = (float*)(ws + 61440);
  float*  gsum = (float*)(ws + 61696);
  float*  Z2   = (float*)(ws + 65536);
  float*  fn2  = (float*)(ws + 196608);
  float*  tn2  = (float*)(ws + 327680);
  unsigned char* cmpb = (unsigned char*)(ws + 360448);
  float*  tenc = (float*)(ws + 2408448);
  float*  f1   = (float*)(ws + 8962048);   // f_enc fp32 (16,2000,256)
  if(ws_size < 41730048) return;

  // conv scratch inside the (dead until score_gemm) logp region; 256B-aligned base
  char* lr = (char*)(((uintptr_t)logp + 255) & ~(uintptr_t)255);
  u16* inbfT = (u16*)lr;                    // (16,402,256)  3.29MB   [txt phase]
  u16* tout1 = (u16*)(lr + 4000000);        // (16,402,256)  3.29MB   [txt phase]
  u16* inbfA = (u16*)lr;                    // (16,2002,512) 32.80MB  [f phase 1; AFTER txt phase]
  u16* out2  = (u16*)lr;                    // (16,2002,256) 16.40MB  [f phase 3, after inbfA dead]
  u16* wbase = (u16*)(lr + 32900000);       // packs, 1.84MB, live all conv phases
  u16* fw1p = wbase;
  u16* fw2p = wbase + 393216;
  u16* fw3p = wbase + 589824;
  u16* tw1p = wbase + 655360;
  u16* tw2p = wbase + 851968;
  u16* out1  = (u16*)(lr + 34750000);       // (16,2002,256) 16.40MB

  k_lgt  <<<10,256,0,stream>>>(lgt);
  k_terms<<<10,256,0,stream>>>(lgt,rowA,colA,sA);

  prep1_k<<<2048,256,0,stream>>>(fw1,fw2,fw3,tw1,tw2, txt,
                                 fw1p,fw2p,fw3p,tw1p,tw2p, inbfT, tout1, out1);

  // txt path
  mfconv_k<256,3,true ,true ><<<dim3(7,NB),256,0,stream>>>(inbfT, tw1p, tb1, tout1, TT);
  mfconv_k<256,1,false,false><<<dim3(7,NB),256,0,stream>>>(tout1, tw2p, tb2, tenc, TT);

  // f path (speech convert must run AFTER txt phase: inbfA overlaps inbfT/tout1)
  cvt_pad_k<<<4096,256,0,stream>>>(speech, inbfA, TF, 512);
  mfconv_k<512,3,true ,true ><<<dim3(32,NB),256,0,stream>>>(inbfA, fw1p, fb1, out1, TF);
  zpad_k<<<32,256,0,stream>>>(out2, TF);               // after fconv1: inbfA region dead
  mfconv_k<256,3,true ,true ><<<dim3(32,NB),256,0,stream>>>(out1, fw2p, fb2, out2, TF);
  mfconv_k<256,1,false,false><<<dim3(32,NB),256,0,stream>>>(out2, fw3p, fb3, f1, TF);

  norm2b_k<<<(NB*TF+NB*TT)/4,256,0,stream>>>(f1, tenc, fn2, tn2);

  score_gemm<<<dim3(7,32,NB),256,0,stream>>>(f1, tenc, fn2, tn2, logp);
  softmax_prior_k<<<NB*TF,128,0,stream>>>(logp, rowA, colA, sA, Z2);

  scan_k<<<2*NB,256,0,stream>>>(logp, Z2, cmpb, nll);
  masback_k<<<NB,256,0,stream>>>(cmpb, logp, ds, gsum);
  final_k<<<1,64,0,stream>>>(nll, gsum, out);
}